// Round 10
// baseline (4758.258 us; speedup 1.0000x reference)
//
#include <hip/hip_runtime.h>
#include <math.h>

// ---------------------------------------------------------------------------
// ParallelExpertsMixer — Round 10: R7 pipeline, GEMM = R5's verified 4-phase
// schedule with BK=32 and 64 KiB LDS -> 2 blocks/CU (cross-block overlap
// covers VMW/barrier stalls; m114 mechanism). Steady VMW(2); drain 2/1/0.
// ---------------------------------------------------------------------------

#define N_TOT 16384
#define EPSV 1e-5f

typedef unsigned short u16;
typedef unsigned int   u32;
typedef __attribute__((ext_vector_type(8))) short  short8;
typedef __attribute__((ext_vector_type(4))) float  floatx4;

__device__ __forceinline__ float gelu_exact(float x) {
    return 0.5f * x * (1.0f + erff(x * 0.70710678118654752440f));
}
__device__ __forceinline__ float wave_sum(float v) {
    #pragma unroll
    for (int o = 32; o > 0; o >>= 1) v += __shfl_xor(v, o);
    return v;
}
__device__ __forceinline__ u16 f2bf(float f) {
    u32 u = __float_as_uint(f);
    return (u16)((u + 0x7fffu + ((u >> 16) & 1u)) >> 16);
}
__device__ __forceinline__ u32 pack2(float lo, float hi) {
    return (u32)f2bf(lo) | ((u32)f2bf(hi) << 16);
}
__device__ __forceinline__ float bf1f(u16 u) { return __uint_as_float((u32)u << 16); }
__device__ __forceinline__ float2 bf2f2(u32 u) {
    return make_float2(__uint_as_float(u << 16), __uint_as_float(u & 0xffff0000u));
}
__device__ __forceinline__ void gload_lds16(const void* g, void* l) {
    __builtin_amdgcn_global_load_lds(
        (const __attribute__((address_space(1))) unsigned int*)g,
        (__attribute__((address_space(3))) unsigned int*)l, 16, 0, 0);
}

#define BARR() asm volatile("s_barrier" ::: "memory")
#define VMW(N) asm volatile("s_waitcnt vmcnt(" #N ")" ::: "memory")

// ---- bf16 weight conversion (once per launch) -----------------------------
#define W_CONVPW 0
#define W_INPROJ 262144
#define W_ATTNO  1048576
#define W_FFN1   1310720
#define W_FFN2   1835008
#define W_MLP1   2359296
#define W_MLP2   2883584
#define W_GATE1  3407872
#define W_SE1    3538944
#define W_SE2    3571712
#define W_OUTP   3604480
#define W_TOT    3866624

__global__ __launch_bounds__(256) void k_w2b(
        const float* __restrict__ p0, const float* __restrict__ p1,
        const float* __restrict__ p2, const float* __restrict__ p3,
        const float* __restrict__ p4, const float* __restrict__ p5,
        const float* __restrict__ p6, const float* __restrict__ p7,
        const float* __restrict__ p8, const float* __restrict__ p9,
        const float* __restrict__ p10, u16* __restrict__ dst)
{
    int i = blockIdx.x * 256 + threadIdx.x;
    if (i >= W_TOT) return;
    const float* s; int off;
    if      (i < W_INPROJ) { s = p0;  off = W_CONVPW; }
    else if (i < W_ATTNO)  { s = p1;  off = W_INPROJ; }
    else if (i < W_FFN1)   { s = p2;  off = W_ATTNO; }
    else if (i < W_FFN2)   { s = p3;  off = W_FFN1; }
    else if (i < W_MLP1)   { s = p4;  off = W_FFN2; }
    else if (i < W_MLP2)   { s = p5;  off = W_MLP1; }
    else if (i < W_GATE1)  { s = p6;  off = W_MLP2; }
    else if (i < W_SE1)    { s = p7;  off = W_GATE1; }
    else if (i < W_SE2)    { s = p8;  off = W_SE1; }
    else if (i < W_OUTP)   { s = p9;  off = W_SE2; }
    else                   { s = p10; off = W_OUTP; }
    dst[i] = f2bf(s[i - off]);
}

// ---- prep (4 samples/block): branches -> Tb + CTX + both LayerNorms -------
__global__ __launch_bounds__(256) void k_prep_ln(const float* __restrict__ br,
        int baseN, u16* __restrict__ Tb, u16* __restrict__ CTX,
        const float* __restrict__ law, const float* __restrict__ lab, u16* __restrict__ LNA,
        const float* __restrict__ lmw, const float* __restrict__ lmb, u16* __restrict__ LNM)
{
    __shared__ float lds[4][4][516];
    int t = threadIdx.x;
    int s0 = blockIdx.x * 4;
    #pragma unroll
    for (int s = 0; s < 4; ++s) {
        const float* p = br + (size_t)(baseN + s0 + s) * 2048;
        u16* c = CTX + (size_t)(s0 + s) * 1024;
        #pragma unroll
        for (int i = 0; i < 2; ++i) {
            int f = t + i * 256;
            float4 v = *(const float4*)(p + f * 4);
            lds[s][0][f] = v.x; lds[s][1][f] = v.y; lds[s][2][f] = v.z; lds[s][3][f] = v.w;
            c[f]       = f2bf((v.x + v.y + v.z + v.w) * 0.25f);
            c[512 + f] = f2bf(fmaxf(fmaxf(v.x, v.y), fmaxf(v.z, v.w)));
        }
    }
    __syncthreads();
    int wv = t >> 6, lane = t & 63, f0 = lane * 8;
    #pragma unroll
    for (int p4i = 0; p4i < 4; ++p4i) {
        int idx = wv * 4 + p4i;
        int s = idx >> 2, b = idx & 3;
        float xv[8];
        #pragma unroll
        for (int i = 0; i < 8; ++i) xv[i] = lds[s][b][f0 + i];
        float sm = 0.f;
        #pragma unroll
        for (int i = 0; i < 8; ++i) sm += xv[i];
        sm = wave_sum(sm);
        float m = sm * (1.f / 512.f);
        float q = 0.f;
        #pragma unroll
        for (int i = 0; i < 8; ++i) { float d = xv[i] - m; q += d * d; }
        q = wave_sum(q);
        float rs = rsqrtf(q * (1.f / 512.f) + EPSV);
        size_t row = (size_t)(s0 + s) * 4 + b;
        *(uint4*)(Tb + row * 512 + f0) = make_uint4(pack2(xv[0], xv[1]), pack2(xv[2], xv[3]),
                                                    pack2(xv[4], xv[5]), pack2(xv[6], xv[7]));
        float o[8];
        #pragma unroll
        for (int i = 0; i < 8; ++i) o[i] = (xv[i] - m) * rs * law[f0 + i] + lab[f0 + i];
        *(uint4*)(LNA + row * 512 + f0) = make_uint4(pack2(o[0], o[1]), pack2(o[2], o[3]),
                                                     pack2(o[4], o[5]), pack2(o[6], o[7]));
        #pragma unroll
        for (int i = 0; i < 8; ++i) o[i] = (xv[i] - m) * rs * lmw[f0 + i] + lmb[f0 + i];
        *(uint4*)(LNM + row * 512 + f0) = make_uint4(pack2(o[0], o[1]), pack2(o[2], o[3]),
                                                     pack2(o[4], o[5]), pack2(o[6], o[7]));
    }
}

// ---- LayerNorm over 512, bf16 in -> bf16 out ------------------------------
__global__ __launch_bounds__(256) void k_ln_b(const u16* __restrict__ X,
        const float* __restrict__ w, const float* __restrict__ b, u16* __restrict__ O)
{
    int t = threadIdx.x;
    int wave = t >> 6, lane = t & 63;
    size_t r = (size_t)blockIdx.x * 4 + wave;
    int f0 = lane * 8;
    uint4 raw = *(const uint4*)(X + r * 512 + f0);
    float xv[8];
    { float2 a = bf2f2(raw.x); xv[0] = a.x; xv[1] = a.y; }
    { float2 a = bf2f2(raw.y); xv[2] = a.x; xv[3] = a.y; }
    { float2 a = bf2f2(raw.z); xv[4] = a.x; xv[5] = a.y; }
    { float2 a = bf2f2(raw.w); xv[6] = a.x; xv[7] = a.y; }
    float s = 0.f;
    #pragma unroll
    for (int i = 0; i < 8; ++i) s += xv[i];
    s = wave_sum(s);
    float m = s * (1.f / 512.f);
    float q = 0.f;
    #pragma unroll
    for (int i = 0; i < 8; ++i) { float d = xv[i] - m; q += d * d; }
    q = wave_sum(q);
    float rs = rsqrtf(q * (1.f / 512.f) + EPSV);
    float o[8];
    #pragma unroll
    for (int i = 0; i < 8; ++i) o[i] = (xv[i] - m) * rs * w[f0 + i] + b[f0 + i];
    *(uint4*)(O + r * 512 + f0) = make_uint4(pack2(o[0], o[1]), pack2(o[2], o[3]),
                                             pack2(o[4], o[5]), pack2(o[6], o[7]));
}

// ===========================================================================
// 256x256 GEMM, BK=32, 4 phases/K-tile (R5 schedule, halved). 512 thr / 8
// waves; per-wave 64x32 piece of EACH 128x128 C-quadrant. LDS: 2 buf x
// [A0|A1|B0|B1] x 8KB = 64 KiB -> 2 blocks/CU. Each half = 128 rows x 32
// elems (64B rows, 4x 16B granules, granule-XOR (r>>1)&3 -> uniform banks).
// Stage order/tile: A0,B0,A1,B1 (1 load/thread each). Steady VMW(2),(2),(2),-;
// drain (2),(1),(0),-. Requires M%256==0, N%256==0, K%32==0, K>=64.
// STORE: 1 bf16 (+opt residual), 2 f4-scatter(out), 3 dw-conv+squeeze.
// ===========================================================================

#define STG_A(MH, TILE) do {                                                  \
    int E_ = tid * 8;                                                         \
    int r_ = E_ >> 5;                                                         \
    int g_ = (tid & 3) ^ ((r_ >> 1) & 3);                                     \
    gload_lds16(A + (size_t)(m0 + (MH) * 128 + r_) * K + (TILE) * 32 + g_ * 8,\
                lds + (((TILE) & 1) * 16384) + (MH) * 4096 + E_);             \
} while (0)

#define STG_B(NH, TILE) do {                                                  \
    int E_ = tid * 8;                                                         \
    int r_ = E_ >> 5;                                                         \
    int g_ = (tid & 3) ^ ((r_ >> 1) & 3);                                     \
    gload_lds16(W + (size_t)(n0 + (NH) * 128 + r_) * K + (TILE) * 32 + g_ * 8,\
                lds + (((TILE) & 1) * 16384) + 8192 + (NH) * 4096 + E_);      \
} while (0)

#define QUAD(MH, NH, STAGESTMT) do {                                          \
    const u16* lb_ = lds + cur * 16384;                                       \
    short8 a_[4], b_[2];                                                      \
    _Pragma("unroll")                                                         \
    for (int mi = 0; mi < 4; ++mi)                                            \
        a_[mi] = *(const short8*)(lb_ + (MH) * 4096 + aoff[mi]);              \
    _Pragma("unroll")                                                         \
    for (int ni = 0; ni < 2; ++ni)                                            \
        b_[ni] = *(const short8*)(lb_ + 8192 + (NH) * 4096 + boff[ni]);       \
    STAGESTMT;                                                                \
    BARR();                                                                   \
    __builtin_amdgcn_s_setprio(1);                                            \
    _Pragma("unroll")                                                         \
    for (int mi = 0; mi < 4; ++mi)                                            \
        _Pragma("unroll")                                                     \
        for (int ni = 0; ni < 2; ++ni)                                        \
            acc[MH][NH][mi][ni] = __builtin_amdgcn_mfma_f32_16x16x32_bf16(    \
                a_[mi], b_[ni], acc[MH][NH][mi][ni], 0, 0, 0);                \
    __builtin_amdgcn_s_setprio(0);                                            \
} while (0)

template<int EPI, bool HAS_BIAS, bool HAS_RES, int STORE>
__global__ __launch_bounds__(512, 4) void k_gemm256(
        const u16* __restrict__ A, const u16* __restrict__ W,
        const float* __restrict__ bias, const u16* __restrict__ Res,
        void* __restrict__ Cout, int Ncols, int K, int baseN, int nTX,
        const float* __restrict__ dwp, u16* __restrict__ Sout)
{
    __shared__ __align__(16) u16 lds[32768];   // 64 KiB -> 2 blocks/CU
    const int tid = threadIdx.x;
    const int wid = tid >> 6, lane = tid & 63;
    const int lr = lane & 15, kg = lane >> 4;
    const int wm = (wid >> 2) * 64;    // M offset within each M-half
    const int wn = (wid & 3) * 32;     // N offset within each N-half

    // bijective XCD swizzle (m204)
    int nwg = gridDim.x, orig = blockIdx.x;
    int q = nwg >> 3, r = nwg & 7;
    int xcd = orig & 7, lin = orig >> 3;
    int wgid = (xcd < r ? xcd * (q + 1) : r * (q + 1) + (xcd - r) * q) + lin;
    const int m0 = (wgid / nTX) * 256, n0 = (wgid % nTX) * 256;

    // fragment LDS element offsets within one half-region (128 rows x 32 elems)
    int aoff[4], boff[2];
    #pragma unroll
    for (int mi = 0; mi < 4; ++mi) {
        int R = wm + mi * 16 + lr;                 // 0..127
        aoff[mi] = R * 32 + ((kg ^ ((R >> 1) & 3)) * 8);
    }
    #pragma unroll
    for (int ni = 0; ni < 2; ++ni) {
        int R = wn + ni * 16 + lr;                 // 0..127
        boff[ni] = R * 32 + ((kg ^ ((R >> 1) & 3)) * 8);
    }

    floatx4 acc[2][2][4][2] = {};

    // prologue: stage K-tile 0 in consumption order (4 loads outstanding)
    STG_A(0, 0); STG_B(0, 0); STG_A(1, 0); STG_B(1, 0);

    const int NT = K >> 5;
    int cur = 0;
    for (int t = 0; t < NT - 1; ++t) {
        int nx = t + 1;
        VMW(2); BARR(); QUAD(0, 0, STG_A(0, nx));
        VMW(2); BARR(); QUAD(1, 0, STG_B(0, nx));
        VMW(2); BARR(); QUAD(0, 1, STG_A(1, nx));
                BARR(); QUAD(1, 1, STG_B(1, nx));
        cur ^= 1;
    }
    // last K-tile: counted drain
    VMW(2); BARR(); QUAD(0, 0, (void)0);
    VMW(1); BARR(); QUAD(1, 0, (void)0);
    VMW(0); BARR(); QUAD(0, 1, (void)0);
            BARR(); QUAD(1, 1, (void)0);

    // epilogue: D col = lane&15 (n), row = kg*4 + reg (m)
    int rm = kg * 4;
    #pragma unroll
    for (int MH = 0; MH < 2; ++MH)
    #pragma unroll
    for (int NH = 0; NH < 2; ++NH)
    #pragma unroll
    for (int ni = 0; ni < 2; ++ni) {
        int n = n0 + NH * 128 + wn + ni * 16 + lr;
        float bv = HAS_BIAS ? bias[n] : 0.f;
        float w0, w1, w2;
        if (STORE == 3) { w0 = dwp[n * 3]; w1 = dwp[n * 3 + 1]; w2 = dwp[n * 3 + 2]; }
        #pragma unroll
        for (int mi = 0; mi < 4; ++mi) {
            int mb = m0 + MH * 128 + wm + mi * 16 + rm;
            float vv[4];
            #pragma unroll
            for (int rr = 0; rr < 4; ++rr) {
                float v = acc[MH][NH][mi][ni][rr] + bv;
                if (EPI == 1) v = gelu_exact(v);
                else if (EPI == 2) v = fmaxf(v, 0.f);
                else if (EPI == 3) v = 1.f / (1.f + expf(-v));
                vv[rr] = v;
            }
            if (STORE == 2) {
                *(float4*)((float*)Cout + (size_t)(baseN + (mb >> 2)) * 2048 + (size_t)n * 4)
                    = make_float4(vv[0], vv[1], vv[2], vv[3]);
            } else if (STORE == 3) {
                // depthwise k=3 over tokens (rows mb..mb+3 = one sample) + squeeze
                float y0 = w1 * vv[0] + w2 * vv[1];
                float y1 = w0 * vv[0] + w1 * vv[1] + w2 * vv[2];
                float y2 = w0 * vv[1] + w1 * vv[2] + w2 * vv[3];
                float y3 = w0 * vv[2] + w1 * vv[3];
                u16* xp = (u16*)Cout + (size_t)mb * Ncols + n;
                xp[0] = f2bf(y0);
                xp[Ncols] = f2bf(y1);
                xp[2 * Ncols] = f2bf(y2);
                xp[3 * Ncols] = f2bf(y3);
                Sout[(size_t)(mb >> 2) * Ncols + n] = f2bf((y0 + y1 + y2 + y3) * 0.25f);
            } else {
                #pragma unroll
                for (int rr = 0; rr < 4; ++rr) {
                    float v = vv[rr];
                    if (HAS_RES) v += bf1f(Res[(size_t)(mb + rr) * Ncols + n]);
                    ((u16*)Cout)[(size_t)(mb + rr) * Ncols + n] = f2bf(v);
                }
            }
        }
    }
}

// ---- 128^2 MFMA GEMM (small shapes: gate1, se1, se2) ----------------------
template<int EPI, bool HAS_BIAS, bool HAS_RES, int STORE>
__global__ __launch_bounds__(256) void k_mfma_gemm(
        const u16* __restrict__ A, const u16* __restrict__ W,
        const float* __restrict__ bias, const u16* __restrict__ Res,
        void* __restrict__ Cout, int M, int Ncols, int K, int baseN)
{
    __shared__ u16 As[128 * 32];
    __shared__ u16 Bs[128 * 32];
    int t = threadIdx.x;
    int wid = t >> 6, lane = t & 63;
    int wm = (wid >> 1) * 64, wn = (wid & 1) * 64;
    int m0 = blockIdx.y * 128, n0 = blockIdx.x * 128;
    int srow = t >> 2;
    int scol = (((t & 3) ^ ((srow >> 1) & 3)) * 8);
    int aR0 = min(m0 + srow, M - 1),      aR1 = min(m0 + 64 + srow, M - 1);
    int bR0 = min(n0 + srow, Ncols - 1),  bR1 = min(n0 + 64 + srow, Ncols - 1);
    const u16* Ap0 = A + (size_t)aR0 * K + scol;
    const u16* Ap1 = A + (size_t)aR1 * K + scol;
    const u16* Wp0 = W + (size_t)bR0 * K + scol;
    const u16* Wp1 = W + (size_t)bR1 * K + scol;
    u16* AsT0 = As + t * 8;  u16* AsT1 = As + 2048 + t * 8;
    u16* BsT0 = Bs + t * 8;  u16* BsT1 = Bs + 2048 + t * 8;

    int kg = lane >> 4, lr = lane & 15;
    int cb = kg ^ ((lr >> 1) & 3);
    const u16* aF = As + (wm + lr) * 32 + cb * 8;
    const u16* bF = Bs + (wn + lr) * 32 + cb * 8;

    floatx4 acc[4][4] = {};
    for (int k0 = 0; k0 < K; k0 += 32) {
        __syncthreads();
        gload_lds16(Ap0 + k0, AsT0);
        gload_lds16(Ap1 + k0, AsT1);
        gload_lds16(Wp0 + k0, BsT0);
        gload_lds16(Wp1 + k0, BsT1);
        __syncthreads();
        short8 a[4], b[4];
        #pragma unroll
        for (int i = 0; i < 4; ++i) {
            a[i] = *(const short8*)(aF + i * 512);
            b[i] = *(const short8*)(bF + i * 512);
        }
        #pragma unroll
        for (int i = 0; i < 4; ++i)
            #pragma unroll
            for (int j = 0; j < 4; ++j)
                acc[i][j] = __builtin_amdgcn_mfma_f32_16x16x32_bf16(a[i], b[j], acc[i][j], 0, 0, 0);
    }
    int rm = (lane >> 4) * 4;
    #pragma unroll
    for (int j = 0; j < 4; ++j) {
        int n = n0 + wn + j * 16 + lr;
        float bv = HAS_BIAS ? bias[min(n, Ncols - 1)] : 0.f;
        #pragma unroll
        for (int i = 0; i < 4; ++i) {
            int mb = m0 + wm + i * 16 + rm;
            float vv[4];
            #pragma unroll
            for (int r = 0; r < 4; ++r) {
                float v = acc[i][j][r] + bv;
                if (EPI == 1) v = gelu_exact(v);
                else if (EPI == 2) v = fmaxf(v, 0.f);
                else if (EPI == 3) v = 1.f / (1.f + expf(-v));
                vv[r] = v;
            }
            #pragma unroll
            for (int r = 0; r < 4; ++r) {
                int m = mb + r;
                if (m < M && n < Ncols) {
                    float v = vv[r];
                    if (HAS_RES) v += bf1f(Res[(size_t)m * Ncols + n]);
                    if (STORE == 0) ((float*)Cout)[(size_t)m * Ncols + n] = v;
                    else            ((u16*)Cout)[(size_t)m * Ncols + n] = f2bf(v);
                }
            }
        }
    }
}

// ---- attention core: 4x4 per (sample, head), bf16 in/out ------------------
__global__ __launch_bounds__(256) void k_attn(const u16* __restrict__ QKV,
        u16* __restrict__ AO)
{
    int t = threadIdx.x;
    int h = t >> 6, lane = t & 63;
    size_t n = (size_t)blockIdx.x;
    const u16* base = QKV + n * 4 * 1536 + h * 128 + lane * 2;
    float2 q[4], k[4], v[4];
    #pragma unroll
    for (int b = 0; b < 4; ++b) {
        q[b] = bf2f2(*(const u32*)(base + b * 1536));
        k[b] = bf2f2(*(const u32*)(base + b * 1536 + 512));
        v[b] = bf2f2(*(const u32*)(base + b * 1536 + 1024));
    }
    const float scale = 0.08838834764831845f;  // 128^-0.5
    float sc[4][4];
    #pragma unroll
    for (int qb = 0; qb < 4; ++qb)
        #pragma unroll
        for (int kb = 0; kb < 4; ++kb) {
            float p = q[qb].x * k[kb].x + q[qb].y * k[kb].y;
            sc[qb][kb] = wave_sum(p) * scale;
        }
    #pragma unroll
    for (int qb = 0; qb < 4; ++qb) {
        float mx = fmaxf(fmaxf(sc[qb][0], sc[qb][1]), fmaxf(sc[qb][2], sc[qb][3]));
        float e0 = expf(sc[qb][0] - mx), e1 = expf(sc[qb][1] - mx);
        float e2 = expf(sc[qb][2] - mx), e3 = expf(sc[qb][3] - mx);
        float inv = 1.f / (e0 + e1 + e2 + e3);
        float ox = (e0 * v[0].x + e1 * v[1].x + e2 * v[2].x + e3 * v[3].x) * inv;
        float oy = (e0 * v[0].y + e1 * v[1].y + e2 * v[2].y + e3 * v[3].y) * inv;
        *(u32*)(AO + (n * 4 + qb) * 512 + h * 128 + lane * 2) = pack2(ox, oy);
    }
}

// ---- SE scale + GroupNorm + GELU + alpha-fuse -> FU bf16 ------------------
__global__ __launch_bounds__(256) void k_gnfin_fuse(
        const u16* __restrict__ XP, const u16* __restrict__ SIG,
        const float* __restrict__ gnw, const float* __restrict__ gnb,
        const u16* __restrict__ X2, const u16* __restrict__ X3,
        const float* __restrict__ alpha, int baseN, u16* __restrict__ FU)
{
    __shared__ float red[8];
    size_t ls = blockIdx.x;
    int t = threadIdx.x;
    int wave = t >> 6, lane = t & 63;
    int f = t * 2;
    const u16* p = XP + ls * 2048;
    float2 sg = bf2f2(*(const u32*)(SIG + ls * 512 + f));
    float2 xr[4];
    #pragma unroll
    for (int b = 0; b < 4; ++b) {
        float2 x = bf2f2(*(const u32*)(p + b * 512 + f));
        xr[b] = make_float2(x.x * sg.x, x.y * sg.y);
    }
    float s = 0.f;
    #pragma unroll
    for (int b = 0; b < 4; ++b) s += xr[b].x + xr[b].y;
    s = wave_sum(s);
    if (lane == 0) red[wave] = s;
    __syncthreads();
    float m = (red[0] + red[1] + red[2] + red[3]) * (1.f / 2048.f);
    float q = 0.f;
    #pragma unroll
    for (int b = 0; b < 4; ++b) {
        float dx = xr[b].x - m, dy = xr[b].y - m;
        q += dx * dx + dy * dy;
    }
    q = wave_sum(q);
    if (lane == 0) red[4 + wave] = q;
    __syncthreads();
    float rs = rsqrtf((red[4] + red[5] + red[6] + red[7]) * (1.f / 2048.f) + EPSV);
    const float* a = alpha + (size_t)(baseN + ls) * 3;
    float a0 = a[0], a1 = a[1], a2 = a[2];
    float gw0 = gnw[f], gw1 = gnw[f + 1], gb0 = gnb[f], gb1 = gnb[f + 1];
    #pragma unroll
    for (int b = 0; b < 4; ++b) {
        float x1a = gelu_exact((xr[b].x - m) * rs * gw0 + gb0);
        float x1b = gelu_exact((xr[b].y - m) * rs * gw1 + gb1);
        float2 v2 = bf2f2(*(const u32*)(X2 + (ls * 4 + b) * 512 + f));
        float2 v3 = bf2f2(*(const u32*)(X3 + (ls * 4 + b) * 512 + f));
        *(u32*)(FU + (ls * 4 + b) * 512 + f) =
            pack2(a0 * x1a + a1 * v2.x + a2 * v3.x,
                  a0 * x1b + a1 * v2.y + a2 * v3.y);
    }
}

// ---- gate stage 2: logits (3x128 dot) + softmax -> alpha ------------------
__global__ __launch_bounds__(256) void k_gate2(const u16* __restrict__ G1,
        const float* __restrict__ w2, const float* __restrict__ b2,
        float* __restrict__ alpha, int CH)
{
    int s = blockIdx.x * 256 + threadIdx.x;
    if (s >= CH) return;
    float l0 = b2[0], l1 = b2[1], l2 = b2[2];
    const u16* g = G1 + (size_t)s * 128;
    for (int j = 0; j < 128; j += 2) {
        float2 gg = bf2f2(*(const u32*)(g + j));
        l0 += gg.x * w2[j]       + gg.y * w2[j + 1];
        l1 += gg.x * w2[128 + j] + gg.y * w2[129 + j];
        l2 += gg.x * w2[256 + j] + gg.y * w2[257 + j];
    }
    float mx = fmaxf(l0, fmaxf(l1, l2));
    float e0 = expf(l0 - mx), e1 = expf(l1 - mx), e2 = expf(l2 - mx);
    float inv = 1.f / (e0 + e1 + e2);
    float* a = alpha + (size_t)s * 3;
    a[0] = e0 * inv; a[1] = e1 * inv; a[2] = e2 * inv;
}

// ---------------------------------------------------------------------------
extern "C" void kernel_launch(void* const* d_in, const int* in_sizes, int n_in,
                              void* d_out, int out_size, void* d_ws, size_t ws_size,
                              hipStream_t stream)
{
    (void)in_sizes; (void)n_in; (void)out_size;
    const float* br         = (const float*)d_in[0];
    const float* conv_pw_w  = (const float*)d_in[1];
    const float* conv_dw_w  = (const float*)d_in[2];
    const float* gn_w       = (const float*)d_in[3];
    const float* gn_b       = (const float*)d_in[4];
    const float* se_w1      = (const float*)d_in[5];
    const float* se_w2      = (const float*)d_in[6];
    const float* ln_attn_w  = (const float*)d_in[7];
    const float* ln_attn_b  = (const float*)d_in[8];
    const float* in_proj_w  = (const float*)d_in[9];
    const float* in_proj_b  = (const float*)d_in[10];
    const float* attn_out_w = (const float*)d_in[11];
    const float* attn_out_b = (const float*)d_in[12];
    const float* ln_ffn_w   = (const float*)d_in[13];
    const float* ln_ffn_b   = (const float*)d_in[14];
    const float* ffn_w1     = (const float*)d_in[15];
    const float* ffn_b1     = (const float*)d_in[16];
    const float* ffn_w2     = (const float*)d_in[17];
    const float* ffn_b2     = (const float*)d_in[18];
    const float* mlp_ln_w   = (const float*)d_in[19];
    const float* mlp_ln_b   = (const float*)d_in[20];
    const float* mlp_w1     = (const float*)d_in[21];
    const float* mlp_b1     = (const float*)d_in[22];
    const float* mlp_w2     = (const float*)d_in[23];
    const float* mlp_b2     = (const float*)d_in[24];
    const float* gate_w1    = (const float*)d_in[25];
    const float* gate_b1    = (const float*)d_in[26];
    const float* gate_w2    = (const float*)d_in[27];
    const float* gate_b2    = (const float*)d_in[28];
    const float* outp_w     = (const float*)d_in[29];
    float* out = (float*)d_out;

    char* ws = (char*)d_ws;
    float* alpha = (float*)ws;                       // N_TOT*3 fp32 = 196608 B
    u16* Wb = (u16*)(ws + 196608);                   // W_TOT bf16
    const size_t CB = 196608 + (size_t)W_TOT * 2;    // 7929856
    int CH = N_TOT;
    while (CH > 64 && CB + (size_t)CH * 31104ULL > ws_size) CH >>= 1;

    // ws buffers (31104 B/sample)
    char* p = ws + CB;
    u16* Tb   = (u16*)p; p += (size_t)CH * 4096;
    char* CTXS = p;      p += (size_t)CH * 2048;     // CTX; later S + SIGb
    u16* LNA  = (u16*)p; p += (size_t)CH * 4096;     // aliased as LNF
    u16* LNM  = (u16*)p; p += (size_t)CH * 4096;     // aliased as FU
    u16* QKV  = (u16*)p; p += (size_t)CH * 12288;    // aliased as U
    u16* AOXP = (u16*)p; p += (size_t)CH * 4096;     // AO then XP
    u16* H1   = (u16*)p; p += (size_t)CH * 128;
    u16* G1   = (u16*)p; p += (size_t)CH * 256;
    u16* CTX  = (u16*)CTXS;
    u16* S    = (u16*)CTXS;                          // CH x 512 (first half)
    u16* SIGb = (u16*)(CTXS + (size_t)CH * 1024);    // CH x 512 (second half)
    u16* U    = QKV;
    u16* LNF  = LNA;
    u16* FU   = LNM;

    // d_out as scratch: first half X2, second half T2/X3 (dead before out-proj)
    u16* O16 = (u16*)d_out;

    k_w2b<<<(W_TOT + 255) / 256, 256, 0, stream>>>(
        conv_pw_w, in_proj_w, attn_out_w, ffn_w1, ffn_w2, mlp_w1, mlp_w2,
        gate_w1, se_w1, se_w2, outp_w, Wb);

    const int Ri = CH * 4;
    auto g128 = [](int M, int Nc) { return dim3((Nc + 127) / 128, (M + 127) / 128); };
    auto g256 = [](int M, int Nc) { return dim3((M / 256) * (Nc / 256)); };

    for (int c0 = 0; c0 < N_TOT; c0 += CH) {
        u16* X2b  = O16 + (size_t)c0 * 2048;                         // chunk-local rows
        u16* T2X3 = O16 + (size_t)N_TOT * 2048 + (size_t)c0 * 2048;  // T2 then X3

        k_prep_ln<<<CH / 4, 256, 0, stream>>>(br, c0, Tb, CTX,
                                              ln_attn_w, ln_attn_b, LNA,
                                              mlp_ln_w, mlp_ln_b, LNM);
        // gate
        k_mfma_gemm<1, true, false, 1><<<g128(CH, 128), 256, 0, stream>>>(
            CTX, Wb + W_GATE1, gate_b1, nullptr, G1, CH, 128, 1024, 0);
        k_gate2<<<(CH + 255) / 256, 256, 0, stream>>>(G1, gate_w2, gate_b2,
                                                      alpha + (size_t)c0 * 3, CH);
        // attention expert
        k_gemm256<0, true, false, 1><<<g256(Ri, 1536), 512, 0, stream>>>(
            LNA, Wb + W_INPROJ, in_proj_b, nullptr, QKV, 1536, 512, 0, 6, nullptr, nullptr);
        k_attn<<<CH, 256, 0, stream>>>(QKV, AOXP);
        k_gemm256<0, true, true, 1><<<g256(Ri, 512), 512, 0, stream>>>(
            AOXP, Wb + W_ATTNO, attn_out_b, Tb, T2X3, 512, 512, 0, 2, nullptr, nullptr);
        k_ln_b<<<Ri / 4, 256, 0, stream>>>(T2X3, ln_ffn_w, ln_ffn_b, LNF);
        k_gemm256<1, true, false, 1><<<g256(Ri, 1024), 512, 0, stream>>>(
            LNF, Wb + W_FFN1, ffn_b1, nullptr, U, 1024, 512, 0, 4, nullptr, nullptr);
        k_gemm256<0, true, true, 1><<<g256(Ri, 512), 512, 0, stream>>>(
            U, Wb + W_FFN2, ffn_b2, T2X3, X2b, 512, 1024, 0, 2, nullptr, nullptr);
        // MLP expert (X3 overwrites T2 — T2 dead after ffn2)
        k_gemm256<1, true, false, 1><<<g256(Ri, 1024), 512, 0, stream>>>(
            LNM, Wb + W_MLP1, mlp_b1, nullptr, U, 1024, 512, 0, 4, nullptr, nullptr);
        k_gemm256<0, true, true, 1><<<g256(Ri, 512), 512, 0, stream>>>(
            U, Wb + W_MLP2, mlp_b2, Tb, T2X3, 512, 1024, 0, 2, nullptr, nullptr);
        // conv expert: pw GEMM + fused depthwise + SE squeeze
        k_gemm256<0, false, false, 3><<<g256(Ri, 512), 512, 0, stream>>>(
            Tb, Wb + W_CONVPW, nullptr, nullptr, AOXP, 512, 512, 0, 2, conv_dw_w, S);
        k_mfma_gemm<2, false, false, 1><<<g128(CH, 64), 256, 0, stream>>>(
            S, Wb + W_SE1, nullptr, nullptr, H1, CH, 64, 512, 0);
        k_mfma_gemm<3, false, false, 1><<<g128(CH, 512), 256, 0, stream>>>(
            H1, Wb + W_SE2, nullptr, nullptr, SIGb, CH, 512, 64, 0);
        // GN + gelu + alpha-fuse
        k_gnfin_fuse<<<CH, 256, 0, stream>>>(AOXP, SIGb, gn_w, gn_b,
                                             X2b, T2X3, alpha, c0, FU);
        // output projection, float4 scatter to (n, o, b)
        k_gemm256<0, false, false, 2><<<g256(Ri, 512), 512, 0, stream>>>(
            FU, Wb + W_OUTP, nullptr, nullptr, out, 512, 512, c0, 2, nullptr, nullptr);
    }
}

// Round 11
// 1089.419 us; speedup vs baseline: 4.3677x; 4.3677x over previous
//
#include <hip/hip_runtime.h>
#include <math.h>

// ---------------------------------------------------------------------------
// ParallelExpertsMixer — Round 11: R10 structure (BK=32, 64 KiB LDS, R5's
// 4-phase schedule) with the launch-bounds VGPR cap fixed: (512,4)->(512,2).
// R10's 4758us was pure spill (VGPR capped to 64); structure was correct.
// ---------------------------------------------------------------------------

#define N_TOT 16384
#define EPSV 1e-5f

typedef unsigned short u16;
typedef unsigned int   u32;
typedef __attribute__((ext_vector_type(8))) short  short8;
typedef __attribute__((ext_vector_type(4))) float  floatx4;

__device__ __forceinline__ float gelu_exact(float x) {
    return 0.5f * x * (1.0f + erff(x * 0.70710678118654752440f));
}
__device__ __forceinline__ float wave_sum(float v) {
    #pragma unroll
    for (int o = 32; o > 0; o >>= 1) v += __shfl_xor(v, o);
    return v;
}
__device__ __forceinline__ u16 f2bf(float f) {
    u32 u = __float_as_uint(f);
    return (u16)((u + 0x7fffu + ((u >> 16) & 1u)) >> 16);
}
__device__ __forceinline__ u32 pack2(float lo, float hi) {
    return (u32)f2bf(lo) | ((u32)f2bf(hi) << 16);
}
__device__ __forceinline__ float bf1f(u16 u) { return __uint_as_float((u32)u << 16); }
__device__ __forceinline__ float2 bf2f2(u32 u) {
    return make_float2(__uint_as_float(u << 16), __uint_as_float(u & 0xffff0000u));
}
__device__ __forceinline__ void gload_lds16(const void* g, void* l) {
    __builtin_amdgcn_global_load_lds(
        (const __attribute__((address_space(1))) unsigned int*)g,
        (__attribute__((address_space(3))) unsigned int*)l, 16, 0, 0);
}

#define BARR() asm volatile("s_barrier" ::: "memory")
#define VMW(N) asm volatile("s_waitcnt vmcnt(" #N ")" ::: "memory")

// ---- bf16 weight conversion (once per launch) -----------------------------
#define W_CONVPW 0
#define W_INPROJ 262144
#define W_ATTNO  1048576
#define W_FFN1   1310720
#define W_FFN2   1835008
#define W_MLP1   2359296
#define W_MLP2   2883584
#define W_GATE1  3407872
#define W_SE1    3538944
#define W_SE2    3571712
#define W_OUTP   3604480
#define W_TOT    3866624

__global__ __launch_bounds__(256) void k_w2b(
        const float* __restrict__ p0, const float* __restrict__ p1,
        const float* __restrict__ p2, const float* __restrict__ p3,
        const float* __restrict__ p4, const float* __restrict__ p5,
        const float* __restrict__ p6, const float* __restrict__ p7,
        const float* __restrict__ p8, const float* __restrict__ p9,
        const float* __restrict__ p10, u16* __restrict__ dst)
{
    int i = blockIdx.x * 256 + threadIdx.x;
    if (i >= W_TOT) return;
    const float* s; int off;
    if      (i < W_INPROJ) { s = p0;  off = W_CONVPW; }
    else if (i < W_ATTNO)  { s = p1;  off = W_INPROJ; }
    else if (i < W_FFN1)   { s = p2;  off = W_ATTNO; }
    else if (i < W_FFN2)   { s = p3;  off = W_FFN1; }
    else if (i < W_MLP1)   { s = p4;  off = W_FFN2; }
    else if (i < W_MLP2)   { s = p5;  off = W_MLP1; }
    else if (i < W_GATE1)  { s = p6;  off = W_MLP2; }
    else if (i < W_SE1)    { s = p7;  off = W_GATE1; }
    else if (i < W_SE2)    { s = p8;  off = W_SE1; }
    else if (i < W_OUTP)   { s = p9;  off = W_SE2; }
    else                   { s = p10; off = W_OUTP; }
    dst[i] = f2bf(s[i - off]);
}

// ---- prep (4 samples/block): branches -> Tb + CTX + both LayerNorms -------
__global__ __launch_bounds__(256) void k_prep_ln(const float* __restrict__ br,
        int baseN, u16* __restrict__ Tb, u16* __restrict__ CTX,
        const float* __restrict__ law, const float* __restrict__ lab, u16* __restrict__ LNA,
        const float* __restrict__ lmw, const float* __restrict__ lmb, u16* __restrict__ LNM)
{
    __shared__ float lds[4][4][516];
    int t = threadIdx.x;
    int s0 = blockIdx.x * 4;
    #pragma unroll
    for (int s = 0; s < 4; ++s) {
        const float* p = br + (size_t)(baseN + s0 + s) * 2048;
        u16* c = CTX + (size_t)(s0 + s) * 1024;
        #pragma unroll
        for (int i = 0; i < 2; ++i) {
            int f = t + i * 256;
            float4 v = *(const float4*)(p + f * 4);
            lds[s][0][f] = v.x; lds[s][1][f] = v.y; lds[s][2][f] = v.z; lds[s][3][f] = v.w;
            c[f]       = f2bf((v.x + v.y + v.z + v.w) * 0.25f);
            c[512 + f] = f2bf(fmaxf(fmaxf(v.x, v.y), fmaxf(v.z, v.w)));
        }
    }
    __syncthreads();
    int wv = t >> 6, lane = t & 63, f0 = lane * 8;
    #pragma unroll
    for (int p4i = 0; p4i < 4; ++p4i) {
        int idx = wv * 4 + p4i;
        int s = idx >> 2, b = idx & 3;
        float xv[8];
        #pragma unroll
        for (int i = 0; i < 8; ++i) xv[i] = lds[s][b][f0 + i];
        float sm = 0.f;
        #pragma unroll
        for (int i = 0; i < 8; ++i) sm += xv[i];
        sm = wave_sum(sm);
        float m = sm * (1.f / 512.f);
        float q = 0.f;
        #pragma unroll
        for (int i = 0; i < 8; ++i) { float d = xv[i] - m; q += d * d; }
        q = wave_sum(q);
        float rs = rsqrtf(q * (1.f / 512.f) + EPSV);
        size_t row = (size_t)(s0 + s) * 4 + b;
        *(uint4*)(Tb + row * 512 + f0) = make_uint4(pack2(xv[0], xv[1]), pack2(xv[2], xv[3]),
                                                    pack2(xv[4], xv[5]), pack2(xv[6], xv[7]));
        float o[8];
        #pragma unroll
        for (int i = 0; i < 8; ++i) o[i] = (xv[i] - m) * rs * law[f0 + i] + lab[f0 + i];
        *(uint4*)(LNA + row * 512 + f0) = make_uint4(pack2(o[0], o[1]), pack2(o[2], o[3]),
                                                     pack2(o[4], o[5]), pack2(o[6], o[7]));
        #pragma unroll
        for (int i = 0; i < 8; ++i) o[i] = (xv[i] - m) * rs * lmw[f0 + i] + lmb[f0 + i];
        *(uint4*)(LNM + row * 512 + f0) = make_uint4(pack2(o[0], o[1]), pack2(o[2], o[3]),
                                                     pack2(o[4], o[5]), pack2(o[6], o[7]));
    }
}

// ---- LayerNorm over 512, bf16 in -> bf16 out ------------------------------
__global__ __launch_bounds__(256) void k_ln_b(const u16* __restrict__ X,
        const float* __restrict__ w, const float* __restrict__ b, u16* __restrict__ O)
{
    int t = threadIdx.x;
    int wave = t >> 6, lane = t & 63;
    size_t r = (size_t)blockIdx.x * 4 + wave;
    int f0 = lane * 8;
    uint4 raw = *(const uint4*)(X + r * 512 + f0);
    float xv[8];
    { float2 a = bf2f2(raw.x); xv[0] = a.x; xv[1] = a.y; }
    { float2 a = bf2f2(raw.y); xv[2] = a.x; xv[3] = a.y; }
    { float2 a = bf2f2(raw.z); xv[4] = a.x; xv[5] = a.y; }
    { float2 a = bf2f2(raw.w); xv[6] = a.x; xv[7] = a.y; }
    float s = 0.f;
    #pragma unroll
    for (int i = 0; i < 8; ++i) s += xv[i];
    s = wave_sum(s);
    float m = s * (1.f / 512.f);
    float q = 0.f;
    #pragma unroll
    for (int i = 0; i < 8; ++i) { float d = xv[i] - m; q += d * d; }
    q = wave_sum(q);
    float rs = rsqrtf(q * (1.f / 512.f) + EPSV);
    float o[8];
    #pragma unroll
    for (int i = 0; i < 8; ++i) o[i] = (xv[i] - m) * rs * w[f0 + i] + b[f0 + i];
    *(uint4*)(O + r * 512 + f0) = make_uint4(pack2(o[0], o[1]), pack2(o[2], o[3]),
                                             pack2(o[4], o[5]), pack2(o[6], o[7]));
}

// ===========================================================================
// 256x256 GEMM, BK=32, 4 phases/K-tile (R5 schedule, halved). 512 thr / 8
// waves; per-wave 64x32 piece of EACH 128x128 C-quadrant. LDS: 2 buf x
// [A0|A1|B0|B1] x 8KB = 64 KiB -> 2 blocks/CU at <=128 VGPR. Each half =
// 128 rows x 32 elems (64B rows, granule-XOR (r>>1)&3 -> conflict-free).
// Stage order/tile: A0,B0,A1,B1 (1 load/thread each). Steady VMW(2),(2),(2),-;
// drain (2),(1),(0),-. Requires M%256==0, N%256==0, K%32==0, K>=64.
// STORE: 1 bf16 (+opt residual), 2 f4-scatter(out), 3 dw-conv+squeeze.
// ===========================================================================

#define STG_A(MH, TILE) do {                                                  \
    int E_ = tid * 8;                                                         \
    int r_ = E_ >> 5;                                                         \
    int g_ = (tid & 3) ^ ((r_ >> 1) & 3);                                     \
    gload_lds16(A + (size_t)(m0 + (MH) * 128 + r_) * K + (TILE) * 32 + g_ * 8,\
                lds + (((TILE) & 1) * 16384) + (MH) * 4096 + E_);             \
} while (0)

#define STG_B(NH, TILE) do {                                                  \
    int E_ = tid * 8;                                                         \
    int r_ = E_ >> 5;                                                         \
    int g_ = (tid & 3) ^ ((r_ >> 1) & 3);                                     \
    gload_lds16(W + (size_t)(n0 + (NH) * 128 + r_) * K + (TILE) * 32 + g_ * 8,\
                lds + (((TILE) & 1) * 16384) + 8192 + (NH) * 4096 + E_);      \
} while (0)

#define QUAD(MH, NH, STAGESTMT) do {                                          \
    const u16* lb_ = lds + cur * 16384;                                       \
    short8 a_[4], b_[2];                                                      \
    _Pragma("unroll")                                                         \
    for (int mi = 0; mi < 4; ++mi)                                            \
        a_[mi] = *(const short8*)(lb_ + (MH) * 4096 + aoff[mi]);              \
    _Pragma("unroll")                                                         \
    for (int ni = 0; ni < 2; ++ni)                                            \
        b_[ni] = *(const short8*)(lb_ + 8192 + (NH) * 4096 + boff[ni]);       \
    STAGESTMT;                                                                \
    BARR();                                                                   \
    __builtin_amdgcn_s_setprio(1);                                            \
    _Pragma("unroll")                                                         \
    for (int mi = 0; mi < 4; ++mi)                                            \
        _Pragma("unroll")                                                     \
        for (int ni = 0; ni < 2; ++ni)                                        \
            acc[MH][NH][mi][ni] = __builtin_amdgcn_mfma_f32_16x16x32_bf16(    \
                a_[mi], b_[ni], acc[MH][NH][mi][ni], 0, 0, 0);                \
    __builtin_amdgcn_s_setprio(0);                                            \
} while (0)

template<int EPI, bool HAS_BIAS, bool HAS_RES, int STORE>
__global__ __launch_bounds__(512, 2) void k_gemm256(
        const u16* __restrict__ A, const u16* __restrict__ W,
        const float* __restrict__ bias, const u16* __restrict__ Res,
        void* __restrict__ Cout, int Ncols, int K, int baseN, int nTX,
        const float* __restrict__ dwp, u16* __restrict__ Sout)
{
    __shared__ __align__(16) u16 lds[32768];   // 64 KiB -> 2 blocks/CU
    const int tid = threadIdx.x;
    const int wid = tid >> 6, lane = tid & 63;
    const int lr = lane & 15, kg = lane >> 4;
    const int wm = (wid >> 2) * 64;    // M offset within each M-half
    const int wn = (wid & 3) * 32;     // N offset within each N-half

    // bijective XCD swizzle (m204)
    int nwg = gridDim.x, orig = blockIdx.x;
    int q = nwg >> 3, r = nwg & 7;
    int xcd = orig & 7, lin = orig >> 3;
    int wgid = (xcd < r ? xcd * (q + 1) : r * (q + 1) + (xcd - r) * q) + lin;
    const int m0 = (wgid / nTX) * 256, n0 = (wgid % nTX) * 256;

    // fragment LDS element offsets within one half-region (128 rows x 32 elems)
    int aoff[4], boff[2];
    #pragma unroll
    for (int mi = 0; mi < 4; ++mi) {
        int R = wm + mi * 16 + lr;                 // 0..127
        aoff[mi] = R * 32 + ((kg ^ ((R >> 1) & 3)) * 8);
    }
    #pragma unroll
    for (int ni = 0; ni < 2; ++ni) {
        int R = wn + ni * 16 + lr;                 // 0..127
        boff[ni] = R * 32 + ((kg ^ ((R >> 1) & 3)) * 8);
    }

    floatx4 acc[2][2][4][2] = {};

    // prologue: stage K-tile 0 in consumption order (4 loads outstanding)
    STG_A(0, 0); STG_B(0, 0); STG_A(1, 0); STG_B(1, 0);

    const int NT = K >> 5;
    int cur = 0;
    for (int t = 0; t < NT - 1; ++t) {
        int nx = t + 1;
        VMW(2); BARR(); QUAD(0, 0, STG_A(0, nx));
        VMW(2); BARR(); QUAD(1, 0, STG_B(0, nx));
        VMW(2); BARR(); QUAD(0, 1, STG_A(1, nx));
                BARR(); QUAD(1, 1, STG_B(1, nx));
        cur ^= 1;
    }
    // last K-tile: counted drain
    VMW(2); BARR(); QUAD(0, 0, (void)0);
    VMW(1); BARR(); QUAD(1, 0, (void)0);
    VMW(0); BARR(); QUAD(0, 1, (void)0);
            BARR(); QUAD(1, 1, (void)0);

    // epilogue: D col = lane&15 (n), row = kg*4 + reg (m)
    int rm = kg * 4;
    #pragma unroll
    for (int MH = 0; MH < 2; ++MH)
    #pragma unroll
    for (int NH = 0; NH < 2; ++NH)
    #pragma unroll
    for (int ni = 0; ni < 2; ++ni) {
        int n = n0 + NH * 128 + wn + ni * 16 + lr;
        float bv = HAS_BIAS ? bias[n] : 0.f;
        float w0, w1, w2;
        if (STORE == 3) { w0 = dwp[n * 3]; w1 = dwp[n * 3 + 1]; w2 = dwp[n * 3 + 2]; }
        #pragma unroll
        for (int mi = 0; mi < 4; ++mi) {
            int mb = m0 + MH * 128 + wm + mi * 16 + rm;
            float vv[4];
            #pragma unroll
            for (int rr = 0; rr < 4; ++rr) {
                float v = acc[MH][NH][mi][ni][rr] + bv;
                if (EPI == 1) v = gelu_exact(v);
                else if (EPI == 2) v = fmaxf(v, 0.f);
                else if (EPI == 3) v = 1.f / (1.f + expf(-v));
                vv[rr] = v;
            }
            if (STORE == 2) {
                *(float4*)((float*)Cout + (size_t)(baseN + (mb >> 2)) * 2048 + (size_t)n * 4)
                    = make_float4(vv[0], vv[1], vv[2], vv[3]);
            } else if (STORE == 3) {
                // depthwise k=3 over tokens (rows mb..mb+3 = one sample) + squeeze
                float y0 = w1 * vv[0] + w2 * vv[1];
                float y1 = w0 * vv[0] + w1 * vv[1] + w2 * vv[2];
                float y2 = w0 * vv[1] + w1 * vv[2] + w2 * vv[3];
                float y3 = w0 * vv[2] + w1 * vv[3];
                u16* xp = (u16*)Cout + (size_t)mb * Ncols + n;
                xp[0] = f2bf(y0);
                xp[Ncols] = f2bf(y1);
                xp[2 * Ncols] = f2bf(y2);
                xp[3 * Ncols] = f2bf(y3);
                Sout[(size_t)(mb >> 2) * Ncols + n] = f2bf((y0 + y1 + y2 + y3) * 0.25f);
            } else {
                #pragma unroll
                for (int rr = 0; rr < 4; ++rr) {
                    float v = vv[rr];
                    if (HAS_RES) v += bf1f(Res[(size_t)(mb + rr) * Ncols + n]);
                    ((u16*)Cout)[(size_t)(mb + rr) * Ncols + n] = f2bf(v);
                }
            }
        }
    }
}

// ---- 128^2 MFMA GEMM (small shapes: gate1, se1, se2) ----------------------
template<int EPI, bool HAS_BIAS, bool HAS_RES, int STORE>
__global__ __launch_bounds__(256) void k_mfma_gemm(
        const u16* __restrict__ A, const u16* __restrict__ W,
        const float* __restrict__ bias, const u16* __restrict__ Res,
        void* __restrict__ Cout, int M, int Ncols, int K, int baseN)
{
    __shared__ u16 As[128 * 32];
    __shared__ u16 Bs[128 * 32];
    int t = threadIdx.x;
    int wid = t >> 6, lane = t & 63;
    int wm = (wid >> 1) * 64, wn = (wid & 1) * 64;
    int m0 = blockIdx.y * 128, n0 = blockIdx.x * 128;
    int srow = t >> 2;
    int scol = (((t & 3) ^ ((srow >> 1) & 3)) * 8);
    int aR0 = min(m0 + srow, M - 1),      aR1 = min(m0 + 64 + srow, M - 1);
    int bR0 = min(n0 + srow, Ncols - 1),  bR1 = min(n0 + 64 + srow, Ncols - 1);
    const u16* Ap0 = A + (size_t)aR0 * K + scol;
    const u16* Ap1 = A + (size_t)aR1 * K + scol;
    const u16* Wp0 = W + (size_t)bR0 * K + scol;
    const u16* Wp1 = W + (size_t)bR1 * K + scol;
    u16* AsT0 = As + t * 8;  u16* AsT1 = As + 2048 + t * 8;
    u16* BsT0 = Bs + t * 8;  u16* BsT1 = Bs + 2048 + t * 8;

    int kg = lane >> 4, lr = lane & 15;
    int cb = kg ^ ((lr >> 1) & 3);
    const u16* aF = As + (wm + lr) * 32 + cb * 8;
    const u16* bF = Bs + (wn + lr) * 32 + cb * 8;

    floatx4 acc[4][4] = {};
    for (int k0 = 0; k0 < K; k0 += 32) {
        __syncthreads();
        gload_lds16(Ap0 + k0, AsT0);
        gload_lds16(Ap1 + k0, AsT1);
        gload_lds16(Wp0 + k0, BsT0);
        gload_lds16(Wp1 + k0, BsT1);
        __syncthreads();
        short8 a[4], b[4];
        #pragma unroll
        for (int i = 0; i < 4; ++i) {
            a[i] = *(const short8*)(aF + i * 512);
            b[i] = *(const short8*)(bF + i * 512);
        }
        #pragma unroll
        for (int i = 0; i < 4; ++i)
            #pragma unroll
            for (int j = 0; j < 4; ++j)
                acc[i][j] = __builtin_amdgcn_mfma_f32_16x16x32_bf16(a[i], b[j], acc[i][j], 0, 0, 0);
    }
    int rm = (lane >> 4) * 4;
    #pragma unroll
    for (int j = 0; j < 4; ++j) {
        int n = n0 + wn + j * 16 + lr;
        float bv = HAS_BIAS ? bias[min(n, Ncols - 1)] : 0.f;
        #pragma unroll
        for (int i = 0; i < 4; ++i) {
            int mb = m0 + wm + i * 16 + rm;
            float vv[4];
            #pragma unroll
            for (int r = 0; r < 4; ++r) {
                float v = acc[i][j][r] + bv;
                if (EPI == 1) v = gelu_exact(v);
                else if (EPI == 2) v = fmaxf(v, 0.f);
                else if (EPI == 3) v = 1.f / (1.f + expf(-v));
                vv[r] = v;
            }
            #pragma unroll
            for (int r = 0; r < 4; ++r) {
                int m = mb + r;
                if (m < M && n < Ncols) {
                    float v = vv[r];
                    if (HAS_RES) v += bf1f(Res[(size_t)m * Ncols + n]);
                    if (STORE == 0) ((float*)Cout)[(size_t)m * Ncols + n] = v;
                    else            ((u16*)Cout)[(size_t)m * Ncols + n] = f2bf(v);
                }
            }
        }
    }
}

// ---- attention core: 4x4 per (sample, head), bf16 in/out ------------------
__global__ __launch_bounds__(256) void k_attn(const u16* __restrict__ QKV,
        u16* __restrict__ AO)
{
    int t = threadIdx.x;
    int h = t >> 6, lane = t & 63;
    size_t n = (size_t)blockIdx.x;
    const u16* base = QKV + n * 4 * 1536 + h * 128 + lane * 2;
    float2 q[4], k[4], v[4];
    #pragma unroll
    for (int b = 0; b < 4; ++b) {
        q[b] = bf2f2(*(const u32*)(base + b * 1536));
        k[b] = bf2f2(*(const u32*)(base + b * 1536 + 512));
        v[b] = bf2f2(*(const u32*)(base + b * 1536 + 1024));
    }
    const float scale = 0.08838834764831845f;  // 128^-0.5
    float sc[4][4];
    #pragma unroll
    for (int qb = 0; qb < 4; ++qb)
        #pragma unroll
        for (int kb = 0; kb < 4; ++kb) {
            float p = q[qb].x * k[kb].x + q[qb].y * k[kb].y;
            sc[qb][kb] = wave_sum(p) * scale;
        }
    #pragma unroll
    for (int qb = 0; qb < 4; ++qb) {
        float mx = fmaxf(fmaxf(sc[qb][0], sc[qb][1]), fmaxf(sc[qb][2], sc[qb][3]));
        float e0 = expf(sc[qb][0] - mx), e1 = expf(sc[qb][1] - mx);
        float e2 = expf(sc[qb][2] - mx), e3 = expf(sc[qb][3] - mx);
        float inv = 1.f / (e0 + e1 + e2 + e3);
        float ox = (e0 * v[0].x + e1 * v[1].x + e2 * v[2].x + e3 * v[3].x) * inv;
        float oy = (e0 * v[0].y + e1 * v[1].y + e2 * v[2].y + e3 * v[3].y) * inv;
        *(u32*)(AO + (n * 4 + qb) * 512 + h * 128 + lane * 2) = pack2(ox, oy);
    }
}

// ---- SE scale + GroupNorm + GELU + alpha-fuse -> FU bf16 ------------------
__global__ __launch_bounds__(256) void k_gnfin_fuse(
        const u16* __restrict__ XP, const u16* __restrict__ SIG,
        const float* __restrict__ gnw, const float* __restrict__ gnb,
        const u16* __restrict__ X2, const u16* __restrict__ X3,
        const float* __restrict__ alpha, int baseN, u16* __restrict__ FU)
{
    __shared__ float red[8];
    size_t ls = blockIdx.x;
    int t = threadIdx.x;
    int wave = t >> 6, lane = t & 63;
    int f = t * 2;
    const u16* p = XP + ls * 2048;
    float2 sg = bf2f2(*(const u32*)(SIG + ls * 512 + f));
    float2 xr[4];
    #pragma unroll
    for (int b = 0; b < 4; ++b) {
        float2 x = bf2f2(*(const u32*)(p + b * 512 + f));
        xr[b] = make_float2(x.x * sg.x, x.y * sg.y);
    }
    float s = 0.f;
    #pragma unroll
    for (int b = 0; b < 4; ++b) s += xr[b].x + xr[b].y;
    s = wave_sum(s);
    if (lane == 0) red[wave] = s;
    __syncthreads();
    float m = (red[0] + red[1] + red[2] + red[3]) * (1.f / 2048.f);
    float q = 0.f;
    #pragma unroll
    for (int b = 0; b < 4; ++b) {
        float dx = xr[b].x - m, dy = xr[b].y - m;
        q += dx * dx + dy * dy;
    }
    q = wave_sum(q);
    if (lane == 0) red[4 + wave] = q;
    __syncthreads();
    float rs = rsqrtf((red[4] + red[5] + red[6] + red[7]) * (1.f / 2048.f) + EPSV);
    const float* a = alpha + (size_t)(baseN + ls) * 3;
    float a0 = a[0], a1 = a[1], a2 = a[2];
    float gw0 = gnw[f], gw1 = gnw[f + 1], gb0 = gnb[f], gb1 = gnb[f + 1];
    #pragma unroll
    for (int b = 0; b < 4; ++b) {
        float x1a = gelu_exact((xr[b].x - m) * rs * gw0 + gb0);
        float x1b = gelu_exact((xr[b].y - m) * rs * gw1 + gb1);
        float2 v2 = bf2f2(*(const u32*)(X2 + (ls * 4 + b) * 512 + f));
        float2 v3 = bf2f2(*(const u32*)(X3 + (ls * 4 + b) * 512 + f));
        *(u32*)(FU + (ls * 4 + b) * 512 + f) =
            pack2(a0 * x1a + a1 * v2.x + a2 * v3.x,
                  a0 * x1b + a1 * v2.y + a2 * v3.y);
    }
}

// ---- gate stage 2: logits (3x128 dot) + softmax -> alpha ------------------
__global__ __launch_bounds__(256) void k_gate2(const u16* __restrict__ G1,
        const float* __restrict__ w2, const float* __restrict__ b2,
        float* __restrict__ alpha, int CH)
{
    int s = blockIdx.x * 256 + threadIdx.x;
    if (s >= CH) return;
    float l0 = b2[0], l1 = b2[1], l2 = b2[2];
    const u16* g = G1 + (size_t)s * 128;
    for (int j = 0; j < 128; j += 2) {
        float2 gg = bf2f2(*(const u32*)(g + j));
        l0 += gg.x * w2[j]       + gg.y * w2[j + 1];
        l1 += gg.x * w2[128 + j] + gg.y * w2[129 + j];
        l2 += gg.x * w2[256 + j] + gg.y * w2[257 + j];
    }
    float mx = fmaxf(l0, fmaxf(l1, l2));
    float e0 = expf(l0 - mx), e1 = expf(l1 - mx), e2 = expf(l2 - mx);
    float inv = 1.f / (e0 + e1 + e2);
    float* a = alpha + (size_t)s * 3;
    a[0] = e0 * inv; a[1] = e1 * inv; a[2] = e2 * inv;
}

// ---------------------------------------------------------------------------
extern "C" void kernel_launch(void* const* d_in, const int* in_sizes, int n_in,
                              void* d_out, int out_size, void* d_ws, size_t ws_size,
                              hipStream_t stream)
{
    (void)in_sizes; (void)n_in; (void)out_size;
    const float* br         = (const float*)d_in[0];
    const float* conv_pw_w  = (const float*)d_in[1];
    const float* conv_dw_w  = (const float*)d_in[2];
    const float* gn_w       = (const float*)d_in[3];
    const float* gn_b       = (const float*)d_in[4];
    const float* se_w1      = (const float*)d_in[5];
    const float* se_w2      = (const float*)d_in[6];
    const float* ln_attn_w  = (const float*)d_in[7];
    const float* ln_attn_b  = (const float*)d_in[8];
    const float* in_proj_w  = (const float*)d_in[9];
    const float* in_proj_b  = (const float*)d_in[10];
    const float* attn_out_w = (const float*)d_in[11];
    const float* attn_out_b = (const float*)d_in[12];
    const float* ln_ffn_w   = (const float*)d_in[13];
    const float* ln_ffn_b   = (const float*)d_in[14];
    const float* ffn_w1     = (const float*)d_in[15];
    const float* ffn_b1     = (const float*)d_in[16];
    const float* ffn_w2     = (const float*)d_in[17];
    const float* ffn_b2     = (const float*)d_in[18];
    const float* mlp_ln_w   = (const float*)d_in[19];
    const float* mlp_ln_b   = (const float*)d_in[20];
    const float* mlp_w1     = (const float*)d_in[21];
    const float* mlp_b1     = (const float*)d_in[22];
    const float* mlp_w2     = (const float*)d_in[23];
    const float* mlp_b2     = (const float*)d_in[24];
    const float* gate_w1    = (const float*)d_in[25];
    const float* gate_b1    = (const float*)d_in[26];
    const float* gate_w2    = (const float*)d_in[27];
    const float* gate_b2    = (const float*)d_in[28];
    const float* outp_w     = (const float*)d_in[29];
    float* out = (float*)d_out;

    char* ws = (char*)d_ws;
    float* alpha = (float*)ws;                       // N_TOT*3 fp32 = 196608 B
    u16* Wb = (u16*)(ws + 196608);                   // W_TOT bf16
    const size_t CB = 196608 + (size_t)W_TOT * 2;    // 7929856
    int CH = N_TOT;
    while (CH > 64 && CB + (size_t)CH * 31104ULL > ws_size) CH >>= 1;

    // ws buffers (31104 B/sample)
    char* p = ws + CB;
    u16* Tb   = (u16*)p; p += (size_t)CH * 4096;
    char* CTXS = p;      p += (size_t)CH * 2048;     // CTX; later S + SIGb
    u16* LNA  = (u16*)p; p += (size_t)CH * 4096;     // aliased as LNF
    u16* LNM  = (u16*)p; p += (size_t)CH * 4096;     // aliased as FU
    u16* QKV  = (u16*)p; p += (size_t)CH * 12288;    // aliased as U
    u16* AOXP = (u16*)p; p += (size_t)CH * 4096;     // AO then XP
    u16* H1   = (u16*)p; p += (size_t)CH * 128;
    u16* G1   = (u16*)p; p += (size_t)CH * 256;
    u16* CTX  = (u16*)CTXS;
    u16* S    = (u16*)CTXS;                          // CH x 512 (first half)
    u16* SIGb = (u16*)(CTXS + (size_t)CH * 1024);    // CH x 512 (second half)
    u16* U    = QKV;
    u16* LNF  = LNA;
    u16* FU   = LNM;

    // d_out as scratch: first half X2, second half T2/X3 (dead before out-proj)
    u16* O16 = (u16*)d_out;

    k_w2b<<<(W_TOT + 255) / 256, 256, 0, stream>>>(
        conv_pw_w, in_proj_w, attn_out_w, ffn_w1, ffn_w2, mlp_w1, mlp_w2,
        gate_w1, se_w1, se_w2, outp_w, Wb);

    const int Ri = CH * 4;
    auto g128 = [](int M, int Nc) { return dim3((Nc + 127) / 128, (M + 127) / 128); };
    auto g256 = [](int M, int Nc) { return dim3((M / 256) * (Nc / 256)); };

    for (int c0 = 0; c0 < N_TOT; c0 += CH) {
        u16* X2b  = O16 + (size_t)c0 * 2048;                         // chunk-local rows
        u16* T2X3 = O16 + (size_t)N_TOT * 2048 + (size_t)c0 * 2048;  // T2 then X3

        k_prep_ln<<<CH / 4, 256, 0, stream>>>(br, c0, Tb, CTX,
                                              ln_attn_w, ln_attn_b, LNA,
                                              mlp_ln_w, mlp_ln_b, LNM);
        // gate
        k_mfma_gemm<1, true, false, 1><<<g128(CH, 128), 256, 0, stream>>>(
            CTX, Wb + W_GATE1, gate_b1, nullptr, G1, CH, 128, 1024, 0);
        k_gate2<<<(CH + 255) / 256, 256, 0, stream>>>(G1, gate_w2, gate_b2,
                                                      alpha + (size_t)c0 * 3, CH);
        // attention expert
        k_gemm256<0, true, false, 1><<<g256(Ri, 1536), 512, 0, stream>>>(
            LNA, Wb + W_INPROJ, in_proj_b, nullptr, QKV, 1536, 512, 0, 6, nullptr, nullptr);
        k_attn<<<CH, 256, 0, stream>>>(QKV, AOXP);
        k_gemm256<0, true, true, 1><<<g256(Ri, 512), 512, 0, stream>>>(
            AOXP, Wb + W_ATTNO, attn_out_b, Tb, T2X3, 512, 512, 0, 2, nullptr, nullptr);
        k_ln_b<<<Ri / 4, 256, 0, stream>>>(T2X3, ln_ffn_w, ln_ffn_b, LNF);
        k_gemm256<1, true, false, 1><<<g256(Ri, 1024), 512, 0, stream>>>(
            LNF, Wb + W_FFN1, ffn_b1, nullptr, U, 1024, 512, 0, 4, nullptr, nullptr);
        k_gemm256<0, true, true, 1><<<g256(Ri, 512), 512, 0, stream>>>(
            U, Wb + W_FFN2, ffn_b2, T2X3, X2b, 512, 1024, 0, 2, nullptr, nullptr);
        // MLP expert (X3 overwrites T2 — T2 dead after ffn2)
        k_gemm256<1, true, false, 1><<<g256(Ri, 1024), 512, 0, stream>>>(
            LNM, Wb + W_MLP1, mlp_b1, nullptr, U, 1024, 512, 0, 4, nullptr, nullptr);
        k_gemm256<0, true, true, 1><<<g256(Ri, 512), 512, 0, stream>>>(
            U, Wb + W_MLP2, mlp_b2, Tb, T2X3, 512, 1024, 0, 2, nullptr, nullptr);
        // conv expert: pw GEMM + fused depthwise + SE squeeze
        k_gemm256<0, false, false, 3><<<g256(Ri, 512), 512, 0, stream>>>(
            Tb, Wb + W_CONVPW, nullptr, nullptr, AOXP, 512, 512, 0, 2, conv_dw_w, S);
        k_mfma_gemm<2, false, false, 1><<<g128(CH, 64), 256, 0, stream>>>(
            S, Wb + W_SE1, nullptr, nullptr, H1, CH, 64, 512, 0);
        k_mfma_gemm<3, false, false, 1><<<g128(CH, 512), 256, 0, stream>>>(
            H1, Wb + W_SE2, nullptr, nullptr, SIGb, CH, 512, 64, 0);
        // GN + gelu + alpha-fuse
        k_gnfin_fuse<<<CH, 256, 0, stream>>>(AOXP, SIGb, gn_w, gn_b,
                                             X2b, T2X3, alpha, c0, FU);
        // output projection, float4 scatter to (n, o, b)
        k_gemm256<0, false, false, 2><<<g256(Ri, 512), 512, 0, stream>>>(
            FU, Wb + W_OUTP, nullptr, nullptr, out, 512, 512, c0, 2, nullptr, nullptr);
    }
}

// Round 12
// 1057.210 us; speedup vs baseline: 4.5008x; 1.0305x over previous
//
#include <hip/hip_runtime.h>
#include <math.h>

// ---------------------------------------------------------------------------
// ParallelExpertsMixer — Round 12: R7 pipeline (verified 1036us GEMM config,
// untouched main loop) + LayerNorm folded into weights for in_proj/ffn1/mlp1:
//   LN(x)@W^T|n = rs*(x.W'_n) - (rs*m)*s_n + c_n,  W'=lnw*W, s_n=sum(W'_n),
//   c_n = lnb.W_n + bias_n.  Removes LNA/LNM/LNF buffers (~200MB traffic).
// ---------------------------------------------------------------------------

#define N_TOT 16384
#define EPSV 1e-5f

typedef unsigned short u16;
typedef unsigned int   u32;
typedef __attribute__((ext_vector_type(8))) short  short8;
typedef __attribute__((ext_vector_type(4))) float  floatx4;

__device__ __forceinline__ float gelu_exact(float x) {
    return 0.5f * x * (1.0f + erff(x * 0.70710678118654752440f));
}
__device__ __forceinline__ float wave_sum(float v) {
    #pragma unroll
    for (int o = 32; o > 0; o >>= 1) v += __shfl_xor(v, o);
    return v;
}
__device__ __forceinline__ u16 f2bf(float f) {
    u32 u = __float_as_uint(f);
    return (u16)((u + 0x7fffu + ((u >> 16) & 1u)) >> 16);
}
__device__ __forceinline__ u32 pack2(float lo, float hi) {
    return (u32)f2bf(lo) | ((u32)f2bf(hi) << 16);
}
__device__ __forceinline__ float bf1f(u16 u) { return __uint_as_float((u32)u << 16); }
__device__ __forceinline__ float2 bf2f2(u32 u) {
    return make_float2(__uint_as_float(u << 16), __uint_as_float(u & 0xffff0000u));
}
__device__ __forceinline__ void gload_lds16(const void* g, void* l) {
    __builtin_amdgcn_global_load_lds(
        (const __attribute__((address_space(1))) unsigned int*)g,
        (__attribute__((address_space(3))) unsigned int*)l, 16, 0, 0);
}

#define BARR() asm volatile("s_barrier" ::: "memory")
#define VMW(N) asm volatile("s_waitcnt vmcnt(" #N ")" ::: "memory")

// ---- bf16 weight conversion (once per launch) -----------------------------
#define W_CONVPW 0
#define W_INPROJ 262144
#define W_ATTNO  1048576
#define W_FFN1   1310720
#define W_FFN2   1835008
#define W_MLP1   2359296
#define W_MLP2   2883584
#define W_GATE1  3407872
#define W_SE1    3538944
#define W_SE2    3571712
#define W_OUTP   3604480
#define W_TOT    3866624

__global__ __launch_bounds__(256) void k_w2b(
        const float* __restrict__ p0, const float* __restrict__ p1,
        const float* __restrict__ p2, const float* __restrict__ p3,
        const float* __restrict__ p4, const float* __restrict__ p5,
        const float* __restrict__ p6, const float* __restrict__ p7,
        const float* __restrict__ p8, const float* __restrict__ p9,
        const float* __restrict__ p10, u16* __restrict__ dst)
{
    int i = blockIdx.x * 256 + threadIdx.x;
    if (i >= W_TOT) return;
    const float* s; int off;
    if      (i < W_INPROJ) { s = p0;  off = W_CONVPW; }
    else if (i < W_ATTNO)  { s = p1;  off = W_INPROJ; }
    else if (i < W_FFN1)   { s = p2;  off = W_ATTNO; }
    else if (i < W_FFN2)   { s = p3;  off = W_FFN1; }
    else if (i < W_MLP1)   { s = p4;  off = W_FFN2; }
    else if (i < W_MLP2)   { s = p5;  off = W_MLP1; }
    else if (i < W_GATE1)  { s = p6;  off = W_MLP2; }
    else if (i < W_SE1)    { s = p7;  off = W_GATE1; }
    else if (i < W_SE2)    { s = p8;  off = W_SE1; }
    else if (i < W_OUTP)   { s = p9;  off = W_SE2; }
    else                   { s = p10; off = W_OUTP; }
    dst[i] = f2bf(s[i - off]);
}

// ---- fold LN into weights: W' = lnw*W (bf16), s_n = sum(W'_n),
//      c_n = lnb.W_n + bias_n.  One block per output row (3584 rows, K=512).
__global__ __launch_bounds__(256) void k_wfold(
        const float* __restrict__ wA, const float* __restrict__ lnwA,
        const float* __restrict__ lnbA, const float* __restrict__ biasA,
        const float* __restrict__ wF, const float* __restrict__ lnwF,
        const float* __restrict__ lnbF, const float* __restrict__ biasF,
        const float* __restrict__ wM, const float* __restrict__ lnwM,
        const float* __restrict__ lnbM, const float* __restrict__ biasM,
        u16* __restrict__ Wb,
        float* __restrict__ sA, float* __restrict__ cA,
        float* __restrict__ sF, float* __restrict__ cF,
        float* __restrict__ sM, float* __restrict__ cM)
{
    __shared__ float rs_[4], rc_[4];
    int r = blockIdx.x, t = threadIdx.x;
    const float *W, *lnw, *lnb, *bias;
    u16* dst; float *sp, *cp; int row;
    if (r < 1536)      { W = wA; lnw = lnwA; lnb = lnbA; bias = biasA;
                         dst = Wb + W_INPROJ; sp = sA; cp = cA; row = r; }
    else if (r < 2560) { W = wF; lnw = lnwF; lnb = lnbF; bias = biasF;
                         dst = Wb + W_FFN1;   sp = sF; cp = cF; row = r - 1536; }
    else               { W = wM; lnw = lnwM; lnb = lnbM; bias = biasM;
                         dst = Wb + W_MLP1;   sp = sM; cp = cM; row = r - 2560; }
    const float* wr = W + (size_t)row * 512;
    float s = 0.f, c = 0.f;
    #pragma unroll
    for (int i = 0; i < 2; ++i) {
        int k = t + i * 256;
        float wv = lnw[k] * wr[k];
        dst[(size_t)row * 512 + k] = f2bf(wv);
        s += wv;
        c += lnb[k] * wr[k];
    }
    s = wave_sum(s); c = wave_sum(c);
    if ((t & 63) == 0) { rs_[t >> 6] = s; rc_[t >> 6] = c; }
    __syncthreads();
    if (t == 0) {
        sp[row] = rs_[0] + rs_[1] + rs_[2] + rs_[3];
        cp[row] = rc_[0] + rc_[1] + rc_[2] + rc_[3] + bias[row];
    }
}

// ---- prep (4 samples/block): branches -> Tb + CTX + LN stats (rs, rs*m) ---
__global__ __launch_bounds__(256) void k_prep_ln(const float* __restrict__ br,
        int baseN, u16* __restrict__ Tb, u16* __restrict__ CTX,
        float2* __restrict__ STA)
{
    __shared__ float lds[4][4][516];
    int t = threadIdx.x;
    int s0 = blockIdx.x * 4;
    #pragma unroll
    for (int s = 0; s < 4; ++s) {
        const float* p = br + (size_t)(baseN + s0 + s) * 2048;
        u16* c = CTX + (size_t)(s0 + s) * 1024;
        #pragma unroll
        for (int i = 0; i < 2; ++i) {
            int f = t + i * 256;
            float4 v = *(const float4*)(p + f * 4);
            lds[s][0][f] = v.x; lds[s][1][f] = v.y; lds[s][2][f] = v.z; lds[s][3][f] = v.w;
            c[f]       = f2bf((v.x + v.y + v.z + v.w) * 0.25f);
            c[512 + f] = f2bf(fmaxf(fmaxf(v.x, v.y), fmaxf(v.z, v.w)));
        }
    }
    __syncthreads();
    int wv = t >> 6, lane = t & 63, f0 = lane * 8;
    #pragma unroll
    for (int p4i = 0; p4i < 4; ++p4i) {
        int idx = wv * 4 + p4i;
        int s = idx >> 2, b = idx & 3;
        float xv[8];
        #pragma unroll
        for (int i = 0; i < 8; ++i) xv[i] = lds[s][b][f0 + i];
        float sm = 0.f;
        #pragma unroll
        for (int i = 0; i < 8; ++i) sm += xv[i];
        sm = wave_sum(sm);
        float m = sm * (1.f / 512.f);
        float q = 0.f;
        #pragma unroll
        for (int i = 0; i < 8; ++i) { float d = xv[i] - m; q += d * d; }
        q = wave_sum(q);
        float rs = rsqrtf(q * (1.f / 512.f) + EPSV);
        size_t row = (size_t)(s0 + s) * 4 + b;
        *(uint4*)(Tb + row * 512 + f0) = make_uint4(pack2(xv[0], xv[1]), pack2(xv[2], xv[3]),
                                                    pack2(xv[4], xv[5]), pack2(xv[6], xv[7]));
        if (lane == 0) STA[row] = make_float2(rs, rs * m);
    }
}

// ---- LN row stats only (rs, rs*m) from bf16 rows --------------------------
__global__ __launch_bounds__(256) void k_lnstats(const u16* __restrict__ X,
        float2* __restrict__ ST)
{
    int t = threadIdx.x;
    int wave = t >> 6, lane = t & 63;
    size_t r = (size_t)blockIdx.x * 4 + wave;
    int f0 = lane * 8;
    uint4 raw = *(const uint4*)(X + r * 512 + f0);
    float xv[8];
    { float2 a = bf2f2(raw.x); xv[0] = a.x; xv[1] = a.y; }
    { float2 a = bf2f2(raw.y); xv[2] = a.x; xv[3] = a.y; }
    { float2 a = bf2f2(raw.z); xv[4] = a.x; xv[5] = a.y; }
    { float2 a = bf2f2(raw.w); xv[6] = a.x; xv[7] = a.y; }
    float s = 0.f;
    #pragma unroll
    for (int i = 0; i < 8; ++i) s += xv[i];
    s = wave_sum(s);
    float m = s * (1.f / 512.f);
    float q = 0.f;
    #pragma unroll
    for (int i = 0; i < 8; ++i) { float d = xv[i] - m; q += d * d; }
    q = wave_sum(q);
    float rs = rsqrtf(q * (1.f / 512.f) + EPSV);
    if (lane == 0) ST[r] = make_float2(rs, rs * m);
}

// ===========================================================================
// 256x256 4-phase/K-tile GEMM — R7-verified main loop, byte-identical.
// BK=64, 512 thr / 8 waves, per-wave 64x32 piece of EACH 128x128 C-quadrant.
// LDS: 2 buf x [Ah0|Ah1|Bh0|Bh1] x 16KB = 128KB. Steady VMW(4),(4),(4),- ;
// drain (4),(2),(0),-.
// STORE: 1 bf16 (+opt residual), 2 f4-scatter(out), 3 dw-conv+squeeze.
// LNFOLD: epilogue v = acc*rs[m] - (rs*m)[m]*s[n] + c[n] (LN folded into W).
// ===========================================================================

#define STAGE(SLOT, TILE) do {                                                \
    const u16* sm_ = ((SLOT) < 2) ? A : W;                                    \
    int rb_ = (((SLOT) < 2) ? m0 : n0) + ((SLOT) & 1) * 128;                  \
    int k0_ = (TILE) * 64;                                                    \
    u16* db_ = lds + (((TILE) & 1) * 32768) + (SLOT) * 8192;                  \
    _Pragma("unroll")                                                         \
    for (int l_ = 0; l_ < 2; ++l_) {                                          \
        int L_ = (l_ * 512 + tid) * 16;                                       \
        int row_ = L_ >> 7;                                                   \
        int ir_ = (L_ & 127) ^ ((row_ & 7) << 4);                             \
        gload_lds16(sm_ + (size_t)(rb_ + row_) * K + k0_ + (ir_ >> 1),        \
                    db_ + (L_ >> 1));                                         \
    } } while (0)

#define QUAD(MH, NH, STAGESTMT) do {                                          \
    const u16* lb_ = lds + cur * 32768;                                       \
    short8 a_[4][2], b_[2][2];                                                \
    _Pragma("unroll")                                                         \
    for (int mi = 0; mi < 4; ++mi)                                            \
        _Pragma("unroll")                                                     \
        for (int ks = 0; ks < 2; ++ks)                                        \
            a_[mi][ks] = *(const short8*)(lb_ + (MH) * 8192 + arow[mi] + gcol[ks]); \
    _Pragma("unroll")                                                         \
    for (int ni = 0; ni < 2; ++ni)                                            \
        _Pragma("unroll")                                                     \
        for (int ks = 0; ks < 2; ++ks)                                        \
            b_[ni][ks] = *(const short8*)(lb_ + 16384 + (NH) * 8192 + brow[ni] + gcol[ks]); \
    STAGESTMT;                                                                \
    BARR();                                                                   \
    __builtin_amdgcn_s_setprio(1);                                            \
    _Pragma("unroll")                                                         \
    for (int ks = 0; ks < 2; ++ks)                                            \
        _Pragma("unroll")                                                     \
        for (int mi = 0; mi < 4; ++mi)                                        \
            _Pragma("unroll")                                                 \
            for (int ni = 0; ni < 2; ++ni)                                    \
                acc[MH][NH][mi][ni] = __builtin_amdgcn_mfma_f32_16x16x32_bf16( \
                    a_[mi][ks], b_[ni][ks], acc[MH][NH][mi][ni], 0, 0, 0);    \
    __builtin_amdgcn_s_setprio(0);                                            \
} while (0)

template<int EPI, bool HAS_BIAS, bool HAS_RES, int STORE, bool LNFOLD>
__global__ __launch_bounds__(512, 2) void k_gemm256(
        const u16* __restrict__ A, const u16* __restrict__ W,
        const float* __restrict__ bias, const u16* __restrict__ Res,
        void* __restrict__ Cout, int Ncols, int K, int baseN, int nTX,
        const float* __restrict__ dwp, u16* __restrict__ Sout,
        const float2* __restrict__ Astat, const float* __restrict__ Scol,
        const float* __restrict__ Ccol)
{
    __shared__ __align__(16) u16 lds[65536];   // 128 KiB
    const int tid = threadIdx.x;
    const int wid = tid >> 6, lane = tid & 63;
    const int lr = lane & 15, kg = lane >> 4;
    const int wm = (wid >> 2) * 64;    // M offset within each M-half
    const int wn = (wid & 3) * 32;     // N offset within each N-half

    // bijective XCD swizzle (m204)
    int nwg = gridDim.x, orig = blockIdx.x;
    int q = nwg >> 3, r = nwg & 7;
    int xcd = orig & 7, lin = orig >> 3;
    int wgid = (xcd < r ? xcd * (q + 1) : r * (q + 1) + (xcd - r) * q) + lin;
    const int m0 = (wgid / nTX) * 256, n0 = (wgid % nTX) * 256;

    // fragment LDS element offsets (within one half-tile)
    int arow[4], brow[2], gcol[2];
    #pragma unroll
    for (int mi = 0; mi < 4; ++mi) arow[mi] = (wm + mi * 16 + lr) * 64;
    #pragma unroll
    for (int ni = 0; ni < 2; ++ni) brow[ni] = (wn + ni * 16 + lr) * 64;
    #pragma unroll
    for (int ks = 0; ks < 2; ++ks) gcol[ks] = (ks * 32 + kg * 8) ^ ((lr & 7) << 3);

    floatx4 acc[2][2][4][2] = {};

    // prologue: stage K-tile 0 in consumption order
    STAGE(0, 0); STAGE(2, 0); STAGE(1, 0); STAGE(3, 0);

    const int NT = K >> 6;
    int cur = 0;
    for (int t = 0; t < NT - 1; ++t) {
        int nx = t + 1;
        VMW(4); BARR(); QUAD(0, 0, STAGE(0, nx));
        VMW(4); BARR(); QUAD(1, 0, STAGE(2, nx));
        VMW(4); BARR(); QUAD(0, 1, STAGE(1, nx));
                BARR(); QUAD(1, 1, STAGE(3, nx));
        cur ^= 1;
    }
    // last K-tile: counted drain
    VMW(4); BARR(); QUAD(0, 0, (void)0);
    VMW(2); BARR(); QUAD(1, 0, (void)0);
    VMW(0); BARR(); QUAD(0, 1, (void)0);
            BARR(); QUAD(1, 1, (void)0);

    // epilogue: D col = lane&15 (n), row = kg*4 + reg (m)
    int rm = kg * 4;
    #pragma unroll
    for (int MH = 0; MH < 2; ++MH)
    #pragma unroll
    for (int NH = 0; NH < 2; ++NH)
    #pragma unroll
    for (int ni = 0; ni < 2; ++ni) {
        int n = n0 + NH * 128 + wn + ni * 16 + lr;
        float bv = HAS_BIAS ? bias[n] : 0.f;
        float s_n = 0.f, c_n = 0.f;
        if (LNFOLD) { s_n = Scol[n]; c_n = Ccol[n]; }
        float w0, w1, w2;
        if (STORE == 3) { w0 = dwp[n * 3]; w1 = dwp[n * 3 + 1]; w2 = dwp[n * 3 + 2]; }
        #pragma unroll
        for (int mi = 0; mi < 4; ++mi) {
            int mb = m0 + MH * 128 + wm + mi * 16 + rm;
            float vv[4];
            #pragma unroll
            for (int rr = 0; rr < 4; ++rr) {
                float v;
                if (LNFOLD) {
                    float2 st = Astat[mb + rr];
                    v = acc[MH][NH][mi][ni][rr] * st.x - st.y * s_n + c_n;
                } else {
                    v = acc[MH][NH][mi][ni][rr] + bv;
                }
                if (EPI == 1) v = gelu_exact(v);
                else if (EPI == 2) v = fmaxf(v, 0.f);
                else if (EPI == 3) v = 1.f / (1.f + expf(-v));
                vv[rr] = v;
            }
            if (STORE == 2) {
                *(float4*)((float*)Cout + (size_t)(baseN + (mb >> 2)) * 2048 + (size_t)n * 4)
                    = make_float4(vv[0], vv[1], vv[2], vv[3]);
            } else if (STORE == 3) {
                // depthwise k=3 over tokens (rows mb..mb+3 = one sample) + squeeze
                float y0 = w1 * vv[0] + w2 * vv[1];
                float y1 = w0 * vv[0] + w1 * vv[1] + w2 * vv[2];
                float y2 = w0 * vv[1] + w1 * vv[2] + w2 * vv[3];
                float y3 = w0 * vv[2] + w1 * vv[3];
                u16* xp = (u16*)Cout + (size_t)mb * Ncols + n;
                xp[0] = f2bf(y0);
                xp[Ncols] = f2bf(y1);
                xp[2 * Ncols] = f2bf(y2);
                xp[3 * Ncols] = f2bf(y3);
                Sout[(size_t)(mb >> 2) * Ncols + n] = f2bf((y0 + y1 + y2 + y3) * 0.25f);
            } else {
                #pragma unroll
                for (int rr = 0; rr < 4; ++rr) {
                    float v = vv[rr];
                    if (HAS_RES) v += bf1f(Res[(size_t)(mb + rr) * Ncols + n]);
                    ((u16*)Cout)[(size_t)(mb + rr) * Ncols + n] = f2bf(v);
                }
            }
        }
    }
}

// ---- 128^2 MFMA GEMM (small shapes: gate1, se1, se2) ----------------------
template<int EPI, bool HAS_BIAS, bool HAS_RES, int STORE>
__global__ __launch_bounds__(256) void k_mfma_gemm(
        const u16* __restrict__ A, const u16* __restrict__ W,
        const float* __restrict__ bias, const u16* __restrict__ Res,
        void* __restrict__ Cout, int M, int Ncols, int K, int baseN)
{
    __shared__ u16 As[128 * 32];
    __shared__ u16 Bs[128 * 32];
    int t = threadIdx.x;
    int wid = t >> 6, lane = t & 63;
    int wm = (wid >> 1) * 64, wn = (wid & 1) * 64;
    int m0 = blockIdx.y * 128, n0 = blockIdx.x * 128;
    int srow = t >> 2;
    int scol = (((t & 3) ^ ((srow >> 1) & 3)) * 8);
    int aR0 = min(m0 + srow, M - 1),      aR1 = min(m0 + 64 + srow, M - 1);
    int bR0 = min(n0 + srow, Ncols - 1),  bR1 = min(n0 + 64 + srow, Ncols - 1);
    const u16* Ap0 = A + (size_t)aR0 * K + scol;
    const u16* Ap1 = A + (size_t)aR1 * K + scol;
    const u16* Wp0 = W + (size_t)bR0 * K + scol;
    const u16* Wp1 = W + (size_t)bR1 * K + scol;
    u16* AsT0 = As + t * 8;  u16* AsT1 = As + 2048 + t * 8;
    u16* BsT0 = Bs + t * 8;  u16* BsT1 = Bs + 2048 + t * 8;

    int kg = lane >> 4, lr = lane & 15;
    int cb = kg ^ ((lr >> 1) & 3);
    const u16* aF = As + (wm + lr) * 32 + cb * 8;
    const u16* bF = Bs + (wn + lr) * 32 + cb * 8;

    floatx4 acc[4][4] = {};
    for (int k0 = 0; k0 < K; k0 += 32) {
        __syncthreads();
        gload_lds16(Ap0 + k0, AsT0);
        gload_lds16(Ap1 + k0, AsT1);
        gload_lds16(Wp0 + k0, BsT0);
        gload_lds16(Wp1 + k0, BsT1);
        __syncthreads();
        short8 a[4], b[4];
        #pragma unroll
        for (int i = 0; i < 4; ++i) {
            a[i] = *(const short8*)(aF + i * 512);
            b[i] = *(const short8*)(bF + i * 512);
        }
        #pragma unroll
        for (int i = 0; i < 4; ++i)
            #pragma unroll
            for (int j = 0; j < 4; ++j)
                acc[i][j] = __builtin_amdgcn_mfma_f32_16x16x32_bf16(a[i], b[j], acc[i][j], 0, 0, 0);
    }
    int rm = (lane >> 4) * 4;
    #pragma unroll
    for (int j = 0; j < 4; ++j) {
        int n = n0 + wn + j * 16 + lr;
        float bv = HAS_BIAS ? bias[min(n, Ncols - 1)] : 0.f;
        #pragma unroll
        for (int i = 0; i < 4; ++i) {
            int mb = m0 + wm + i * 16 + rm;
            float vv[4];
            #pragma unroll
            for (int r = 0; r < 4; ++r) {
                float v = acc[i][j][r] + bv;
                if (EPI == 1) v = gelu_exact(v);
                else if (EPI == 2) v = fmaxf(v, 0.f);
                else if (EPI == 3) v = 1.f / (1.f + expf(-v));
                vv[r] = v;
            }
            #pragma unroll
            for (int r = 0; r < 4; ++r) {
                int m = mb + r;
                if (m < M && n < Ncols) {
                    float v = vv[r];
                    if (HAS_RES) v += bf1f(Res[(size_t)m * Ncols + n]);
                    if (STORE == 0) ((float*)Cout)[(size_t)m * Ncols + n] = v;
                    else            ((u16*)Cout)[(size_t)m * Ncols + n] = f2bf(v);
                }
            }
        }
    }
}

// ---- attention core: 4x4 per (sample, head), bf16 in/out ------------------
__global__ __launch_bounds__(256) void k_attn(const u16* __restrict__ QKV,
        u16* __restrict__ AO)
{
    int t = threadIdx.x;
    int h = t >> 6, lane = t & 63;
    size_t n = (size_t)blockIdx.x;
    const u16* base = QKV + n * 4 * 1536 + h * 128 + lane * 2;
    float2 q[4], k[4], v[4];
    #pragma unroll
    for (int b = 0; b < 4; ++b) {
        q[b] = bf2f2(*(const u32*)(base + b * 1536));
        k[b] = bf2f2(*(const u32*)(base + b * 1536 + 512));
        v[b] = bf2f2(*(const u32*)(base + b * 1536 + 1024));
    }
    const float scale = 0.08838834764831845f;  // 128^-0.5
    float sc[4][4];
    #pragma unroll
    for (int qb = 0; qb < 4; ++qb)
        #pragma unroll
        for (int kb = 0; kb < 4; ++kb) {
            float p = q[qb].x * k[kb].x + q[qb].y * k[kb].y;
            sc[qb][kb] = wave_sum(p) * scale;
        }
    #pragma unroll
    for (int qb = 0; qb < 4; ++qb) {
        float mx = fmaxf(fmaxf(sc[qb][0], sc[qb][1]), fmaxf(sc[qb][2], sc[qb][3]));
        float e0 = expf(sc[qb][0] - mx), e1 = expf(sc[qb][1] - mx);
        float e2 = expf(sc[qb][2] - mx), e3 = expf(sc[qb][3] - mx);
        float inv = 1.f / (e0 + e1 + e2 + e3);
        float ox = (e0 * v[0].x + e1 * v[1].x + e2 * v[2].x + e3 * v[3].x) * inv;
        float oy = (e0 * v[0].y + e1 * v[1].y + e2 * v[2].y + e3 * v[3].y) * inv;
        *(u32*)(AO + (n * 4 + qb) * 512 + h * 128 + lane * 2) = pack2(ox, oy);
    }
}

// ---- SE scale + GroupNorm + GELU + alpha-fuse -> FU bf16 ------------------
__global__ __launch_bounds__(256) void k_gnfin_fuse(
        const u16* __restrict__ XP, const u16* __restrict__ SIG,
        const float* __restrict__ gnw, const float* __restrict__ gnb,
        const u16* __restrict__ X2, const u16* __restrict__ X3,
        const float* __restrict__ alpha, int baseN, u16* __restrict__ FU)
{
    __shared__ float red[8];
    size_t ls = blockIdx.x;
    int t = threadIdx.x;
    int wave = t >> 6, lane = t & 63;
    int f = t * 2;
    const u16* p = XP + ls * 2048;
    float2 sg = bf2f2(*(const u32*)(SIG + ls * 512 + f));
    float2 xr[4];
    #pragma unroll
    for (int b = 0; b < 4; ++b) {
        float2 x = bf2f2(*(const u32*)(p + b * 512 + f));
        xr[b] = make_float2(x.x * sg.x, x.y * sg.y);
    }
    float s = 0.f;
    #pragma unroll
    for (int b = 0; b < 4; ++b) s += xr[b].x + xr[b].y;
    s = wave_sum(s);
    if (lane == 0) red[wave] = s;
    __syncthreads();
    float m = (red[0] + red[1] + red[2] + red[3]) * (1.f / 2048.f);
    float q = 0.f;
    #pragma unroll
    for (int b = 0; b < 4; ++b) {
        float dx = xr[b].x - m, dy = xr[b].y - m;
        q += dx * dx + dy * dy;
    }
    q = wave_sum(q);
    if (lane == 0) red[4 + wave] = q;
    __syncthreads();
    float rs = rsqrtf((red[4] + red[5] + red[6] + red[7]) * (1.f / 2048.f) + EPSV);
    const float* a = alpha + (size_t)(baseN + ls) * 3;
    float a0 = a[0], a1 = a[1], a2 = a[2];
    float gw0 = gnw[f], gw1 = gnw[f + 1], gb0 = gnb[f], gb1 = gnb[f + 1];
    #pragma unroll
    for (int b = 0; b < 4; ++b) {
        float x1a = gelu_exact((xr[b].x - m) * rs * gw0 + gb0);
        float x1b = gelu_exact((xr[b].y - m) * rs * gw1 + gb1);
        float2 v2 = bf2f2(*(const u32*)(X2 + (ls * 4 + b) * 512 + f));
        float2 v3 = bf2f2(*(const u32*)(X3 + (ls * 4 + b) * 512 + f));
        *(u32*)(FU + (ls * 4 + b) * 512 + f) =
            pack2(a0 * x1a + a1 * v2.x + a2 * v3.x,
                  a0 * x1b + a1 * v2.y + a2 * v3.y);
    }
}

// ---- gate stage 2: logits (3x128 dot) + softmax -> alpha ------------------
__global__ __launch_bounds__(256) void k_gate2(const u16* __restrict__ G1,
        const float* __restrict__ w2, const float* __restrict__ b2,
        float* __restrict__ alpha, int CH)
{
    int s = blockIdx.x * 256 + threadIdx.x;
    if (s >= CH) return;
    float l0 = b2[0], l1 = b2[1], l2 = b2[2];
    const u16* g = G1 + (size_t)s * 128;
    for (int j = 0; j < 128; j += 2) {
        float2 gg = bf2f2(*(const u32*)(g + j));
        l0 += gg.x * w2[j]       + gg.y * w2[j + 1];
        l1 += gg.x * w2[128 + j] + gg.y * w2[129 + j];
        l2 += gg.x * w2[256 + j] + gg.y * w2[257 + j];
    }
    float mx = fmaxf(l0, fmaxf(l1, l2));
    float e0 = expf(l0 - mx), e1 = expf(l1 - mx), e2 = expf(l2 - mx);
    float inv = 1.f / (e0 + e1 + e2);
    float* a = alpha + (size_t)s * 3;
    a[0] = e0 * inv; a[1] = e1 * inv; a[2] = e2 * inv;
}

// ---------------------------------------------------------------------------
extern "C" void kernel_launch(void* const* d_in, const int* in_sizes, int n_in,
                              void* d_out, int out_size, void* d_ws, size_t ws_size,
                              hipStream_t stream)
{
    (void)in_sizes; (void)n_in; (void)out_size;
    const float* br         = (const float*)d_in[0];
    const float* conv_pw_w  = (const float*)d_in[1];
    const float* conv_dw_w  = (const float*)d_in[2];
    const float* gn_w       = (const float*)d_in[3];
    const float* gn_b       = (const float*)d_in[4];
    const float* se_w1      = (const float*)d_in[5];
    const float* se_w2      = (const float*)d_in[6];
    const float* ln_attn_w  = (const float*)d_in[7];
    const float* ln_attn_b  = (const float*)d_in[8];
    const float* in_proj_w  = (const float*)d_in[9];
    const float* in_proj_b  = (const float*)d_in[10];
    const float* attn_out_w = (const float*)d_in[11];
    const float* attn_out_b = (const float*)d_in[12];
    const float* ln_ffn_w   = (const float*)d_in[13];
    const float* ln_ffn_b   = (const float*)d_in[14];
    const float* ffn_w1     = (const float*)d_in[15];
    const float* ffn_b1     = (const float*)d_in[16];
    const float* ffn_w2     = (const float*)d_in[17];
    const float* ffn_b2     = (const float*)d_in[18];
    const float* mlp_ln_w   = (const float*)d_in[19];
    const float* mlp_ln_b   = (const float*)d_in[20];
    const float* mlp_w1     = (const float*)d_in[21];
    const float* mlp_b1     = (const float*)d_in[22];
    const float* mlp_w2     = (const float*)d_in[23];
    const float* mlp_b2     = (const float*)d_in[24];
    const float* gate_w1    = (const float*)d_in[25];
    const float* gate_b1    = (const float*)d_in[26];
    const float* gate_w2    = (const float*)d_in[27];
    const float* gate_b2    = (const float*)d_in[28];
    const float* outp_w     = (const float*)d_in[29];
    float* out = (float*)d_out;

    char* ws = (char*)d_ws;
    float* alpha = (float*)ws;                       // N_TOT*3 fp32 = 196608 B
    u16* Wb = (u16*)(ws + 196608);                   // W_TOT bf16
    float* sA = (float*)(ws + 196608 + (size_t)W_TOT * 2);
    float* cA = sA + 1536;
    float* sF = cA + 1536;
    float* cF = sF + 1024;
    float* sM = cF + 1024;
    float* cM = sM + 1024;
    const size_t CB = 196608 + (size_t)W_TOT * 2 + 28672;   // 7958528
    int CH = N_TOT;
    while (CH > 64 && CB + (size_t)CH * 27072ULL > ws_size) CH >>= 1;

    // ws buffers (27072 B/sample)
    char* p = ws + CB;
    u16* Tb    = (u16*)p;    p += (size_t)CH * 4096;
    char* CTXS = p;          p += (size_t)CH * 2048;   // CTX; later S + SIGb
    u16* FU    = (u16*)p;    p += (size_t)CH * 4096;
    u16* QKV   = (u16*)p;    p += (size_t)CH * 12288;  // aliased as U
    u16* AOXP  = (u16*)p;    p += (size_t)CH * 4096;   // AO then XP
    u16* H1    = (u16*)p;    p += (size_t)CH * 128;
    u16* G1    = (u16*)p;    p += (size_t)CH * 256;
    float2* STA = (float2*)p; p += (size_t)CH * 32;
    float2* ST2 = (float2*)p; p += (size_t)CH * 32;
    u16* CTX  = (u16*)CTXS;
    u16* S    = (u16*)CTXS;                          // CH x 512 (first half)
    u16* SIGb = (u16*)(CTXS + (size_t)CH * 1024);    // CH x 512 (second half)
    u16* U    = QKV;

    // d_out as scratch: first half X2, second half T2/X3 (dead before out-proj)
    u16* O16 = (u16*)d_out;

    k_w2b<<<(W_TOT + 255) / 256, 256, 0, stream>>>(
        conv_pw_w, in_proj_w, attn_out_w, ffn_w1, ffn_w2, mlp_w1, mlp_w2,
        gate_w1, se_w1, se_w2, outp_w, Wb);
    k_wfold<<<3584, 256, 0, stream>>>(
        in_proj_w, ln_attn_w, ln_attn_b, in_proj_b,
        ffn_w1, ln_ffn_w, ln_ffn_b, ffn_b1,
        mlp_w1, mlp_ln_w, mlp_ln_b, mlp_b1,
        Wb, sA, cA, sF, cF, sM, cM);

    const int Ri = CH * 4;
    auto g128 = [](int M, int Nc) { return dim3((Nc + 127) / 128, (M + 127) / 128); };
    auto g256 = [](int M, int Nc) { return dim3((M / 256) * (Nc / 256)); };

    for (int c0 = 0; c0 < N_TOT; c0 += CH) {
        u16* X2b  = O16 + (size_t)c0 * 2048;                         // chunk-local rows
        u16* T2X3 = O16 + (size_t)N_TOT * 2048 + (size_t)c0 * 2048;  // T2 then X3

        k_prep_ln<<<CH / 4, 256, 0, stream>>>(br, c0, Tb, CTX, STA);
        // gate
        k_mfma_gemm<1, true, false, 1><<<g128(CH, 128), 256, 0, stream>>>(
            CTX, Wb + W_GATE1, gate_b1, nullptr, G1, CH, 128, 1024, 0);
        k_gate2<<<(CH + 255) / 256, 256, 0, stream>>>(G1, gate_w2, gate_b2,
                                                      alpha + (size_t)c0 * 3, CH);
        // attention expert (LN folded into in_proj weights)
        k_gemm256<0, false, false, 1, true><<<g256(Ri, 1536), 512, 0, stream>>>(
            Tb, Wb + W_INPROJ, nullptr, nullptr, QKV, 1536, 512, 0, 6,
            nullptr, nullptr, STA, sA, cA);
        k_attn<<<CH, 256, 0, stream>>>(QKV, AOXP);
        k_gemm256<0, true, true, 1, false><<<g256(Ri, 512), 512, 0, stream>>>(
            AOXP, Wb + W_ATTNO, attn_out_b, Tb, T2X3, 512, 512, 0, 2,
            nullptr, nullptr, nullptr, nullptr, nullptr);
        k_lnstats<<<Ri / 4, 256, 0, stream>>>(T2X3, ST2);
        k_gemm256<1, false, false, 1, true><<<g256(Ri, 1024), 512, 0, stream>>>(
            T2X3, Wb + W_FFN1, nullptr, nullptr, U, 1024, 512, 0, 4,
            nullptr, nullptr, ST2, sF, cF);
        k_gemm256<0, true, true, 1, false><<<g256(Ri, 512), 512, 0, stream>>>(
            U, Wb + W_FFN2, ffn_b2, T2X3, X2b, 512, 1024, 0, 2,
            nullptr, nullptr, nullptr, nullptr, nullptr);
        // MLP expert (LN folded into mlp1 weights; X3 overwrites T2)
        k_gemm256<1, false, false, 1, true><<<g256(Ri, 1024), 512, 0, stream>>>(
            Tb, Wb + W_MLP1, nullptr, nullptr, U, 1024, 512, 0, 4,
            nullptr, nullptr, STA, sM, cM);
        k_gemm256<0, true, true, 1, false><<<g256(Ri, 512), 512, 0, stream>>>(
            U, Wb + W_MLP2, mlp_b2, Tb, T2X3, 512, 1024, 0, 2,
            nullptr, nullptr, nullptr, nullptr, nullptr);
        // conv expert: pw GEMM + fused depthwise + SE squeeze
        k_gemm256<0, false, false, 3, false><<<g256(Ri, 512), 512, 0, stream>>>(
            Tb, Wb + W_CONVPW, nullptr, nullptr, AOXP, 512, 512, 0, 2,
            conv_dw_w, S, nullptr, nullptr, nullptr);
        k_mfma_gemm<2, false, false, 1><<<g128(CH, 64), 256, 0, stream>>>(
            S, Wb + W_SE1, nullptr, nullptr, H1, CH, 64, 512, 0);
        k_mfma_gemm<3, false, false, 1><<<g128(CH, 512), 256, 0, stream>>>(
            H1, Wb + W_SE2, nullptr, nullptr, SIGb, CH, 512, 64, 0);
        // GN + gelu + alpha-fuse
        k_gnfin_fuse<<<CH, 256, 0, stream>>>(AOXP, SIGb, gn_w, gn_b,
                                             X2b, T2X3, alpha, c0, FU);
        // output projection, float4 scatter to (n, o, b)
        k_gemm256<0, false, false, 2, false><<<g256(Ri, 512), 512, 0, stream>>>(
            FU, Wb + W_OUTP, nullptr, nullptr, out, 512, 512, c0, 2,
            nullptr, nullptr, nullptr, nullptr, nullptr);
    }
}

// Round 13
// 1024.883 us; speedup vs baseline: 4.6427x; 1.0315x over previous
//
#include <hip/hip_runtime.h>
#include <math.h>

// ---------------------------------------------------------------------------
// ParallelExpertsMixer — Round 13: R12 (LN folded into in_proj/ffn1/mlp1
// weights) with the LNFOLD epilogue loads hoisted: 144 scalar loads/thread
// -> 24 (s,c preloaded; row stats as 2x float4 per (MH,mi)). GEMM main loop
// byte-identical to the R7-verified config.
// ---------------------------------------------------------------------------

#define N_TOT 16384
#define EPSV 1e-5f

typedef unsigned short u16;
typedef unsigned int   u32;
typedef __attribute__((ext_vector_type(8))) short  short8;
typedef __attribute__((ext_vector_type(4))) float  floatx4;

__device__ __forceinline__ float gelu_exact(float x) {
    return 0.5f * x * (1.0f + erff(x * 0.70710678118654752440f));
}
__device__ __forceinline__ float wave_sum(float v) {
    #pragma unroll
    for (int o = 32; o > 0; o >>= 1) v += __shfl_xor(v, o);
    return v;
}
__device__ __forceinline__ u16 f2bf(float f) {
    u32 u = __float_as_uint(f);
    return (u16)((u + 0x7fffu + ((u >> 16) & 1u)) >> 16);
}
__device__ __forceinline__ u32 pack2(float lo, float hi) {
    return (u32)f2bf(lo) | ((u32)f2bf(hi) << 16);
}
__device__ __forceinline__ float bf1f(u16 u) { return __uint_as_float((u32)u << 16); }
__device__ __forceinline__ float2 bf2f2(u32 u) {
    return make_float2(__uint_as_float(u << 16), __uint_as_float(u & 0xffff0000u));
}
__device__ __forceinline__ void gload_lds16(const void* g, void* l) {
    __builtin_amdgcn_global_load_lds(
        (const __attribute__((address_space(1))) unsigned int*)g,
        (__attribute__((address_space(3))) unsigned int*)l, 16, 0, 0);
}

#define BARR() asm volatile("s_barrier" ::: "memory")
#define VMW(N) asm volatile("s_waitcnt vmcnt(" #N ")" ::: "memory")

// ---- bf16 weight conversion (once per launch) -----------------------------
#define W_CONVPW 0
#define W_INPROJ 262144
#define W_ATTNO  1048576
#define W_FFN1   1310720
#define W_FFN2   1835008
#define W_MLP1   2359296
#define W_MLP2   2883584
#define W_GATE1  3407872
#define W_SE1    3538944
#define W_SE2    3571712
#define W_OUTP   3604480
#define W_TOT    3866624

__global__ __launch_bounds__(256) void k_w2b(
        const float* __restrict__ p0, const float* __restrict__ p1,
        const float* __restrict__ p2, const float* __restrict__ p3,
        const float* __restrict__ p4, const float* __restrict__ p5,
        const float* __restrict__ p6, const float* __restrict__ p7,
        const float* __restrict__ p8, const float* __restrict__ p9,
        const float* __restrict__ p10, u16* __restrict__ dst)
{
    int i = blockIdx.x * 256 + threadIdx.x;
    if (i >= W_TOT) return;
    const float* s; int off;
    if      (i < W_INPROJ) { s = p0;  off = W_CONVPW; }
    else if (i < W_ATTNO)  { s = p1;  off = W_INPROJ; }
    else if (i < W_FFN1)   { s = p2;  off = W_ATTNO; }
    else if (i < W_FFN2)   { s = p3;  off = W_FFN1; }
    else if (i < W_MLP1)   { s = p4;  off = W_FFN2; }
    else if (i < W_MLP2)   { s = p5;  off = W_MLP1; }
    else if (i < W_GATE1)  { s = p6;  off = W_MLP2; }
    else if (i < W_SE1)    { s = p7;  off = W_GATE1; }
    else if (i < W_SE2)    { s = p8;  off = W_SE1; }
    else if (i < W_OUTP)   { s = p9;  off = W_SE2; }
    else                   { s = p10; off = W_OUTP; }
    dst[i] = f2bf(s[i - off]);
}

// ---- fold LN into weights: W' = lnw*W (bf16), s_n = sum(W'_n),
//      c_n = lnb.W_n + bias_n.  One block per output row (3584 rows, K=512).
__global__ __launch_bounds__(256) void k_wfold(
        const float* __restrict__ wA, const float* __restrict__ lnwA,
        const float* __restrict__ lnbA, const float* __restrict__ biasA,
        const float* __restrict__ wF, const float* __restrict__ lnwF,
        const float* __restrict__ lnbF, const float* __restrict__ biasF,
        const float* __restrict__ wM, const float* __restrict__ lnwM,
        const float* __restrict__ lnbM, const float* __restrict__ biasM,
        u16* __restrict__ Wb,
        float* __restrict__ sA, float* __restrict__ cA,
        float* __restrict__ sF, float* __restrict__ cF,
        float* __restrict__ sM, float* __restrict__ cM)
{
    __shared__ float rs_[4], rc_[4];
    int r = blockIdx.x, t = threadIdx.x;
    const float *W, *lnw, *lnb, *bias;
    u16* dst; float *sp, *cp; int row;
    if (r < 1536)      { W = wA; lnw = lnwA; lnb = lnbA; bias = biasA;
                         dst = Wb + W_INPROJ; sp = sA; cp = cA; row = r; }
    else if (r < 2560) { W = wF; lnw = lnwF; lnb = lnbF; bias = biasF;
                         dst = Wb + W_FFN1;   sp = sF; cp = cF; row = r - 1536; }
    else               { W = wM; lnw = lnwM; lnb = lnbM; bias = biasM;
                         dst = Wb + W_MLP1;   sp = sM; cp = cM; row = r - 2560; }
    const float* wr = W + (size_t)row * 512;
    float s = 0.f, c = 0.f;
    #pragma unroll
    for (int i = 0; i < 2; ++i) {
        int k = t + i * 256;
        float wv = lnw[k] * wr[k];
        dst[(size_t)row * 512 + k] = f2bf(wv);
        s += wv;
        c += lnb[k] * wr[k];
    }
    s = wave_sum(s); c = wave_sum(c);
    if ((t & 63) == 0) { rs_[t >> 6] = s; rc_[t >> 6] = c; }
    __syncthreads();
    if (t == 0) {
        sp[row] = rs_[0] + rs_[1] + rs_[2] + rs_[3];
        cp[row] = rc_[0] + rc_[1] + rc_[2] + rc_[3] + bias[row];
    }
}

// ---- prep (4 samples/block): branches -> Tb + CTX + LN stats (rs, rs*m) ---
__global__ __launch_bounds__(256) void k_prep_ln(const float* __restrict__ br,
        int baseN, u16* __restrict__ Tb, u16* __restrict__ CTX,
        float2* __restrict__ STA)
{
    __shared__ float lds[4][4][516];
    int t = threadIdx.x;
    int s0 = blockIdx.x * 4;
    #pragma unroll
    for (int s = 0; s < 4; ++s) {
        const float* p = br + (size_t)(baseN + s0 + s) * 2048;
        u16* c = CTX + (size_t)(s0 + s) * 1024;
        #pragma unroll
        for (int i = 0; i < 2; ++i) {
            int f = t + i * 256;
            float4 v = *(const float4*)(p + f * 4);
            lds[s][0][f] = v.x; lds[s][1][f] = v.y; lds[s][2][f] = v.z; lds[s][3][f] = v.w;
            c[f]       = f2bf((v.x + v.y + v.z + v.w) * 0.25f);
            c[512 + f] = f2bf(fmaxf(fmaxf(v.x, v.y), fmaxf(v.z, v.w)));
        }
    }
    __syncthreads();
    int wv = t >> 6, lane = t & 63, f0 = lane * 8;
    #pragma unroll
    for (int p4i = 0; p4i < 4; ++p4i) {
        int idx = wv * 4 + p4i;
        int s = idx >> 2, b = idx & 3;
        float xv[8];
        #pragma unroll
        for (int i = 0; i < 8; ++i) xv[i] = lds[s][b][f0 + i];
        float sm = 0.f;
        #pragma unroll
        for (int i = 0; i < 8; ++i) sm += xv[i];
        sm = wave_sum(sm);
        float m = sm * (1.f / 512.f);
        float q = 0.f;
        #pragma unroll
        for (int i = 0; i < 8; ++i) { float d = xv[i] - m; q += d * d; }
        q = wave_sum(q);
        float rs = rsqrtf(q * (1.f / 512.f) + EPSV);
        size_t row = (size_t)(s0 + s) * 4 + b;
        *(uint4*)(Tb + row * 512 + f0) = make_uint4(pack2(xv[0], xv[1]), pack2(xv[2], xv[3]),
                                                    pack2(xv[4], xv[5]), pack2(xv[6], xv[7]));
        if (lane == 0) STA[row] = make_float2(rs, rs * m);
    }
}

// ---- LN row stats only (rs, rs*m) from bf16 rows --------------------------
__global__ __launch_bounds__(256) void k_lnstats(const u16* __restrict__ X,
        float2* __restrict__ ST)
{
    int t = threadIdx.x;
    int wave = t >> 6, lane = t & 63;
    size_t r = (size_t)blockIdx.x * 4 + wave;
    int f0 = lane * 8;
    uint4 raw = *(const uint4*)(X + r * 512 + f0);
    float xv[8];
    { float2 a = bf2f2(raw.x); xv[0] = a.x; xv[1] = a.y; }
    { float2 a = bf2f2(raw.y); xv[2] = a.x; xv[3] = a.y; }
    { float2 a = bf2f2(raw.z); xv[4] = a.x; xv[5] = a.y; }
    { float2 a = bf2f2(raw.w); xv[6] = a.x; xv[7] = a.y; }
    float s = 0.f;
    #pragma unroll
    for (int i = 0; i < 8; ++i) s += xv[i];
    s = wave_sum(s);
    float m = s * (1.f / 512.f);
    float q = 0.f;
    #pragma unroll
    for (int i = 0; i < 8; ++i) { float d = xv[i] - m; q += d * d; }
    q = wave_sum(q);
    float rs = rsqrtf(q * (1.f / 512.f) + EPSV);
    if (lane == 0) ST[r] = make_float2(rs, rs * m);
}

// ===========================================================================
// 256x256 4-phase/K-tile GEMM — R7-verified main loop, byte-identical.
// BK=64, 512 thr / 8 waves, per-wave 64x32 piece of EACH 128x128 C-quadrant.
// LDS: 2 buf x [Ah0|Ah1|Bh0|Bh1] x 16KB = 128KB. Steady VMW(4),(4),(4),- ;
// drain (4),(2),(0),-.
// STORE: 1 bf16 (+opt residual), 2 f4-scatter(out), 3 dw-conv+squeeze.
// LNFOLD (STORE=1, no bias/res): v = acc*rs[m] - (rs*m)[m]*s[n] + c[n],
//   loads hoisted: s,c preloaded (4/thread); row stats 2x float4 per (MH,mi).
// ===========================================================================

#define STAGE(SLOT, TILE) do {                                                \
    const u16* sm_ = ((SLOT) < 2) ? A : W;                                    \
    int rb_ = (((SLOT) < 2) ? m0 : n0) + ((SLOT) & 1) * 128;                  \
    int k0_ = (TILE) * 64;                                                    \
    u16* db_ = lds + (((TILE) & 1) * 32768) + (SLOT) * 8192;                  \
    _Pragma("unroll")                                                         \
    for (int l_ = 0; l_ < 2; ++l_) {                                          \
        int L_ = (l_ * 512 + tid) * 16;                                       \
        int row_ = L_ >> 7;                                                   \
        int ir_ = (L_ & 127) ^ ((row_ & 7) << 4);                             \
        gload_lds16(sm_ + (size_t)(rb_ + row_) * K + k0_ + (ir_ >> 1),        \
                    db_ + (L_ >> 1));                                         \
    } } while (0)

#define QUAD(MH, NH, STAGESTMT) do {                                          \
    const u16* lb_ = lds + cur * 32768;                                       \
    short8 a_[4][2], b_[2][2];                                                \
    _Pragma("unroll")                                                         \
    for (int mi = 0; mi < 4; ++mi)                                            \
        _Pragma("unroll")                                                     \
        for (int ks = 0; ks < 2; ++ks)                                        \
            a_[mi][ks] = *(const short8*)(lb_ + (MH) * 8192 + arow[mi] + gcol[ks]); \
    _Pragma("unroll")                                                         \
    for (int ni = 0; ni < 2; ++ni)                                            \
        _Pragma("unroll")                                                     \
        for (int ks = 0; ks < 2; ++ks)                                        \
            b_[ni][ks] = *(const short8*)(lb_ + 16384 + (NH) * 8192 + brow[ni] + gcol[ks]); \
    STAGESTMT;                                                                \
    BARR();                                                                   \
    __builtin_amdgcn_s_setprio(1);                                            \
    _Pragma("unroll")                                                         \
    for (int ks = 0; ks < 2; ++ks)                                            \
        _Pragma("unroll")                                                     \
        for (int mi = 0; mi < 4; ++mi)                                        \
            _Pragma("unroll")                                                 \
            for (int ni = 0; ni < 2; ++ni)                                    \
                acc[MH][NH][mi][ni] = __builtin_amdgcn_mfma_f32_16x16x32_bf16( \
                    a_[mi][ks], b_[ni][ks], acc[MH][NH][mi][ni], 0, 0, 0);    \
    __builtin_amdgcn_s_setprio(0);                                            \
} while (0)

template<int EPI, bool HAS_BIAS, bool HAS_RES, int STORE, bool LNFOLD>
__global__ __launch_bounds__(512, 2) void k_gemm256(
        const u16* __restrict__ A, const u16* __restrict__ W,
        const float* __restrict__ bias, const u16* __restrict__ Res,
        void* __restrict__ Cout, int Ncols, int K, int baseN, int nTX,
        const float* __restrict__ dwp, u16* __restrict__ Sout,
        const float2* __restrict__ Astat, const float* __restrict__ Scol,
        const float* __restrict__ Ccol)
{
    __shared__ __align__(16) u16 lds[65536];   // 128 KiB
    const int tid = threadIdx.x;
    const int wid = tid >> 6, lane = tid & 63;
    const int lr = lane & 15, kg = lane >> 4;
    const int wm = (wid >> 2) * 64;    // M offset within each M-half
    const int wn = (wid & 3) * 32;     // N offset within each N-half

    // bijective XCD swizzle (m204)
    int nwg = gridDim.x, orig = blockIdx.x;
    int q = nwg >> 3, r = nwg & 7;
    int xcd = orig & 7, lin = orig >> 3;
    int wgid = (xcd < r ? xcd * (q + 1) : r * (q + 1) + (xcd - r) * q) + lin;
    const int m0 = (wgid / nTX) * 256, n0 = (wgid % nTX) * 256;

    // fragment LDS element offsets (within one half-tile)
    int arow[4], brow[2], gcol[2];
    #pragma unroll
    for (int mi = 0; mi < 4; ++mi) arow[mi] = (wm + mi * 16 + lr) * 64;
    #pragma unroll
    for (int ni = 0; ni < 2; ++ni) brow[ni] = (wn + ni * 16 + lr) * 64;
    #pragma unroll
    for (int ks = 0; ks < 2; ++ks) gcol[ks] = (ks * 32 + kg * 8) ^ ((lr & 7) << 3);

    floatx4 acc[2][2][4][2] = {};

    // prologue: stage K-tile 0 in consumption order
    STAGE(0, 0); STAGE(2, 0); STAGE(1, 0); STAGE(3, 0);

    const int NT = K >> 6;
    int cur = 0;
    for (int t = 0; t < NT - 1; ++t) {
        int nx = t + 1;
        VMW(4); BARR(); QUAD(0, 0, STAGE(0, nx));
        VMW(4); BARR(); QUAD(1, 0, STAGE(2, nx));
        VMW(4); BARR(); QUAD(0, 1, STAGE(1, nx));
                BARR(); QUAD(1, 1, STAGE(3, nx));
        cur ^= 1;
    }
    // last K-tile: counted drain
    VMW(4); BARR(); QUAD(0, 0, (void)0);
    VMW(2); BARR(); QUAD(1, 0, (void)0);
    VMW(0); BARR(); QUAD(0, 1, (void)0);
            BARR(); QUAD(1, 1, (void)0);

    int rm = kg * 4;
    if (LNFOLD) {
        // hoisted epilogue: s,c for this thread's 4 n-values; row stats per (MH,mi)
        float sv[4], cv[4];
        int nidx[4];
        #pragma unroll
        for (int g = 0; g < 4; ++g) {   // g = NH*2 + ni
            int n = n0 + (g >> 1) * 128 + wn + (g & 1) * 16 + lr;
            nidx[g] = n;
            sv[g] = Scol[n];
            cv[g] = Ccol[n];
        }
        #pragma unroll
        for (int MH = 0; MH < 2; ++MH)
        #pragma unroll
        for (int mi = 0; mi < 4; ++mi) {
            int mb = m0 + MH * 128 + wm + mi * 16 + rm;
            float4 stA = *(const float4*)((const float*)(Astat + mb));      // rows mb,mb+1
            float4 stB = *(const float4*)((const float*)(Astat + mb + 2)); // rows mb+2,mb+3
            float rsv[4] = {stA.x, stA.z, stB.x, stB.z};
            float rmv[4] = {stA.y, stA.w, stB.y, stB.w};
            #pragma unroll
            for (int g = 0; g < 4; ++g) {
                int NH = g >> 1, ni = g & 1;
                #pragma unroll
                for (int rr = 0; rr < 4; ++rr) {
                    float v = acc[MH][NH][mi][ni][rr] * rsv[rr] - rmv[rr] * sv[g] + cv[g];
                    if (EPI == 1) v = gelu_exact(v);
                    ((u16*)Cout)[(size_t)(mb + rr) * Ncols + nidx[g]] = f2bf(v);
                }
            }
        }
        return;
    }

    // epilogue: D col = lane&15 (n), row = kg*4 + reg (m)
    #pragma unroll
    for (int MH = 0; MH < 2; ++MH)
    #pragma unroll
    for (int NH = 0; NH < 2; ++NH)
    #pragma unroll
    for (int ni = 0; ni < 2; ++ni) {
        int n = n0 + NH * 128 + wn + ni * 16 + lr;
        float bv = HAS_BIAS ? bias[n] : 0.f;
        float w0, w1, w2;
        if (STORE == 3) { w0 = dwp[n * 3]; w1 = dwp[n * 3 + 1]; w2 = dwp[n * 3 + 2]; }
        #pragma unroll
        for (int mi = 0; mi < 4; ++mi) {
            int mb = m0 + MH * 128 + wm + mi * 16 + rm;
            float vv[4];
            #pragma unroll
            for (int rr = 0; rr < 4; ++rr) {
                float v = acc[MH][NH][mi][ni][rr] + bv;
                if (EPI == 1) v = gelu_exact(v);
                else if (EPI == 2) v = fmaxf(v, 0.f);
                else if (EPI == 3) v = 1.f / (1.f + expf(-v));
                vv[rr] = v;
            }
            if (STORE == 2) {
                *(float4*)((float*)Cout + (size_t)(baseN + (mb >> 2)) * 2048 + (size_t)n * 4)
                    = make_float4(vv[0], vv[1], vv[2], vv[3]);
            } else if (STORE == 3) {
                // depthwise k=3 over tokens (rows mb..mb+3 = one sample) + squeeze
                float y0 = w1 * vv[0] + w2 * vv[1];
                float y1 = w0 * vv[0] + w1 * vv[1] + w2 * vv[2];
                float y2 = w0 * vv[1] + w1 * vv[2] + w2 * vv[3];
                float y3 = w0 * vv[2] + w1 * vv[3];
                u16* xp = (u16*)Cout + (size_t)mb * Ncols + n;
                xp[0] = f2bf(y0);
                xp[Ncols] = f2bf(y1);
                xp[2 * Ncols] = f2bf(y2);
                xp[3 * Ncols] = f2bf(y3);
                Sout[(size_t)(mb >> 2) * Ncols + n] = f2bf((y0 + y1 + y2 + y3) * 0.25f);
            } else {
                #pragma unroll
                for (int rr = 0; rr < 4; ++rr) {
                    float v = vv[rr];
                    if (HAS_RES) v += bf1f(Res[(size_t)(mb + rr) * Ncols + n]);
                    ((u16*)Cout)[(size_t)(mb + rr) * Ncols + n] = f2bf(v);
                }
            }
        }
    }
}

// ---- 128^2 MFMA GEMM (small shapes: gate1, se1, se2) ----------------------
template<int EPI, bool HAS_BIAS, bool HAS_RES, int STORE>
__global__ __launch_bounds__(256) void k_mfma_gemm(
        const u16* __restrict__ A, const u16* __restrict__ W,
        const float* __restrict__ bias, const u16* __restrict__ Res,
        void* __restrict__ Cout, int M, int Ncols, int K, int baseN)
{
    __shared__ u16 As[128 * 32];
    __shared__ u16 Bs[128 * 32];
    int t = threadIdx.x;
    int wid = t >> 6, lane = t & 63;
    int wm = (wid >> 1) * 64, wn = (wid & 1) * 64;
    int m0 = blockIdx.y * 128, n0 = blockIdx.x * 128;
    int srow = t >> 2;
    int scol = (((t & 3) ^ ((srow >> 1) & 3)) * 8);
    int aR0 = min(m0 + srow, M - 1),      aR1 = min(m0 + 64 + srow, M - 1);
    int bR0 = min(n0 + srow, Ncols - 1),  bR1 = min(n0 + 64 + srow, Ncols - 1);
    const u16* Ap0 = A + (size_t)aR0 * K + scol;
    const u16* Ap1 = A + (size_t)aR1 * K + scol;
    const u16* Wp0 = W + (size_t)bR0 * K + scol;
    const u16* Wp1 = W + (size_t)bR1 * K + scol;
    u16* AsT0 = As + t * 8;  u16* AsT1 = As + 2048 + t * 8;
    u16* BsT0 = Bs + t * 8;  u16* BsT1 = Bs + 2048 + t * 8;

    int kg = lane >> 4, lr = lane & 15;
    int cb = kg ^ ((lr >> 1) & 3);
    const u16* aF = As + (wm + lr) * 32 + cb * 8;
    const u16* bF = Bs + (wn + lr) * 32 + cb * 8;

    floatx4 acc[4][4] = {};
    for (int k0 = 0; k0 < K; k0 += 32) {
        __syncthreads();
        gload_lds16(Ap0 + k0, AsT0);
        gload_lds16(Ap1 + k0, AsT1);
        gload_lds16(Wp0 + k0, BsT0);
        gload_lds16(Wp1 + k0, BsT1);
        __syncthreads();
        short8 a[4], b[4];
        #pragma unroll
        for (int i = 0; i < 4; ++i) {
            a[i] = *(const short8*)(aF + i * 512);
            b[i] = *(const short8*)(bF + i * 512);
        }
        #pragma unroll
        for (int i = 0; i < 4; ++i)
            #pragma unroll
            for (int j = 0; j < 4; ++j)
                acc[i][j] = __builtin_amdgcn_mfma_f32_16x16x32_bf16(a[i], b[j], acc[i][j], 0, 0, 0);
    }
    int rm = (lane >> 4) * 4;
    #pragma unroll
    for (int j = 0; j < 4; ++j) {
        int n = n0 + wn + j * 16 + lr;
        float bv = HAS_BIAS ? bias[min(n, Ncols - 1)] : 0.f;
        #pragma unroll
        for (int i = 0; i < 4; ++i) {
            int mb = m0 + wm + i * 16 + rm;
            float vv[4];
            #pragma unroll
            for (int r = 0; r < 4; ++r) {
                float v = acc[i][j][r] + bv;
                if (EPI == 1) v = gelu_exact(v);
                else if (EPI == 2) v = fmaxf(v, 0.f);
                else if (EPI == 3) v = 1.f / (1.f + expf(-v));
                vv[r] = v;
            }
            #pragma unroll
            for (int r = 0; r < 4; ++r) {
                int m = mb + r;
                if (m < M && n < Ncols) {
                    float v = vv[r];
                    if (HAS_RES) v += bf1f(Res[(size_t)m * Ncols + n]);
                    if (STORE == 0) ((float*)Cout)[(size_t)m * Ncols + n] = v;
                    else            ((u16*)Cout)[(size_t)m * Ncols + n] = f2bf(v);
                }
            }
        }
    }
}

// ---- attention core: 4x4 per (sample, head), bf16 in/out ------------------
__global__ __launch_bounds__(256) void k_attn(const u16* __restrict__ QKV,
        u16* __restrict__ AO)
{
    int t = threadIdx.x;
    int h = t >> 6, lane = t & 63;
    size_t n = (size_t)blockIdx.x;
    const u16* base = QKV + n * 4 * 1536 + h * 128 + lane * 2;
    float2 q[4], k[4], v[4];
    #pragma unroll
    for (int b = 0; b < 4; ++b) {
        q[b] = bf2f2(*(const u32*)(base + b * 1536));
        k[b] = bf2f2(*(const u32*)(base + b * 1536 + 512));
        v[b] = bf2f2(*(const u32*)(base + b * 1536 + 1024));
    }
    const float scale = 0.08838834764831845f;  // 128^-0.5
    float sc[4][4];
    #pragma unroll
    for (int qb = 0; qb < 4; ++qb)
        #pragma unroll
        for (int kb = 0; kb < 4; ++kb) {
            float p = q[qb].x * k[kb].x + q[qb].y * k[kb].y;
            sc[qb][kb] = wave_sum(p) * scale;
        }
    #pragma unroll
    for (int qb = 0; qb < 4; ++qb) {
        float mx = fmaxf(fmaxf(sc[qb][0], sc[qb][1]), fmaxf(sc[qb][2], sc[qb][3]));
        float e0 = expf(sc[qb][0] - mx), e1 = expf(sc[qb][1] - mx);
        float e2 = expf(sc[qb][2] - mx), e3 = expf(sc[qb][3] - mx);
        float inv = 1.f / (e0 + e1 + e2 + e3);
        float ox = (e0 * v[0].x + e1 * v[1].x + e2 * v[2].x + e3 * v[3].x) * inv;
        float oy = (e0 * v[0].y + e1 * v[1].y + e2 * v[2].y + e3 * v[3].y) * inv;
        *(u32*)(AO + (n * 4 + qb) * 512 + h * 128 + lane * 2) = pack2(ox, oy);
    }
}

// ---- SE scale + GroupNorm + GELU + alpha-fuse -> FU bf16 ------------------
__global__ __launch_bounds__(256) void k_gnfin_fuse(
        const u16* __restrict__ XP, const u16* __restrict__ SIG,
        const float* __restrict__ gnw, const float* __restrict__ gnb,
        const u16* __restrict__ X2, const u16* __restrict__ X3,
        const float* __restrict__ alpha, int baseN, u16* __restrict__ FU)
{
    __shared__ float red[8];
    size_t ls = blockIdx.x;
    int t = threadIdx.x;
    int wave = t >> 6, lane = t & 63;
    int f = t * 2;
    const u16* p = XP + ls * 2048;
    float2 sg = bf2f2(*(const u32*)(SIG + ls * 512 + f));
    float2 xr[4];
    #pragma unroll
    for (int b = 0; b < 4; ++b) {
        float2 x = bf2f2(*(const u32*)(p + b * 512 + f));
        xr[b] = make_float2(x.x * sg.x, x.y * sg.y);
    }
    float s = 0.f;
    #pragma unroll
    for (int b = 0; b < 4; ++b) s += xr[b].x + xr[b].y;
    s = wave_sum(s);
    if (lane == 0) red[wave] = s;
    __syncthreads();
    float m = (red[0] + red[1] + red[2] + red[3]) * (1.f / 2048.f);
    float q = 0.f;
    #pragma unroll
    for (int b = 0; b < 4; ++b) {
        float dx = xr[b].x - m, dy = xr[b].y - m;
        q += dx * dx + dy * dy;
    }
    q = wave_sum(q);
    if (lane == 0) red[4 + wave] = q;
    __syncthreads();
    float rs = rsqrtf((red[4] + red[5] + red[6] + red[7]) * (1.f / 2048.f) + EPSV);
    const float* a = alpha + (size_t)(baseN + ls) * 3;
    float a0 = a[0], a1 = a[1], a2 = a[2];
    float gw0 = gnw[f], gw1 = gnw[f + 1], gb0 = gnb[f], gb1 = gnb[f + 1];
    #pragma unroll
    for (int b = 0; b < 4; ++b) {
        float x1a = gelu_exact((xr[b].x - m) * rs * gw0 + gb0);
        float x1b = gelu_exact((xr[b].y - m) * rs * gw1 + gb1);
        float2 v2 = bf2f2(*(const u32*)(X2 + (ls * 4 + b) * 512 + f));
        float2 v3 = bf2f2(*(const u32*)(X3 + (ls * 4 + b) * 512 + f));
        *(u32*)(FU + (ls * 4 + b) * 512 + f) =
            pack2(a0 * x1a + a1 * v2.x + a2 * v3.x,
                  a0 * x1b + a1 * v2.y + a2 * v3.y);
    }
}

// ---- gate stage 2: logits (3x128 dot) + softmax -> alpha ------------------
__global__ __launch_bounds__(256) void k_gate2(const u16* __restrict__ G1,
        const float* __restrict__ w2, const float* __restrict__ b2,
        float* __restrict__ alpha, int CH)
{
    int s = blockIdx.x * 256 + threadIdx.x;
    if (s >= CH) return;
    float l0 = b2[0], l1 = b2[1], l2 = b2[2];
    const u16* g = G1 + (size_t)s * 128;
    for (int j = 0; j < 128; j += 2) {
        float2 gg = bf2f2(*(const u32*)(g + j));
        l0 += gg.x * w2[j]       + gg.y * w2[j + 1];
        l1 += gg.x * w2[128 + j] + gg.y * w2[129 + j];
        l2 += gg.x * w2[256 + j] + gg.y * w2[257 + j];
    }
    float mx = fmaxf(l0, fmaxf(l1, l2));
    float e0 = expf(l0 - mx), e1 = expf(l1 - mx), e2 = expf(l2 - mx);
    float inv = 1.f / (e0 + e1 + e2);
    float* a = alpha + (size_t)s * 3;
    a[0] = e0 * inv; a[1] = e1 * inv; a[2] = e2 * inv;
}

// ---------------------------------------------------------------------------
extern "C" void kernel_launch(void* const* d_in, const int* in_sizes, int n_in,
                              void* d_out, int out_size, void* d_ws, size_t ws_size,
                              hipStream_t stream)
{
    (void)in_sizes; (void)n_in; (void)out_size;
    const float* br         = (const float*)d_in[0];
    const float* conv_pw_w  = (const float*)d_in[1];
    const float* conv_dw_w  = (const float*)d_in[2];
    const float* gn_w       = (const float*)d_in[3];
    const float* gn_b       = (const float*)d_in[4];
    const float* se_w1      = (const float*)d_in[5];
    const float* se_w2      = (const float*)d_in[6];
    const float* ln_attn_w  = (const float*)d_in[7];
    const float* ln_attn_b  = (const float*)d_in[8];
    const float* in_proj_w  = (const float*)d_in[9];
    const float* in_proj_b  = (const float*)d_in[10];
    const float* attn_out_w = (const float*)d_in[11];
    const float* attn_out_b = (const float*)d_in[12];
    const float* ln_ffn_w   = (const float*)d_in[13];
    const float* ln_ffn_b   = (const float*)d_in[14];
    const float* ffn_w1     = (const float*)d_in[15];
    const float* ffn_b1     = (const float*)d_in[16];
    const float* ffn_w2     = (const float*)d_in[17];
    const float* ffn_b2     = (const float*)d_in[18];
    const float* mlp_ln_w   = (const float*)d_in[19];
    const float* mlp_ln_b   = (const float*)d_in[20];
    const float* mlp_w1     = (const float*)d_in[21];
    const float* mlp_b1     = (const float*)d_in[22];
    const float* mlp_w2     = (const float*)d_in[23];
    const float* mlp_b2     = (const float*)d_in[24];
    const float* gate_w1    = (const float*)d_in[25];
    const float* gate_b1    = (const float*)d_in[26];
    const float* gate_w2    = (const float*)d_in[27];
    const float* gate_b2    = (const float*)d_in[28];
    const float* outp_w     = (const float*)d_in[29];
    float* out = (float*)d_out;

    char* ws = (char*)d_ws;
    float* alpha = (float*)ws;                       // N_TOT*3 fp32 = 196608 B
    u16* Wb = (u16*)(ws + 196608);                   // W_TOT bf16
    float* sA = (float*)(ws + 196608 + (size_t)W_TOT * 2);
    float* cA = sA + 1536;
    float* sF = cA + 1536;
    float* cF = sF + 1024;
    float* sM = cF + 1024;
    float* cM = sM + 1024;
    const size_t CB = 196608 + (size_t)W_TOT * 2 + 28672;   // 7958528
    int CH = N_TOT;
    while (CH > 64 && CB + (size_t)CH * 27072ULL > ws_size) CH >>= 1;

    // ws buffers (27072 B/sample)
    char* p = ws + CB;
    u16* Tb    = (u16*)p;    p += (size_t)CH * 4096;
    char* CTXS = p;          p += (size_t)CH * 2048;   // CTX; later S + SIGb
    u16* FU    = (u16*)p;    p += (size_t)CH * 4096;
    u16* QKV   = (u16*)p;    p += (size_t)CH * 12288;  // aliased as U
    u16* AOXP  = (u16*)p;    p += (size_t)CH * 4096;   // AO then XP
    u16* H1    = (u16*)p;    p += (size_t)CH * 128;
    u16* G1    = (u16*)p;    p += (size_t)CH * 256;
    float2* STA = (float2*)p; p += (size_t)CH * 32;
    float2* ST2 = (float2*)p; p += (size_t)CH * 32;
    u16* CTX  = (u16*)CTXS;
    u16* S    = (u16*)CTXS;                          // CH x 512 (first half)
    u16* SIGb = (u16*)(CTXS + (size_t)CH * 1024);    // CH x 512 (second half)
    u16* U    = QKV;

    // d_out as scratch: first half X2, second half T2/X3 (dead before out-proj)
    u16* O16 = (u16*)d_out;

    k_w2b<<<(W_TOT + 255) / 256, 256, 0, stream>>>(
        conv_pw_w, in_proj_w, attn_out_w, ffn_w1, ffn_w2, mlp_w1, mlp_w2,
        gate_w1, se_w1, se_w2, outp_w, Wb);
    k_wfold<<<3584, 256, 0, stream>>>(
        in_proj_w, ln_attn_w, ln_attn_b, in_proj_b,
        ffn_w1, ln_ffn_w, ln_ffn_b, ffn_b1,
        mlp_w1, mlp_ln_w, mlp_ln_b, mlp_b1,
        Wb, sA, cA, sF, cF, sM, cM);

    const int Ri = CH * 4;
    auto g128 = [](int M, int Nc) { return dim3((Nc + 127) / 128, (M + 127) / 128); };
    auto g256 = [](int M, int Nc) { return dim3((M / 256) * (Nc / 256)); };

    for (int c0 = 0; c0 < N_TOT; c0 += CH) {
        u16* X2b  = O16 + (size_t)c0 * 2048;                         // chunk-local rows
        u16* T2X3 = O16 + (size_t)N_TOT * 2048 + (size_t)c0 * 2048;  // T2 then X3

        k_prep_ln<<<CH / 4, 256, 0, stream>>>(br, c0, Tb, CTX, STA);
        // gate
        k_mfma_gemm<1, true, false, 1><<<g128(CH, 128), 256, 0, stream>>>(
            CTX, Wb + W_GATE1, gate_b1, nullptr, G1, CH, 128, 1024, 0);
        k_gate2<<<(CH + 255) / 256, 256, 0, stream>>>(G1, gate_w2, gate_b2,
                                                      alpha + (size_t)c0 * 3, CH);
        // attention expert (LN folded into in_proj weights)
        k_gemm256<0, false, false, 1, true><<<g256(Ri, 1536), 512, 0, stream>>>(
            Tb, Wb + W_INPROJ, nullptr, nullptr, QKV, 1536, 512, 0, 6,
            nullptr, nullptr, STA, sA, cA);
        k_attn<<<CH, 256, 0, stream>>>(QKV, AOXP);
        k_gemm256<0, true, true, 1, false><<<g256(Ri, 512), 512, 0, stream>>>(
            AOXP, Wb + W_ATTNO, attn_out_b, Tb, T2X3, 512, 512, 0, 2,
            nullptr, nullptr, nullptr, nullptr, nullptr);
        k_lnstats<<<Ri / 4, 256, 0, stream>>>(T2X3, ST2);
        k_gemm256<1, false, false, 1, true><<<g256(Ri, 1024), 512, 0, stream>>>(
            T2X3, Wb + W_FFN1, nullptr, nullptr, U, 1024, 512, 0, 4,
            nullptr, nullptr, ST2, sF, cF);
        k_gemm256<0, true, true, 1, false><<<g256(Ri, 512), 512, 0, stream>>>(
            U, Wb + W_FFN2, ffn_b2, T2X3, X2b, 512, 1024, 0, 2,
            nullptr, nullptr, nullptr, nullptr, nullptr);
        // MLP expert (LN folded into mlp1 weights; X3 overwrites T2)
        k_gemm256<1, false, false, 1, true><<<g256(Ri, 1024), 512, 0, stream>>>(
            Tb, Wb + W_MLP1, nullptr, nullptr, U, 1024, 512, 0, 4,
            nullptr, nullptr, STA, sM, cM);
        k_gemm256<0, true, true, 1, false><<<g256(Ri, 512), 512, 0, stream>>>(
            U, Wb + W_MLP2, mlp_b2, Tb, T2X3, 512, 1024, 0, 2,
            nullptr, nullptr, nullptr, nullptr, nullptr);
        // conv expert: pw GEMM + fused depthwise + SE squeeze
        k_gemm256<0, false, false, 3, false><<<g256(Ri, 512), 512, 0, stream>>>(
            Tb, Wb + W_CONVPW, nullptr, nullptr, AOXP, 512, 512, 0, 2,
            conv_dw_w, S, nullptr, nullptr, nullptr);
        k_mfma_gemm<2, false, false, 1><<<g128(CH, 64), 256, 0, stream>>>(
            S, Wb + W_SE1, nullptr, nullptr, H1, CH, 64, 512, 0);
        k_mfma_gemm<3, false, false, 1><<<g128(CH, 512), 256, 0, stream>>>(
            H1, Wb + W_SE2, nullptr, nullptr, SIGb, CH, 512, 64, 0);
        // GN + gelu + alpha-fuse
        k_gnfin_fuse<<<CH, 256, 0, stream>>>(AOXP, SIGb, gn_w, gn_b,
                                             X2b, T2X3, alpha, c0, FU);
        // output projection, float4 scatter to (n, o, b)
        k_gemm256<0, false, false, 2, false><<<g256(Ri, 512), 512, 0, stream>>>(
            FU, Wb + W_OUTP, nullptr, nullptr, out, 512, 512, c0, 2,
            nullptr, nullptr, nullptr, nullptr, nullptr);
    }
}

// Round 14
// 990.260 us; speedup vs baseline: 4.8051x; 1.0350x over previous
//
#include <hip/hip_runtime.h>
#include <math.h>

// ---------------------------------------------------------------------------
// ParallelExpertsMixer — Round 14: R13 with the redundant inner barrier
// removed from each GEMM phase (8 -> 4 barriers per K-tile). Within a tile,
// ds_reads hit buf `cur` and stages hit `cur^1` (disjoint); across tiles the
// phase-top VMW+BARR orders region reuse. Waits/addressing byte-identical.
// ---------------------------------------------------------------------------

#define N_TOT 16384
#define EPSV 1e-5f

typedef unsigned short u16;
typedef unsigned int   u32;
typedef __attribute__((ext_vector_type(8))) short  short8;
typedef __attribute__((ext_vector_type(4))) float  floatx4;

__device__ __forceinline__ float gelu_exact(float x) {
    return 0.5f * x * (1.0f + erff(x * 0.70710678118654752440f));
}
__device__ __forceinline__ float wave_sum(float v) {
    #pragma unroll
    for (int o = 32; o > 0; o >>= 1) v += __shfl_xor(v, o);
    return v;
}
__device__ __forceinline__ u16 f2bf(float f) {
    u32 u = __float_as_uint(f);
    return (u16)((u + 0x7fffu + ((u >> 16) & 1u)) >> 16);
}
__device__ __forceinline__ u32 pack2(float lo, float hi) {
    return (u32)f2bf(lo) | ((u32)f2bf(hi) << 16);
}
__device__ __forceinline__ float bf1f(u16 u) { return __uint_as_float((u32)u << 16); }
__device__ __forceinline__ float2 bf2f2(u32 u) {
    return make_float2(__uint_as_float(u << 16), __uint_as_float(u & 0xffff0000u));
}
__device__ __forceinline__ void gload_lds16(const void* g, void* l) {
    __builtin_amdgcn_global_load_lds(
        (const __attribute__((address_space(1))) unsigned int*)g,
        (__attribute__((address_space(3))) unsigned int*)l, 16, 0, 0);
}

#define BARR() asm volatile("s_barrier" ::: "memory")
#define VMW(N) asm volatile("s_waitcnt vmcnt(" #N ")" ::: "memory")

// ---- bf16 weight conversion (once per launch) -----------------------------
#define W_CONVPW 0
#define W_INPROJ 262144
#define W_ATTNO  1048576
#define W_FFN1   1310720
#define W_FFN2   1835008
#define W_MLP1   2359296
#define W_MLP2   2883584
#define W_GATE1  3407872
#define W_SE1    3538944
#define W_SE2    3571712
#define W_OUTP   3604480
#define W_TOT    3866624

__global__ __launch_bounds__(256) void k_w2b(
        const float* __restrict__ p0, const float* __restrict__ p1,
        const float* __restrict__ p2, const float* __restrict__ p3,
        const float* __restrict__ p4, const float* __restrict__ p5,
        const float* __restrict__ p6, const float* __restrict__ p7,
        const float* __restrict__ p8, const float* __restrict__ p9,
        const float* __restrict__ p10, u16* __restrict__ dst)
{
    int i = blockIdx.x * 256 + threadIdx.x;
    if (i >= W_TOT) return;
    const float* s; int off;
    if      (i < W_INPROJ) { s = p0;  off = W_CONVPW; }
    else if (i < W_ATTNO)  { s = p1;  off = W_INPROJ; }
    else if (i < W_FFN1)   { s = p2;  off = W_ATTNO; }
    else if (i < W_FFN2)   { s = p3;  off = W_FFN1; }
    else if (i < W_MLP1)   { s = p4;  off = W_FFN2; }
    else if (i < W_MLP2)   { s = p5;  off = W_MLP1; }
    else if (i < W_GATE1)  { s = p6;  off = W_MLP2; }
    else if (i < W_SE1)    { s = p7;  off = W_GATE1; }
    else if (i < W_SE2)    { s = p8;  off = W_SE1; }
    else if (i < W_OUTP)   { s = p9;  off = W_SE2; }
    else                   { s = p10; off = W_OUTP; }
    dst[i] = f2bf(s[i - off]);
}

// ---- fold LN into weights: W' = lnw*W (bf16), s_n = sum(W'_n),
//      c_n = lnb.W_n + bias_n.  One block per output row (3584 rows, K=512).
__global__ __launch_bounds__(256) void k_wfold(
        const float* __restrict__ wA, const float* __restrict__ lnwA,
        const float* __restrict__ lnbA, const float* __restrict__ biasA,
        const float* __restrict__ wF, const float* __restrict__ lnwF,
        const float* __restrict__ lnbF, const float* __restrict__ biasF,
        const float* __restrict__ wM, const float* __restrict__ lnwM,
        const float* __restrict__ lnbM, const float* __restrict__ biasM,
        u16* __restrict__ Wb,
        float* __restrict__ sA, float* __restrict__ cA,
        float* __restrict__ sF, float* __restrict__ cF,
        float* __restrict__ sM, float* __restrict__ cM)
{
    __shared__ float rs_[4], rc_[4];
    int r = blockIdx.x, t = threadIdx.x;
    const float *W, *lnw, *lnb, *bias;
    u16* dst; float *sp, *cp; int row;
    if (r < 1536)      { W = wA; lnw = lnwA; lnb = lnbA; bias = biasA;
                         dst = Wb + W_INPROJ; sp = sA; cp = cA; row = r; }
    else if (r < 2560) { W = wF; lnw = lnwF; lnb = lnbF; bias = biasF;
                         dst = Wb + W_FFN1;   sp = sF; cp = cF; row = r - 1536; }
    else               { W = wM; lnw = lnwM; lnb = lnbM; bias = biasM;
                         dst = Wb + W_MLP1;   sp = sM; cp = cM; row = r - 2560; }
    const float* wr = W + (size_t)row * 512;
    float s = 0.f, c = 0.f;
    #pragma unroll
    for (int i = 0; i < 2; ++i) {
        int k = t + i * 256;
        float wv = lnw[k] * wr[k];
        dst[(size_t)row * 512 + k] = f2bf(wv);
        s += wv;
        c += lnb[k] * wr[k];
    }
    s = wave_sum(s); c = wave_sum(c);
    if ((t & 63) == 0) { rs_[t >> 6] = s; rc_[t >> 6] = c; }
    __syncthreads();
    if (t == 0) {
        sp[row] = rs_[0] + rs_[1] + rs_[2] + rs_[3];
        cp[row] = rc_[0] + rc_[1] + rc_[2] + rc_[3] + bias[row];
    }
}

// ---- prep (4 samples/block): branches -> Tb + CTX + LN stats (rs, rs*m) ---
__global__ __launch_bounds__(256) void k_prep_ln(const float* __restrict__ br,
        int baseN, u16* __restrict__ Tb, u16* __restrict__ CTX,
        float2* __restrict__ STA)
{
    __shared__ float lds[4][4][516];
    int t = threadIdx.x;
    int s0 = blockIdx.x * 4;
    #pragma unroll
    for (int s = 0; s < 4; ++s) {
        const float* p = br + (size_t)(baseN + s0 + s) * 2048;
        u16* c = CTX + (size_t)(s0 + s) * 1024;
        #pragma unroll
        for (int i = 0; i < 2; ++i) {
            int f = t + i * 256;
            float4 v = *(const float4*)(p + f * 4);
            lds[s][0][f] = v.x; lds[s][1][f] = v.y; lds[s][2][f] = v.z; lds[s][3][f] = v.w;
            c[f]       = f2bf((v.x + v.y + v.z + v.w) * 0.25f);
            c[512 + f] = f2bf(fmaxf(fmaxf(v.x, v.y), fmaxf(v.z, v.w)));
        }
    }
    __syncthreads();
    int wv = t >> 6, lane = t & 63, f0 = lane * 8;
    #pragma unroll
    for (int p4i = 0; p4i < 4; ++p4i) {
        int idx = wv * 4 + p4i;
        int s = idx >> 2, b = idx & 3;
        float xv[8];
        #pragma unroll
        for (int i = 0; i < 8; ++i) xv[i] = lds[s][b][f0 + i];
        float sm = 0.f;
        #pragma unroll
        for (int i = 0; i < 8; ++i) sm += xv[i];
        sm = wave_sum(sm);
        float m = sm * (1.f / 512.f);
        float q = 0.f;
        #pragma unroll
        for (int i = 0; i < 8; ++i) { float d = xv[i] - m; q += d * d; }
        q = wave_sum(q);
        float rs = rsqrtf(q * (1.f / 512.f) + EPSV);
        size_t row = (size_t)(s0 + s) * 4 + b;
        *(uint4*)(Tb + row * 512 + f0) = make_uint4(pack2(xv[0], xv[1]), pack2(xv[2], xv[3]),
                                                    pack2(xv[4], xv[5]), pack2(xv[6], xv[7]));
        if (lane == 0) STA[row] = make_float2(rs, rs * m);
    }
}

// ---- LN row stats only (rs, rs*m) from bf16 rows --------------------------
__global__ __launch_bounds__(256) void k_lnstats(const u16* __restrict__ X,
        float2* __restrict__ ST)
{
    int t = threadIdx.x;
    int wave = t >> 6, lane = t & 63;
    size_t r = (size_t)blockIdx.x * 4 + wave;
    int f0 = lane * 8;
    uint4 raw = *(const uint4*)(X + r * 512 + f0);
    float xv[8];
    { float2 a = bf2f2(raw.x); xv[0] = a.x; xv[1] = a.y; }
    { float2 a = bf2f2(raw.y); xv[2] = a.x; xv[3] = a.y; }
    { float2 a = bf2f2(raw.z); xv[4] = a.x; xv[5] = a.y; }
    { float2 a = bf2f2(raw.w); xv[6] = a.x; xv[7] = a.y; }
    float s = 0.f;
    #pragma unroll
    for (int i = 0; i < 8; ++i) s += xv[i];
    s = wave_sum(s);
    float m = s * (1.f / 512.f);
    float q = 0.f;
    #pragma unroll
    for (int i = 0; i < 8; ++i) { float d = xv[i] - m; q += d * d; }
    q = wave_sum(q);
    float rs = rsqrtf(q * (1.f / 512.f) + EPSV);
    if (lane == 0) ST[r] = make_float2(rs, rs * m);
}

// ===========================================================================
// 256x256 4-phase/K-tile GEMM. BK=64, 512 thr / 8 waves, per-wave 64x32
// piece of EACH 128x128 C-quadrant. LDS: 2 buf x [Ah0|Ah1|Bh0|Bh1] x 16KB.
// ONE barrier per phase (top, after VMW): within a tile ds_reads hit buf
// `cur`, stages hit `cur^1`; region reuse across tiles is ordered by the
// phase-top VMW+BARR (reads complete before each wave's MFMA issues, which
// precedes its barrier arrival). Steady VMW(4),(4),(4),-; drain (4),(2),(0),-.
// STORE: 1 bf16 (+opt residual), 2 f4-scatter(out), 3 dw-conv+squeeze.
// LNFOLD (STORE=1): v = acc*rs[m] - (rs*m)[m]*s[n] + c[n], hoisted loads.
// ===========================================================================

#define STAGE(SLOT, TILE) do {                                                \
    const u16* sm_ = ((SLOT) < 2) ? A : W;                                    \
    int rb_ = (((SLOT) < 2) ? m0 : n0) + ((SLOT) & 1) * 128;                  \
    int k0_ = (TILE) * 64;                                                    \
    u16* db_ = lds + (((TILE) & 1) * 32768) + (SLOT) * 8192;                  \
    _Pragma("unroll")                                                         \
    for (int l_ = 0; l_ < 2; ++l_) {                                          \
        int L_ = (l_ * 512 + tid) * 16;                                       \
        int row_ = L_ >> 7;                                                   \
        int ir_ = (L_ & 127) ^ ((row_ & 7) << 4);                             \
        gload_lds16(sm_ + (size_t)(rb_ + row_) * K + k0_ + (ir_ >> 1),        \
                    db_ + (L_ >> 1));                                         \
    } } while (0)

#define QUAD(MH, NH, STAGESTMT) do {                                          \
    const u16* lb_ = lds + cur * 32768;                                       \
    short8 a_[4][2], b_[2][2];                                                \
    _Pragma("unroll")                                                         \
    for (int mi = 0; mi < 4; ++mi)                                            \
        _Pragma("unroll")                                                     \
        for (int ks = 0; ks < 2; ++ks)                                        \
            a_[mi][ks] = *(const short8*)(lb_ + (MH) * 8192 + arow[mi] + gcol[ks]); \
    _Pragma("unroll")                                                         \
    for (int ni = 0; ni < 2; ++ni)                                            \
        _Pragma("unroll")                                                     \
        for (int ks = 0; ks < 2; ++ks)                                        \
            b_[ni][ks] = *(const short8*)(lb_ + 16384 + (NH) * 8192 + brow[ni] + gcol[ks]); \
    STAGESTMT;                                                                \
    __builtin_amdgcn_s_setprio(1);                                            \
    _Pragma("unroll")                                                         \
    for (int ks = 0; ks < 2; ++ks)                                            \
        _Pragma("unroll")                                                     \
        for (int mi = 0; mi < 4; ++mi)                                        \
            _Pragma("unroll")                                                 \
            for (int ni = 0; ni < 2; ++ni)                                    \
                acc[MH][NH][mi][ni] = __builtin_amdgcn_mfma_f32_16x16x32_bf16( \
                    a_[mi][ks], b_[ni][ks], acc[MH][NH][mi][ni], 0, 0, 0);    \
    __builtin_amdgcn_s_setprio(0);                                            \
} while (0)

template<int EPI, bool HAS_BIAS, bool HAS_RES, int STORE, bool LNFOLD>
__global__ __launch_bounds__(512, 2) void k_gemm256(
        const u16* __restrict__ A, const u16* __restrict__ W,
        const float* __restrict__ bias, const u16* __restrict__ Res,
        void* __restrict__ Cout, int Ncols, int K, int baseN, int nTX,
        const float* __restrict__ dwp, u16* __restrict__ Sout,
        const float2* __restrict__ Astat, const float* __restrict__ Scol,
        const float* __restrict__ Ccol)
{
    __shared__ __align__(16) u16 lds[65536];   // 128 KiB
    const int tid = threadIdx.x;
    const int wid = tid >> 6, lane = tid & 63;
    const int lr = lane & 15, kg = lane >> 4;
    const int wm = (wid >> 2) * 64;    // M offset within each M-half
    const int wn = (wid & 3) * 32;     // N offset within each N-half

    // bijective XCD swizzle (m204)
    int nwg = gridDim.x, orig = blockIdx.x;
    int q = nwg >> 3, r = nwg & 7;
    int xcd = orig & 7, lin = orig >> 3;
    int wgid = (xcd < r ? xcd * (q + 1) : r * (q + 1) + (xcd - r) * q) + lin;
    const int m0 = (wgid / nTX) * 256, n0 = (wgid % nTX) * 256;

    // fragment LDS element offsets (within one half-tile)
    int arow[4], brow[2], gcol[2];
    #pragma unroll
    for (int mi = 0; mi < 4; ++mi) arow[mi] = (wm + mi * 16 + lr) * 64;
    #pragma unroll
    for (int ni = 0; ni < 2; ++ni) brow[ni] = (wn + ni * 16 + lr) * 64;
    #pragma unroll
    for (int ks = 0; ks < 2; ++ks) gcol[ks] = (ks * 32 + kg * 8) ^ ((lr & 7) << 3);

    floatx4 acc[2][2][4][2] = {};

    // prologue: stage K-tile 0 in consumption order
    STAGE(0, 0); STAGE(2, 0); STAGE(1, 0); STAGE(3, 0);

    const int NT = K >> 6;
    int cur = 0;
    for (int t = 0; t < NT - 1; ++t) {
        int nx = t + 1;
        VMW(4); BARR(); QUAD(0, 0, STAGE(0, nx));
        VMW(4); BARR(); QUAD(1, 0, STAGE(2, nx));
        VMW(4); BARR(); QUAD(0, 1, STAGE(1, nx));
                BARR(); QUAD(1, 1, STAGE(3, nx));
        cur ^= 1;
    }
    // last K-tile: counted drain
    VMW(4); BARR(); QUAD(0, 0, (void)0);
    VMW(2); BARR(); QUAD(1, 0, (void)0);
    VMW(0); BARR(); QUAD(0, 1, (void)0);
            BARR(); QUAD(1, 1, (void)0);

    int rm = kg * 4;
    if (LNFOLD) {
        // hoisted epilogue: s,c for this thread's 4 n-values; row stats per (MH,mi)
        float sv[4], cv[4];
        int nidx[4];
        #pragma unroll
        for (int g = 0; g < 4; ++g) {   // g = NH*2 + ni
            int n = n0 + (g >> 1) * 128 + wn + (g & 1) * 16 + lr;
            nidx[g] = n;
            sv[g] = Scol[n];
            cv[g] = Ccol[n];
        }
        #pragma unroll
        for (int MH = 0; MH < 2; ++MH)
        #pragma unroll
        for (int mi = 0; mi < 4; ++mi) {
            int mb = m0 + MH * 128 + wm + mi * 16 + rm;
            float4 stA = *(const float4*)((const float*)(Astat + mb));      // rows mb,mb+1
            float4 stB = *(const float4*)((const float*)(Astat + mb + 2)); // rows mb+2,mb+3
            float rsv[4] = {stA.x, stA.z, stB.x, stB.z};
            float rmv[4] = {stA.y, stA.w, stB.y, stB.w};
            #pragma unroll
            for (int g = 0; g < 4; ++g) {
                int NH = g >> 1, ni = g & 1;
                #pragma unroll
                for (int rr = 0; rr < 4; ++rr) {
                    float v = acc[MH][NH][mi][ni][rr] * rsv[rr] - rmv[rr] * sv[g] + cv[g];
                    if (EPI == 1) v = gelu_exact(v);
                    ((u16*)Cout)[(size_t)(mb + rr) * Ncols + nidx[g]] = f2bf(v);
                }
            }
        }
        return;
    }

    // epilogue: D col = lane&15 (n), row = kg*4 + reg (m)
    #pragma unroll
    for (int MH = 0; MH < 2; ++MH)
    #pragma unroll
    for (int NH = 0; NH < 2; ++NH)
    #pragma unroll
    for (int ni = 0; ni < 2; ++ni) {
        int n = n0 + NH * 128 + wn + ni * 16 + lr;
        float bv = HAS_BIAS ? bias[n] : 0.f;
        float w0, w1, w2;
        if (STORE == 3) { w0 = dwp[n * 3]; w1 = dwp[n * 3 + 1]; w2 = dwp[n * 3 + 2]; }
        #pragma unroll
        for (int mi = 0; mi < 4; ++mi) {
            int mb = m0 + MH * 128 + wm + mi * 16 + rm;
            float vv[4];
            #pragma unroll
            for (int rr = 0; rr < 4; ++rr) {
                float v = acc[MH][NH][mi][ni][rr] + bv;
                if (EPI == 1) v = gelu_exact(v);
                else if (EPI == 2) v = fmaxf(v, 0.f);
                else if (EPI == 3) v = 1.f / (1.f + expf(-v));
                vv[rr] = v;
            }
            if (STORE == 2) {
                *(float4*)((float*)Cout + (size_t)(baseN + (mb >> 2)) * 2048 + (size_t)n * 4)
                    = make_float4(vv[0], vv[1], vv[2], vv[3]);
            } else if (STORE == 3) {
                // depthwise k=3 over tokens (rows mb..mb+3 = one sample) + squeeze
                float y0 = w1 * vv[0] + w2 * vv[1];
                float y1 = w0 * vv[0] + w1 * vv[1] + w2 * vv[2];
                float y2 = w0 * vv[1] + w1 * vv[2] + w2 * vv[3];
                float y3 = w0 * vv[2] + w1 * vv[3];
                u16* xp = (u16*)Cout + (size_t)mb * Ncols + n;
                xp[0] = f2bf(y0);
                xp[Ncols] = f2bf(y1);
                xp[2 * Ncols] = f2bf(y2);
                xp[3 * Ncols] = f2bf(y3);
                Sout[(size_t)(mb >> 2) * Ncols + n] = f2bf((y0 + y1 + y2 + y3) * 0.25f);
            } else {
                #pragma unroll
                for (int rr = 0; rr < 4; ++rr) {
                    float v = vv[rr];
                    if (HAS_RES) v += bf1f(Res[(size_t)(mb + rr) * Ncols + n]);
                    ((u16*)Cout)[(size_t)(mb + rr) * Ncols + n] = f2bf(v);
                }
            }
        }
    }
}

// ---- 128^2 MFMA GEMM (small shapes: gate1, se1, se2) ----------------------
template<int EPI, bool HAS_BIAS, bool HAS_RES, int STORE>
__global__ __launch_bounds__(256) void k_mfma_gemm(
        const u16* __restrict__ A, const u16* __restrict__ W,
        const float* __restrict__ bias, const u16* __restrict__ Res,
        void* __restrict__ Cout, int M, int Ncols, int K, int baseN)
{
    __shared__ u16 As[128 * 32];
    __shared__ u16 Bs[128 * 32];
    int t = threadIdx.x;
    int wid = t >> 6, lane = t & 63;
    int wm = (wid >> 1) * 64, wn = (wid & 1) * 64;
    int m0 = blockIdx.y * 128, n0 = blockIdx.x * 128;
    int srow = t >> 2;
    int scol = (((t & 3) ^ ((srow >> 1) & 3)) * 8);
    int aR0 = min(m0 + srow, M - 1),      aR1 = min(m0 + 64 + srow, M - 1);
    int bR0 = min(n0 + srow, Ncols - 1),  bR1 = min(n0 + 64 + srow, Ncols - 1);
    const u16* Ap0 = A + (size_t)aR0 * K + scol;
    const u16* Ap1 = A + (size_t)aR1 * K + scol;
    const u16* Wp0 = W + (size_t)bR0 * K + scol;
    const u16* Wp1 = W + (size_t)bR1 * K + scol;
    u16* AsT0 = As + t * 8;  u16* AsT1 = As + 2048 + t * 8;
    u16* BsT0 = Bs + t * 8;  u16* BsT1 = Bs + 2048 + t * 8;

    int kg = lane >> 4, lr = lane & 15;
    int cb = kg ^ ((lr >> 1) & 3);
    const u16* aF = As + (wm + lr) * 32 + cb * 8;
    const u16* bF = Bs + (wn + lr) * 32 + cb * 8;

    floatx4 acc[4][4] = {};
    for (int k0 = 0; k0 < K; k0 += 32) {
        __syncthreads();
        gload_lds16(Ap0 + k0, AsT0);
        gload_lds16(Ap1 + k0, AsT1);
        gload_lds16(Wp0 + k0, BsT0);
        gload_lds16(Wp1 + k0, BsT1);
        __syncthreads();
        short8 a[4], b[4];
        #pragma unroll
        for (int i = 0; i < 4; ++i) {
            a[i] = *(const short8*)(aF + i * 512);
            b[i] = *(const short8*)(bF + i * 512);
        }
        #pragma unroll
        for (int i = 0; i < 4; ++i)
            #pragma unroll
            for (int j = 0; j < 4; ++j)
                acc[i][j] = __builtin_amdgcn_mfma_f32_16x16x32_bf16(a[i], b[j], acc[i][j], 0, 0, 0);
    }
    int rm = (lane >> 4) * 4;
    #pragma unroll
    for (int j = 0; j < 4; ++j) {
        int n = n0 + wn + j * 16 + lr;
        float bv = HAS_BIAS ? bias[min(n, Ncols - 1)] : 0.f;
        #pragma unroll
        for (int i = 0; i < 4; ++i) {
            int mb = m0 + wm + i * 16 + rm;
            float vv[4];
            #pragma unroll
            for (int r = 0; r < 4; ++r) {
                float v = acc[i][j][r] + bv;
                if (EPI == 1) v = gelu_exact(v);
                else if (EPI == 2) v = fmaxf(v, 0.f);
                else if (EPI == 3) v = 1.f / (1.f + expf(-v));
                vv[r] = v;
            }
            #pragma unroll
            for (int r = 0; r < 4; ++r) {
                int m = mb + r;
                if (m < M && n < Ncols) {
                    float v = vv[r];
                    if (HAS_RES) v += bf1f(Res[(size_t)m * Ncols + n]);
                    if (STORE == 0) ((float*)Cout)[(size_t)m * Ncols + n] = v;
                    else            ((u16*)Cout)[(size_t)m * Ncols + n] = f2bf(v);
                }
            }
        }
    }
}

// ---- attention core: 4x4 per (sample, head), bf16 in/out ------------------
__global__ __launch_bounds__(256) void k_attn(const u16* __restrict__ QKV,
        u16* __restrict__ AO)
{
    int t = threadIdx.x;
    int h = t >> 6, lane = t & 63;
    size_t n = (size_t)blockIdx.x;
    const u16* base = QKV + n * 4 * 1536 + h * 128 + lane * 2;
    float2 q[4], k[4], v[4];
    #pragma unroll
    for (int b = 0; b < 4; ++b) {
        q[b] = bf2f2(*(const u32*)(base + b * 1536));
        k[b] = bf2f2(*(const u32*)(base + b * 1536 + 512));
        v[b] = bf2f2(*(const u32*)(base + b * 1536 + 1024));
    }
    const float scale = 0.08838834764831845f;  // 128^-0.5
    float sc[4][4];
    #pragma unroll
    for (int qb = 0; qb < 4; ++qb)
        #pragma unroll
        for (int kb = 0; kb < 4; ++kb) {
            float p = q[qb].x * k[kb].x + q[qb].y * k[kb].y;
            sc[qb][kb] = wave_sum(p) * scale;
        }
    #pragma unroll
    for (int qb = 0; qb < 4; ++qb) {
        float mx = fmaxf(fmaxf(sc[qb][0], sc[qb][1]), fmaxf(sc[qb][2], sc[qb][3]));
        float e0 = expf(sc[qb][0] - mx), e1 = expf(sc[qb][1] - mx);
        float e2 = expf(sc[qb][2] - mx), e3 = expf(sc[qb][3] - mx);
        float inv = 1.f / (e0 + e1 + e2 + e3);
        float ox = (e0 * v[0].x + e1 * v[1].x + e2 * v[2].x + e3 * v[3].x) * inv;
        float oy = (e0 * v[0].y + e1 * v[1].y + e2 * v[2].y + e3 * v[3].y) * inv;
        *(u32*)(AO + (n * 4 + qb) * 512 + h * 128 + lane * 2) = pack2(ox, oy);
    }
}

// ---- SE scale + GroupNorm + GELU + alpha-fuse -> FU bf16 ------------------
__global__ __launch_bounds__(256) void k_gnfin_fuse(
        const u16* __restrict__ XP, const u16* __restrict__ SIG,
        const float* __restrict__ gnw, const float* __restrict__ gnb,
        const u16* __restrict__ X2, const u16* __restrict__ X3,
        const float* __restrict__ alpha, int baseN, u16* __restrict__ FU)
{
    __shared__ float red[8];
    size_t ls = blockIdx.x;
    int t = threadIdx.x;
    int wave = t >> 6, lane = t & 63;
    int f = t * 2;
    const u16* p = XP + ls * 2048;
    float2 sg = bf2f2(*(const u32*)(SIG + ls * 512 + f));
    float2 xr[4];
    #pragma unroll
    for (int b = 0; b < 4; ++b) {
        float2 x = bf2f2(*(const u32*)(p + b * 512 + f));
        xr[b] = make_float2(x.x * sg.x, x.y * sg.y);
    }
    float s = 0.f;
    #pragma unroll
    for (int b = 0; b < 4; ++b) s += xr[b].x + xr[b].y;
    s = wave_sum(s);
    if (lane == 0) red[wave] = s;
    __syncthreads();
    float m = (red[0] + red[1] + red[2] + red[3]) * (1.f / 2048.f);
    float q = 0.f;
    #pragma unroll
    for (int b = 0; b < 4; ++b) {
        float dx = xr[b].x - m, dy = xr[b].y - m;
        q += dx * dx + dy * dy;
    }
    q = wave_sum(q);
    if (lane == 0) red[4 + wave] = q;
    __syncthreads();
    float rs = rsqrtf((red[4] + red[5] + red[6] + red[7]) * (1.f / 2048.f) + EPSV);
    const float* a = alpha + (size_t)(baseN + ls) * 3;
    float a0 = a[0], a1 = a[1], a2 = a[2];
    float gw0 = gnw[f], gw1 = gnw[f + 1], gb0 = gnb[f], gb1 = gnb[f + 1];
    #pragma unroll
    for (int b = 0; b < 4; ++b) {
        float x1a = gelu_exact((xr[b].x - m) * rs * gw0 + gb0);
        float x1b = gelu_exact((xr[b].y - m) * rs * gw1 + gb1);
        float2 v2 = bf2f2(*(const u32*)(X2 + (ls * 4 + b) * 512 + f));
        float2 v3 = bf2f2(*(const u32*)(X3 + (ls * 4 + b) * 512 + f));
        *(u32*)(FU + (ls * 4 + b) * 512 + f) =
            pack2(a0 * x1a + a1 * v2.x + a2 * v3.x,
                  a0 * x1b + a1 * v2.y + a2 * v3.y);
    }
}

// ---- gate stage 2: logits (3x128 dot) + softmax -> alpha ------------------
__global__ __launch_bounds__(256) void k_gate2(const u16* __restrict__ G1,
        const float* __restrict__ w2, const float* __restrict__ b2,
        float* __restrict__ alpha, int CH)
{
    int s = blockIdx.x * 256 + threadIdx.x;
    if (s >= CH) return;
    float l0 = b2[0], l1 = b2[1], l2 = b2[2];
    const u16* g = G1 + (size_t)s * 128;
    for (int j = 0; j < 128; j += 2) {
        float2 gg = bf2f2(*(const u32*)(g + j));
        l0 += gg.x * w2[j]       + gg.y * w2[j + 1];
        l1 += gg.x * w2[128 + j] + gg.y * w2[129 + j];
        l2 += gg.x * w2[256 + j] + gg.y * w2[257 + j];
    }
    float mx = fmaxf(l0, fmaxf(l1, l2));
    float e0 = expf(l0 - mx), e1 = expf(l1 - mx), e2 = expf(l2 - mx);
    float inv = 1.f / (e0 + e1 + e2);
    float* a = alpha + (size_t)s * 3;
    a[0] = e0 * inv; a[1] = e1 * inv; a[2] = e2 * inv;
}

// ---------------------------------------------------------------------------
extern "C" void kernel_launch(void* const* d_in, const int* in_sizes, int n_in,
                              void* d_out, int out_size, void* d_ws, size_t ws_size,
                              hipStream_t stream)
{
    (void)in_sizes; (void)n_in; (void)out_size;
    const float* br         = (const float*)d_in[0];
    const float* conv_pw_w  = (const float*)d_in[1];
    const float* conv_dw_w  = (const float*)d_in[2];
    const float* gn_w       = (const float*)d_in[3];
    const float* gn_b       = (const float*)d_in[4];
    const float* se_w1      = (const float*)d_in[5];
    const float* se_w2      = (const float*)d_in[6];
    const float* ln_attn_w  = (const float*)d_in[7];
    const float* ln_attn_b  = (const float*)d_in[8];
    const float* in_proj_w  = (const float*)d_in[9];
    const float* in_proj_b  = (const float*)d_in[10];
    const float* attn_out_w = (const float*)d_in[11];
    const float* attn_out_b = (const float*)d_in[12];
    const float* ln_ffn_w   = (const float*)d_in[13];
    const float* ln_ffn_b   = (const float*)d_in[14];
    const float* ffn_w1     = (const float*)d_in[15];
    const float* ffn_b1     = (const float*)d_in[16];
    const float* ffn_w2     = (const float*)d_in[17];
    const float* ffn_b2     = (const float*)d_in[18];
    const float* mlp_ln_w   = (const float*)d_in[19];
    const float* mlp_ln_b   = (const float*)d_in[20];
    const float* mlp_w1     = (const float*)d_in[21];
    const float* mlp_b1     = (const float*)d_in[22];
    const float* mlp_w2     = (const float*)d_in[23];
    const float* mlp_b2     = (const float*)d_in[24];
    const float* gate_w1    = (const float*)d_in[25];
    const float* gate_b1    = (const float*)d_in[26];
    const float* gate_w2    = (const float*)d_in[27];
    const float* gate_b2    = (const float*)d_in[28];
    const float* outp_w     = (const float*)d_in[29];
    float* out = (float*)d_out;

    char* ws = (char*)d_ws;
    float* alpha = (float*)ws;                       // N_TOT*3 fp32 = 196608 B
    u16* Wb = (u16*)(ws + 196608);                   // W_TOT bf16
    float* sA = (float*)(ws + 196608 + (size_t)W_TOT * 2);
    float* cA = sA + 1536;
    float* sF = cA + 1536;
    float* cF = sF + 1024;
    float* sM = cF + 1024;
    float* cM = sM + 1024;
    const size_t CB = 196608 + (size_t)W_TOT * 2 + 28672;   // 7958528
    int CH = N_TOT;
    while (CH > 64 && CB + (size_t)CH * 27072ULL > ws_size) CH >>= 1;

    // ws buffers (27072 B/sample)
    char* p = ws + CB;
    u16* Tb    = (u16*)p;    p += (size_t)CH * 4096;
    char* CTXS = p;          p += (size_t)CH * 2048;   // CTX; later S + SIGb
    u16* FU    = (u16*)p;    p += (size_t)CH * 4096;
    u16* QKV   = (u16*)p;    p += (size_t)CH * 12288;  // aliased as U
    u16* AOXP  = (u16*)p;    p += (size_t)CH * 4096;   // AO then XP
    u16* H1    = (u16*)p;    p += (size_t)CH * 128;
    u16* G1    = (u16*)p;    p += (size_t)CH * 256;
    float2* STA = (float2*)p; p += (size_t)CH * 32;
    float2* ST2 = (float2*)p; p += (size_t)CH * 32;
    u16* CTX  = (u16*)CTXS;
    u16* S    = (u16*)CTXS;                          // CH x 512 (first half)
    u16* SIGb = (u16*)(CTXS + (size_t)CH * 1024);    // CH x 512 (second half)
    u16* U    = QKV;

    // d_out as scratch: first half X2, second half T2/X3 (dead before out-proj)
    u16* O16 = (u16*)d_out;

    k_w2b<<<(W_TOT + 255) / 256, 256, 0, stream>>>(
        conv_pw_w, in_proj_w, attn_out_w, ffn_w1, ffn_w2, mlp_w1, mlp_w2,
        gate_w1, se_w1, se_w2, outp_w, Wb);
    k_wfold<<<3584, 256, 0, stream>>>(
        in_proj_w, ln_attn_w, ln_attn_b, in_proj_b,
        ffn_w1, ln_ffn_w, ln_ffn_b, ffn_b1,
        mlp_w1, mlp_ln_w, mlp_ln_b, mlp_b1,
        Wb, sA, cA, sF, cF, sM, cM);

    const int Ri = CH * 4;
    auto g128 = [](int M, int Nc) { return dim3((Nc + 127) / 128, (M + 127) / 128); };
    auto g256 = [](int M, int Nc) { return dim3((M / 256) * (Nc / 256)); };

    for (int c0 = 0; c0 < N_TOT; c0 += CH) {
        u16* X2b  = O16 + (size_t)c0 * 2048;                         // chunk-local rows
        u16* T2X3 = O16 + (size_t)N_TOT * 2048 + (size_t)c0 * 2048;  // T2 then X3

        k_prep_ln<<<CH / 4, 256, 0, stream>>>(br, c0, Tb, CTX, STA);
        // gate
        k_mfma_gemm<1, true, false, 1><<<g128(CH, 128), 256, 0, stream>>>(
            CTX, Wb + W_GATE1, gate_b1, nullptr, G1, CH, 128, 1024, 0);
        k_gate2<<<(CH + 255) / 256, 256, 0, stream>>>(G1, gate_w2, gate_b2,
                                                      alpha + (size_t)c0 * 3, CH);
        // attention expert (LN folded into in_proj weights)
        k_gemm256<0, false, false, 1, true><<<g256(Ri, 1536), 512, 0, stream>>>(
            Tb, Wb + W_INPROJ, nullptr, nullptr, QKV, 1536, 512, 0, 6,
            nullptr, nullptr, STA, sA, cA);
        k_attn<<<CH, 256, 0, stream>>>(QKV, AOXP);
        k_gemm256<0, true, true, 1, false><<<g256(Ri, 512), 512, 0, stream>>>(
            AOXP, Wb + W_ATTNO, attn_out_b, Tb, T2X3, 512, 512, 0, 2,
            nullptr, nullptr, nullptr, nullptr, nullptr);
        k_lnstats<<<Ri / 4, 256, 0, stream>>>(T2X3, ST2);
        k_gemm256<1, false, false, 1, true><<<g256(Ri, 1024), 512, 0, stream>>>(
            T2X3, Wb + W_FFN1, nullptr, nullptr, U, 1024, 512, 0, 4,
            nullptr, nullptr, ST2, sF, cF);
        k_gemm256<0, true, true, 1, false><<<g256(Ri, 512), 512, 0, stream>>>(
            U, Wb + W_FFN2, ffn_b2, T2X3, X2b, 512, 1024, 0, 2,
            nullptr, nullptr, nullptr, nullptr, nullptr);
        // MLP expert (LN folded into mlp1 weights; X3 overwrites T2)
        k_gemm256<1, false, false, 1, true><<<g256(Ri, 1024), 512, 0, stream>>>(
            Tb, Wb + W_MLP1, nullptr, nullptr, U, 1024, 512, 0, 4,
            nullptr, nullptr, STA, sM, cM);
        k_gemm256<0, true, true, 1, false><<<g256(Ri, 512), 512, 0, stream>>>(
            U, Wb + W_MLP2, mlp_b2, Tb, T2X3, 512, 1024, 0, 2,
            nullptr, nullptr, nullptr, nullptr, nullptr);
        // conv expert: pw GEMM + fused depthwise + SE squeeze
        k_gemm256<0, false, false, 3, false><<<g256(Ri, 512), 512, 0, stream>>>(
            Tb, Wb + W_CONVPW, nullptr, nullptr, AOXP, 512, 512, 0, 2,
            conv_dw_w, S, nullptr, nullptr, nullptr);
        k_mfma_gemm<2, false, false, 1><<<g128(CH, 64), 256, 0, stream>>>(
            S, Wb + W_SE1, nullptr, nullptr, H1, CH, 64, 512, 0);
        k_mfma_gemm<3, false, false, 1><<<g128(CH, 512), 256, 0, stream>>>(
            H1, Wb + W_SE2, nullptr, nullptr, SIGb, CH, 512, 64, 0);
        // GN + gelu + alpha-fuse
        k_gnfin_fuse<<<CH, 256, 0, stream>>>(AOXP, SIGb, gn_w, gn_b,
                                             X2b, T2X3, alpha, c0, FU);
        // output projection, float4 scatter to (n, o, b)
        k_gemm256<0, false, false, 2, false><<<g256(Ri, 512), 512, 0, stream>>>(
            FU, Wb + W_OUTP, nullptr, nullptr, out, 512, 512, c0, 2,
            nullptr, nullptr, nullptr, nullptr, nullptr);
    }
}

// Round 16
// 985.809 us; speedup vs baseline: 4.8268x; 1.0045x over previous
//
#include <hip/hip_runtime.h>
#include <math.h>

// ---------------------------------------------------------------------------
// ParallelExpertsMixer — Round 16: R14 + nontemporal stores for the final
// out-projection (STORE=2), fixed to use ext_vector floatx4 (the builtin
// rejects HIP_vector_type float4). Everything else identical to R14 (990us).
// ---------------------------------------------------------------------------

#define N_TOT 16384
#define EPSV 1e-5f

typedef unsigned short u16;
typedef unsigned int   u32;
typedef __attribute__((ext_vector_type(8))) short  short8;
typedef __attribute__((ext_vector_type(4))) float  floatx4;

__device__ __forceinline__ float gelu_exact(float x) {
    return 0.5f * x * (1.0f + erff(x * 0.70710678118654752440f));
}
__device__ __forceinline__ float wave_sum(float v) {
    #pragma unroll
    for (int o = 32; o > 0; o >>= 1) v += __shfl_xor(v, o);
    return v;
}
__device__ __forceinline__ u16 f2bf(float f) {
    u32 u = __float_as_uint(f);
    return (u16)((u + 0x7fffu + ((u >> 16) & 1u)) >> 16);
}
__device__ __forceinline__ u32 pack2(float lo, float hi) {
    return (u32)f2bf(lo) | ((u32)f2bf(hi) << 16);
}
__device__ __forceinline__ float bf1f(u16 u) { return __uint_as_float((u32)u << 16); }
__device__ __forceinline__ float2 bf2f2(u32 u) {
    return make_float2(__uint_as_float(u << 16), __uint_as_float(u & 0xffff0000u));
}
__device__ __forceinline__ void gload_lds16(const void* g, void* l) {
    __builtin_amdgcn_global_load_lds(
        (const __attribute__((address_space(1))) unsigned int*)g,
        (__attribute__((address_space(3))) unsigned int*)l, 16, 0, 0);
}

#define BARR() asm volatile("s_barrier" ::: "memory")
#define VMW(N) asm volatile("s_waitcnt vmcnt(" #N ")" ::: "memory")

// ---- bf16 weight conversion (once per launch) -----------------------------
#define W_CONVPW 0
#define W_INPROJ 262144
#define W_ATTNO  1048576
#define W_FFN1   1310720
#define W_FFN2   1835008
#define W_MLP1   2359296
#define W_MLP2   2883584
#define W_GATE1  3407872
#define W_SE1    3538944
#define W_SE2    3571712
#define W_OUTP   3604480
#define W_TOT    3866624

__global__ __launch_bounds__(256) void k_w2b(
        const float* __restrict__ p0, const float* __restrict__ p1,
        const float* __restrict__ p2, const float* __restrict__ p3,
        const float* __restrict__ p4, const float* __restrict__ p5,
        const float* __restrict__ p6, const float* __restrict__ p7,
        const float* __restrict__ p8, const float* __restrict__ p9,
        const float* __restrict__ p10, u16* __restrict__ dst)
{
    int i = blockIdx.x * 256 + threadIdx.x;
    if (i >= W_TOT) return;
    const float* s; int off;
    if      (i < W_INPROJ) { s = p0;  off = W_CONVPW; }
    else if (i < W_ATTNO)  { s = p1;  off = W_INPROJ; }
    else if (i < W_FFN1)   { s = p2;  off = W_ATTNO; }
    else if (i < W_FFN2)   { s = p3;  off = W_FFN1; }
    else if (i < W_MLP1)   { s = p4;  off = W_FFN2; }
    else if (i < W_MLP2)   { s = p5;  off = W_MLP1; }
    else if (i < W_GATE1)  { s = p6;  off = W_MLP2; }
    else if (i < W_SE1)    { s = p7;  off = W_GATE1; }
    else if (i < W_SE2)    { s = p8;  off = W_SE1; }
    else if (i < W_OUTP)   { s = p9;  off = W_SE2; }
    else                   { s = p10; off = W_OUTP; }
    dst[i] = f2bf(s[i - off]);
}

// ---- fold LN into weights: W' = lnw*W (bf16), s_n = sum(W'_n),
//      c_n = lnb.W_n + bias_n.  One block per output row (3584 rows, K=512).
__global__ __launch_bounds__(256) void k_wfold(
        const float* __restrict__ wA, const float* __restrict__ lnwA,
        const float* __restrict__ lnbA, const float* __restrict__ biasA,
        const float* __restrict__ wF, const float* __restrict__ lnwF,
        const float* __restrict__ lnbF, const float* __restrict__ biasF,
        const float* __restrict__ wM, const float* __restrict__ lnwM,
        const float* __restrict__ lnbM, const float* __restrict__ biasM,
        u16* __restrict__ Wb,
        float* __restrict__ sA, float* __restrict__ cA,
        float* __restrict__ sF, float* __restrict__ cF,
        float* __restrict__ sM, float* __restrict__ cM)
{
    __shared__ float rs_[4], rc_[4];
    int r = blockIdx.x, t = threadIdx.x;
    const float *W, *lnw, *lnb, *bias;
    u16* dst; float *sp, *cp; int row;
    if (r < 1536)      { W = wA; lnw = lnwA; lnb = lnbA; bias = biasA;
                         dst = Wb + W_INPROJ; sp = sA; cp = cA; row = r; }
    else if (r < 2560) { W = wF; lnw = lnwF; lnb = lnbF; bias = biasF;
                         dst = Wb + W_FFN1;   sp = sF; cp = cF; row = r - 1536; }
    else               { W = wM; lnw = lnwM; lnb = lnbM; bias = biasM;
                         dst = Wb + W_MLP1;   sp = sM; cp = cM; row = r - 2560; }
    const float* wr = W + (size_t)row * 512;
    float s = 0.f, c = 0.f;
    #pragma unroll
    for (int i = 0; i < 2; ++i) {
        int k = t + i * 256;
        float wv = lnw[k] * wr[k];
        dst[(size_t)row * 512 + k] = f2bf(wv);
        s += wv;
        c += lnb[k] * wr[k];
    }
    s = wave_sum(s); c = wave_sum(c);
    if ((t & 63) == 0) { rs_[t >> 6] = s; rc_[t >> 6] = c; }
    __syncthreads();
    if (t == 0) {
        sp[row] = rs_[0] + rs_[1] + rs_[2] + rs_[3];
        cp[row] = rc_[0] + rc_[1] + rc_[2] + rc_[3] + bias[row];
    }
}

// ---- prep (4 samples/block): branches -> Tb + CTX + LN stats (rs, rs*m) ---
__global__ __launch_bounds__(256) void k_prep_ln(const float* __restrict__ br,
        int baseN, u16* __restrict__ Tb, u16* __restrict__ CTX,
        float2* __restrict__ STA)
{
    __shared__ float lds[4][4][516];
    int t = threadIdx.x;
    int s0 = blockIdx.x * 4;
    #pragma unroll
    for (int s = 0; s < 4; ++s) {
        const float* p = br + (size_t)(baseN + s0 + s) * 2048;
        u16* c = CTX + (size_t)(s0 + s) * 1024;
        #pragma unroll
        for (int i = 0; i < 2; ++i) {
            int f = t + i * 256;
            float4 v = *(const float4*)(p + f * 4);
            lds[s][0][f] = v.x; lds[s][1][f] = v.y; lds[s][2][f] = v.z; lds[s][3][f] = v.w;
            c[f]       = f2bf((v.x + v.y + v.z + v.w) * 0.25f);
            c[512 + f] = f2bf(fmaxf(fmaxf(v.x, v.y), fmaxf(v.z, v.w)));
        }
    }
    __syncthreads();
    int wv = t >> 6, lane = t & 63, f0 = lane * 8;
    #pragma unroll
    for (int p4i = 0; p4i < 4; ++p4i) {
        int idx = wv * 4 + p4i;
        int s = idx >> 2, b = idx & 3;
        float xv[8];
        #pragma unroll
        for (int i = 0; i < 8; ++i) xv[i] = lds[s][b][f0 + i];
        float sm = 0.f;
        #pragma unroll
        for (int i = 0; i < 8; ++i) sm += xv[i];
        sm = wave_sum(sm);
        float m = sm * (1.f / 512.f);
        float q = 0.f;
        #pragma unroll
        for (int i = 0; i < 8; ++i) { float d = xv[i] - m; q += d * d; }
        q = wave_sum(q);
        float rs = rsqrtf(q * (1.f / 512.f) + EPSV);
        size_t row = (size_t)(s0 + s) * 4 + b;
        *(uint4*)(Tb + row * 512 + f0) = make_uint4(pack2(xv[0], xv[1]), pack2(xv[2], xv[3]),
                                                    pack2(xv[4], xv[5]), pack2(xv[6], xv[7]));
        if (lane == 0) STA[row] = make_float2(rs, rs * m);
    }
}

// ---- LN row stats only (rs, rs*m) from bf16 rows --------------------------
__global__ __launch_bounds__(256) void k_lnstats(const u16* __restrict__ X,
        float2* __restrict__ ST)
{
    int t = threadIdx.x;
    int wave = t >> 6, lane = t & 63;
    size_t r = (size_t)blockIdx.x * 4 + wave;
    int f0 = lane * 8;
    uint4 raw = *(const uint4*)(X + r * 512 + f0);
    float xv[8];
    { float2 a = bf2f2(raw.x); xv[0] = a.x; xv[1] = a.y; }
    { float2 a = bf2f2(raw.y); xv[2] = a.x; xv[3] = a.y; }
    { float2 a = bf2f2(raw.z); xv[4] = a.x; xv[5] = a.y; }
    { float2 a = bf2f2(raw.w); xv[6] = a.x; xv[7] = a.y; }
    float s = 0.f;
    #pragma unroll
    for (int i = 0; i < 8; ++i) s += xv[i];
    s = wave_sum(s);
    float m = s * (1.f / 512.f);
    float q = 0.f;
    #pragma unroll
    for (int i = 0; i < 8; ++i) { float d = xv[i] - m; q += d * d; }
    q = wave_sum(q);
    float rs = rsqrtf(q * (1.f / 512.f) + EPSV);
    if (lane == 0) ST[r] = make_float2(rs, rs * m);
}

// ===========================================================================
// 256x256 4-phase/K-tile GEMM. BK=64, 512 thr / 8 waves, per-wave 64x32
// piece of EACH 128x128 C-quadrant. LDS: 2 buf x [Ah0|Ah1|Bh0|Bh1] x 16KB.
// ONE barrier per phase (R14-verified). Steady VMW(4),(4),(4),-; drain
// (4),(2),(0),-.
// STORE: 1 bf16 (+opt residual), 2 NT-f4-scatter(out), 3 dw-conv+squeeze.
// LNFOLD (STORE=1): v = acc*rs[m] - (rs*m)[m]*s[n] + c[n], hoisted loads.
// ===========================================================================

#define STAGE(SLOT, TILE) do {                                                \
    const u16* sm_ = ((SLOT) < 2) ? A : W;                                    \
    int rb_ = (((SLOT) < 2) ? m0 : n0) + ((SLOT) & 1) * 128;                  \
    int k0_ = (TILE) * 64;                                                    \
    u16* db_ = lds + (((TILE) & 1) * 32768) + (SLOT) * 8192;                  \
    _Pragma("unroll")                                                         \
    for (int l_ = 0; l_ < 2; ++l_) {                                          \
        int L_ = (l_ * 512 + tid) * 16;                                       \
        int row_ = L_ >> 7;                                                   \
        int ir_ = (L_ & 127) ^ ((row_ & 7) << 4);                             \
        gload_lds16(sm_ + (size_t)(rb_ + row_) * K + k0_ + (ir_ >> 1),        \
                    db_ + (L_ >> 1));                                         \
    } } while (0)

#define QUAD(MH, NH, STAGESTMT) do {                                          \
    const u16* lb_ = lds + cur * 32768;                                       \
    short8 a_[4][2], b_[2][2];                                                \
    _Pragma("unroll")                                                         \
    for (int mi = 0; mi < 4; ++mi)                                            \
        _Pragma("unroll")                                                     \
        for (int ks = 0; ks < 2; ++ks)                                        \
            a_[mi][ks] = *(const short8*)(lb_ + (MH) * 8192 + arow[mi] + gcol[ks]); \
    _Pragma("unroll")                                                         \
    for (int ni = 0; ni < 2; ++ni)                                            \
        _Pragma("unroll")                                                     \
        for (int ks = 0; ks < 2; ++ks)                                        \
            b_[ni][ks] = *(const short8*)(lb_ + 16384 + (NH) * 8192 + brow[ni] + gcol[ks]); \
    STAGESTMT;                                                                \
    __builtin_amdgcn_s_setprio(1);                                            \
    _Pragma("unroll")                                                         \
    for (int ks = 0; ks < 2; ++ks)                                            \
        _Pragma("unroll")                                                     \
        for (int mi = 0; mi < 4; ++mi)                                        \
            _Pragma("unroll")                                                 \
            for (int ni = 0; ni < 2; ++ni)                                    \
                acc[MH][NH][mi][ni] = __builtin_amdgcn_mfma_f32_16x16x32_bf16( \
                    a_[mi][ks], b_[ni][ks], acc[MH][NH][mi][ni], 0, 0, 0);    \
    __builtin_amdgcn_s_setprio(0);                                            \
} while (0)

template<int EPI, bool HAS_BIAS, bool HAS_RES, int STORE, bool LNFOLD>
__global__ __launch_bounds__(512, 2) void k_gemm256(
        const u16* __restrict__ A, const u16* __restrict__ W,
        const float* __restrict__ bias, const u16* __restrict__ Res,
        void* __restrict__ Cout, int Ncols, int K, int baseN, int nTX,
        const float* __restrict__ dwp, u16* __restrict__ Sout,
        const float2* __restrict__ Astat, const float* __restrict__ Scol,
        const float* __restrict__ Ccol)
{
    __shared__ __align__(16) u16 lds[65536];   // 128 KiB
    const int tid = threadIdx.x;
    const int wid = tid >> 6, lane = tid & 63;
    const int lr = lane & 15, kg = lane >> 4;
    const int wm = (wid >> 2) * 64;    // M offset within each M-half
    const int wn = (wid & 3) * 32;     // N offset within each N-half

    // bijective XCD swizzle (m204)
    int nwg = gridDim.x, orig = blockIdx.x;
    int q = nwg >> 3, r = nwg & 7;
    int xcd = orig & 7, lin = orig >> 3;
    int wgid = (xcd < r ? xcd * (q + 1) : r * (q + 1) + (xcd - r) * q) + lin;
    const int m0 = (wgid / nTX) * 256, n0 = (wgid % nTX) * 256;

    // fragment LDS element offsets (within one half-tile)
    int arow[4], brow[2], gcol[2];
    #pragma unroll
    for (int mi = 0; mi < 4; ++mi) arow[mi] = (wm + mi * 16 + lr) * 64;
    #pragma unroll
    for (int ni = 0; ni < 2; ++ni) brow[ni] = (wn + ni * 16 + lr) * 64;
    #pragma unroll
    for (int ks = 0; ks < 2; ++ks) gcol[ks] = (ks * 32 + kg * 8) ^ ((lr & 7) << 3);

    floatx4 acc[2][2][4][2] = {};

    // prologue: stage K-tile 0 in consumption order
    STAGE(0, 0); STAGE(2, 0); STAGE(1, 0); STAGE(3, 0);

    const int NT = K >> 6;
    int cur = 0;
    for (int t = 0; t < NT - 1; ++t) {
        int nx = t + 1;
        VMW(4); BARR(); QUAD(0, 0, STAGE(0, nx));
        VMW(4); BARR(); QUAD(1, 0, STAGE(2, nx));
        VMW(4); BARR(); QUAD(0, 1, STAGE(1, nx));
                BARR(); QUAD(1, 1, STAGE(3, nx));
        cur ^= 1;
    }
    // last K-tile: counted drain
    VMW(4); BARR(); QUAD(0, 0, (void)0);
    VMW(2); BARR(); QUAD(1, 0, (void)0);
    VMW(0); BARR(); QUAD(0, 1, (void)0);
            BARR(); QUAD(1, 1, (void)0);

    int rm = kg * 4;
    if (LNFOLD) {
        // hoisted epilogue: s,c for this thread's 4 n-values; row stats per (MH,mi)
        float sv[4], cv[4];
        int nidx[4];
        #pragma unroll
        for (int g = 0; g < 4; ++g) {   // g = NH*2 + ni
            int n = n0 + (g >> 1) * 128 + wn + (g & 1) * 16 + lr;
            nidx[g] = n;
            sv[g] = Scol[n];
            cv[g] = Ccol[n];
        }
        #pragma unroll
        for (int MH = 0; MH < 2; ++MH)
        #pragma unroll
        for (int mi = 0; mi < 4; ++mi) {
            int mb = m0 + MH * 128 + wm + mi * 16 + rm;
            float4 stA = *(const float4*)((const float*)(Astat + mb));      // rows mb,mb+1
            float4 stB = *(const float4*)((const float*)(Astat + mb + 2)); // rows mb+2,mb+3
            float rsv[4] = {stA.x, stA.z, stB.x, stB.z};
            float rmv[4] = {stA.y, stA.w, stB.y, stB.w};
            #pragma unroll
            for (int g = 0; g < 4; ++g) {
                int NH = g >> 1, ni = g & 1;
                #pragma unroll
                for (int rr = 0; rr < 4; ++rr) {
                    float v = acc[MH][NH][mi][ni][rr] * rsv[rr] - rmv[rr] * sv[g] + cv[g];
                    if (EPI == 1) v = gelu_exact(v);
                    ((u16*)Cout)[(size_t)(mb + rr) * Ncols + nidx[g]] = f2bf(v);
                }
            }
        }
        return;
    }

    // epilogue: D col = lane&15 (n), row = kg*4 + reg (m)
    #pragma unroll
    for (int MH = 0; MH < 2; ++MH)
    #pragma unroll
    for (int NH = 0; NH < 2; ++NH)
    #pragma unroll
    for (int ni = 0; ni < 2; ++ni) {
        int n = n0 + NH * 128 + wn + ni * 16 + lr;
        float bv = HAS_BIAS ? bias[n] : 0.f;
        float w0, w1, w2;
        if (STORE == 3) { w0 = dwp[n * 3]; w1 = dwp[n * 3 + 1]; w2 = dwp[n * 3 + 2]; }
        #pragma unroll
        for (int mi = 0; mi < 4; ++mi) {
            int mb = m0 + MH * 128 + wm + mi * 16 + rm;
            float vv[4];
            #pragma unroll
            for (int rr = 0; rr < 4; ++rr) {
                float v = acc[MH][NH][mi][ni][rr] + bv;
                if (EPI == 1) v = gelu_exact(v);
                else if (EPI == 2) v = fmaxf(v, 0.f);
                else if (EPI == 3) v = 1.f / (1.f + expf(-v));
                vv[rr] = v;
            }
            if (STORE == 2) {
                // nontemporal: output is write-once, never re-read -> skip L2 alloc
                floatx4 val;
                val[0] = vv[0]; val[1] = vv[1]; val[2] = vv[2]; val[3] = vv[3];
                floatx4* dst = (floatx4*)((float*)Cout
                    + (size_t)(baseN + (mb >> 2)) * 2048 + (size_t)n * 4);
                __builtin_nontemporal_store(val, dst);
            } else if (STORE == 3) {
                // depthwise k=3 over tokens (rows mb..mb+3 = one sample) + squeeze
                float y0 = w1 * vv[0] + w2 * vv[1];
                float y1 = w0 * vv[0] + w1 * vv[1] + w2 * vv[2];
                float y2 = w0 * vv[1] + w1 * vv[2] + w2 * vv[3];
                float y3 = w0 * vv[2] + w1 * vv[3];
                u16* xp = (u16*)Cout + (size_t)mb * Ncols + n;
                xp[0] = f2bf(y0);
                xp[Ncols] = f2bf(y1);
                xp[2 * Ncols] = f2bf(y2);
                xp[3 * Ncols] = f2bf(y3);
                Sout[(size_t)(mb >> 2) * Ncols + n] = f2bf((y0 + y1 + y2 + y3) * 0.25f);
            } else {
                #pragma unroll
                for (int rr = 0; rr < 4; ++rr) {
                    float v = vv[rr];
                    if (HAS_RES) v += bf1f(Res[(size_t)(mb + rr) * Ncols + n]);
                    ((u16*)Cout)[(size_t)(mb + rr) * Ncols + n] = f2bf(v);
                }
            }
        }
    }
}

// ---- 128^2 MFMA GEMM (small shapes: gate1, se1, se2) ----------------------
template<int EPI, bool HAS_BIAS, bool HAS_RES, int STORE>
__global__ __launch_bounds__(256) void k_mfma_gemm(
        const u16* __restrict__ A, const u16* __restrict__ W,
        const float* __restrict__ bias, const u16* __restrict__ Res,
        void* __restrict__ Cout, int M, int Ncols, int K, int baseN)
{
    __shared__ u16 As[128 * 32];
    __shared__ u16 Bs[128 * 32];
    int t = threadIdx.x;
    int wid = t >> 6, lane = t & 63;
    int wm = (wid >> 1) * 64, wn = (wid & 1) * 64;
    int m0 = blockIdx.y * 128, n0 = blockIdx.x * 128;
    int srow = t >> 2;
    int scol = (((t & 3) ^ ((srow >> 1) & 3)) * 8);
    int aR0 = min(m0 + srow, M - 1),      aR1 = min(m0 + 64 + srow, M - 1);
    int bR0 = min(n0 + srow, Ncols - 1),  bR1 = min(n0 + 64 + srow, Ncols - 1);
    const u16* Ap0 = A + (size_t)aR0 * K + scol;
    const u16* Ap1 = A + (size_t)aR1 * K + scol;
    const u16* Wp0 = W + (size_t)bR0 * K + scol;
    const u16* Wp1 = W + (size_t)bR1 * K + scol;
    u16* AsT0 = As + t * 8;  u16* AsT1 = As + 2048 + t * 8;
    u16* BsT0 = Bs + t * 8;  u16* BsT1 = Bs + 2048 + t * 8;

    int kg = lane >> 4, lr = lane & 15;
    int cb = kg ^ ((lr >> 1) & 3);
    const u16* aF = As + (wm + lr) * 32 + cb * 8;
    const u16* bF = Bs + (wn + lr) * 32 + cb * 8;

    floatx4 acc[4][4] = {};
    for (int k0 = 0; k0 < K; k0 += 32) {
        __syncthreads();
        gload_lds16(Ap0 + k0, AsT0);
        gload_lds16(Ap1 + k0, AsT1);
        gload_lds16(Wp0 + k0, BsT0);
        gload_lds16(Wp1 + k0, BsT1);
        __syncthreads();
        short8 a[4], b[4];
        #pragma unroll
        for (int i = 0; i < 4; ++i) {
            a[i] = *(const short8*)(aF + i * 512);
            b[i] = *(const short8*)(bF + i * 512);
        }
        #pragma unroll
        for (int i = 0; i < 4; ++i)
            #pragma unroll
            for (int j = 0; j < 4; ++j)
                acc[i][j] = __builtin_amdgcn_mfma_f32_16x16x32_bf16(a[i], b[j], acc[i][j], 0, 0, 0);
    }
    int rm = (lane >> 4) * 4;
    #pragma unroll
    for (int j = 0; j < 4; ++j) {
        int n = n0 + wn + j * 16 + lr;
        float bv = HAS_BIAS ? bias[min(n, Ncols - 1)] : 0.f;
        #pragma unroll
        for (int i = 0; i < 4; ++i) {
            int mb = m0 + wm + i * 16 + rm;
            float vv[4];
            #pragma unroll
            for (int r = 0; r < 4; ++r) {
                float v = acc[i][j][r] + bv;
                if (EPI == 1) v = gelu_exact(v);
                else if (EPI == 2) v = fmaxf(v, 0.f);
                else if (EPI == 3) v = 1.f / (1.f + expf(-v));
                vv[r] = v;
            }
            #pragma unroll
            for (int r = 0; r < 4; ++r) {
                int m = mb + r;
                if (m < M && n < Ncols) {
                    float v = vv[r];
                    if (HAS_RES) v += bf1f(Res[(size_t)m * Ncols + n]);
                    if (STORE == 0) ((float*)Cout)[(size_t)m * Ncols + n] = v;
                    else            ((u16*)Cout)[(size_t)m * Ncols + n] = f2bf(v);
                }
            }
        }
    }
}

// ---- attention core: 4x4 per (sample, head), bf16 in/out ------------------
__global__ __launch_bounds__(256) void k_attn(const u16* __restrict__ QKV,
        u16* __restrict__ AO)
{
    int t = threadIdx.x;
    int h = t >> 6, lane = t & 63;
    size_t n = (size_t)blockIdx.x;
    const u16* base = QKV + n * 4 * 1536 + h * 128 + lane * 2;
    float2 q[4], k[4], v[4];
    #pragma unroll
    for (int b = 0; b < 4; ++b) {
        q[b] = bf2f2(*(const u32*)(base + b * 1536));
        k[b] = bf2f2(*(const u32*)(base + b * 1536 + 512));
        v[b] = bf2f2(*(const u32*)(base + b * 1536 + 1024));
    }
    const float scale = 0.08838834764831845f;  // 128^-0.5
    float sc[4][4];
    #pragma unroll
    for (int qb = 0; qb < 4; ++qb)
        #pragma unroll
        for (int kb = 0; kb < 4; ++kb) {
            float p = q[qb].x * k[kb].x + q[qb].y * k[kb].y;
            sc[qb][kb] = wave_sum(p) * scale;
        }
    #pragma unroll
    for (int qb = 0; qb < 4; ++qb) {
        float mx = fmaxf(fmaxf(sc[qb][0], sc[qb][1]), fmaxf(sc[qb][2], sc[qb][3]));
        float e0 = expf(sc[qb][0] - mx), e1 = expf(sc[qb][1] - mx);
        float e2 = expf(sc[qb][2] - mx), e3 = expf(sc[qb][3] - mx);
        float inv = 1.f / (e0 + e1 + e2 + e3);
        float ox = (e0 * v[0].x + e1 * v[1].x + e2 * v[2].x + e3 * v[3].x) * inv;
        float oy = (e0 * v[0].y + e1 * v[1].y + e2 * v[2].y + e3 * v[3].y) * inv;
        *(u32*)(AO + (n * 4 + qb) * 512 + h * 128 + lane * 2) = pack2(ox, oy);
    }
}

// ---- SE scale + GroupNorm + GELU + alpha-fuse -> FU bf16 ------------------
__global__ __launch_bounds__(256) void k_gnfin_fuse(
        const u16* __restrict__ XP, const u16* __restrict__ SIG,
        const float* __restrict__ gnw, const float* __restrict__ gnb,
        const u16* __restrict__ X2, const u16* __restrict__ X3,
        const float* __restrict__ alpha, int baseN, u16* __restrict__ FU)
{
    __shared__ float red[8];
    size_t ls = blockIdx.x;
    int t = threadIdx.x;
    int wave = t >> 6, lane = t & 63;
    int f = t * 2;
    const u16* p = XP + ls * 2048;
    float2 sg = bf2f2(*(const u32*)(SIG + ls * 512 + f));
    float2 xr[4];
    #pragma unroll
    for (int b = 0; b < 4; ++b) {
        float2 x = bf2f2(*(const u32*)(p + b * 512 + f));
        xr[b] = make_float2(x.x * sg.x, x.y * sg.y);
    }
    float s = 0.f;
    #pragma unroll
    for (int b = 0; b < 4; ++b) s += xr[b].x + xr[b].y;
    s = wave_sum(s);
    if (lane == 0) red[wave] = s;
    __syncthreads();
    float m = (red[0] + red[1] + red[2] + red[3]) * (1.f / 2048.f);
    float q = 0.f;
    #pragma unroll
    for (int b = 0; b < 4; ++b) {
        float dx = xr[b].x - m, dy = xr[b].y - m;
        q += dx * dx + dy * dy;
    }
    q = wave_sum(q);
    if (lane == 0) red[4 + wave] = q;
    __syncthreads();
    float rs = rsqrtf((red[4] + red[5] + red[6] + red[7]) * (1.f / 2048.f) + EPSV);
    const float* a = alpha + (size_t)(baseN + ls) * 3;
    float a0 = a[0], a1 = a[1], a2 = a[2];
    float gw0 = gnw[f], gw1 = gnw[f + 1], gb0 = gnb[f], gb1 = gnb[f + 1];
    #pragma unroll
    for (int b = 0; b < 4; ++b) {
        float x1a = gelu_exact((xr[b].x - m) * rs * gw0 + gb0);
        float x1b = gelu_exact((xr[b].y - m) * rs * gw1 + gb1);
        float2 v2 = bf2f2(*(const u32*)(X2 + (ls * 4 + b) * 512 + f));
        float2 v3 = bf2f2(*(const u32*)(X3 + (ls * 4 + b) * 512 + f));
        *(u32*)(FU + (ls * 4 + b) * 512 + f) =
            pack2(a0 * x1a + a1 * v2.x + a2 * v3.x,
                  a0 * x1b + a1 * v2.y + a2 * v3.y);
    }
}

// ---- gate stage 2: logits (3x128 dot) + softmax -> alpha ------------------
__global__ __launch_bounds__(256) void k_gate2(const u16* __restrict__ G1,
        const float* __restrict__ w2, const float* __restrict__ b2,
        float* __restrict__ alpha, int CH)
{
    int s = blockIdx.x * 256 + threadIdx.x;
    if (s >= CH) return;
    float l0 = b2[0], l1 = b2[1], l2 = b2[2];
    const u16* g = G1 + (size_t)s * 128;
    for (int j = 0; j < 128; j += 2) {
        float2 gg = bf2f2(*(const u32*)(g + j));
        l0 += gg.x * w2[j]       + gg.y * w2[j + 1];
        l1 += gg.x * w2[128 + j] + gg.y * w2[129 + j];
        l2 += gg.x * w2[256 + j] + gg.y * w2[257 + j];
    }
    float mx = fmaxf(l0, fmaxf(l1, l2));
    float e0 = expf(l0 - mx), e1 = expf(l1 - mx), e2 = expf(l2 - mx);
    float inv = 1.f / (e0 + e1 + e2);
    float* a = alpha + (size_t)s * 3;
    a[0] = e0 * inv; a[1] = e1 * inv; a[2] = e2 * inv;
}

// ---------------------------------------------------------------------------
extern "C" void kernel_launch(void* const* d_in, const int* in_sizes, int n_in,
                              void* d_out, int out_size, void* d_ws, size_t ws_size,
                              hipStream_t stream)
{
    (void)in_sizes; (void)n_in; (void)out_size;
    const float* br         = (const float*)d_in[0];
    const float* conv_pw_w  = (const float*)d_in[1];
    const float* conv_dw_w  = (const float*)d_in[2];
    const float* gn_w       = (const float*)d_in[3];
    const float* gn_b       = (const float*)d_in[4];
    const float* se_w1      = (const float*)d_in[5];
    const float* se_w2      = (const float*)d_in[6];
    const float* ln_attn_w  = (const float*)d_in[7];
    const float* ln_attn_b  = (const float*)d_in[8];
    const float* in_proj_w  = (const float*)d_in[9];
    const float* in_proj_b  = (const float*)d_in[10];
    const float* attn_out_w = (const float*)d_in[11];
    const float* attn_out_b = (const float*)d_in[12];
    const float* ln_ffn_w   = (const float*)d_in[13];
    const float* ln_ffn_b   = (const float*)d_in[14];
    const float* ffn_w1     = (const float*)d_in[15];
    const float* ffn_b1     = (const float*)d_in[16];
    const float* ffn_w2     = (const float*)d_in[17];
    const float* ffn_b2     = (const float*)d_in[18];
    const float* mlp_ln_w   = (const float*)d_in[19];
    const float* mlp_ln_b   = (const float*)d_in[20];
    const float* mlp_w1     = (const float*)d_in[21];
    const float* mlp_b1     = (const float*)d_in[22];
    const float* mlp_w2     = (const float*)d_in[23];
    const float* mlp_b2     = (const float*)d_in[24];
    const float* gate_w1    = (const float*)d_in[25];
    const float* gate_b1    = (const float*)d_in[26];
    const float* gate_w2    = (const float*)d_in[27];
    const float* gate_b2    = (const float*)d_in[28];
    const float* outp_w     = (const float*)d_in[29];
    float* out = (float*)d_out;

    char* ws = (char*)d_ws;
    float* alpha = (float*)ws;                       // N_TOT*3 fp32 = 196608 B
    u16* Wb = (u16*)(ws + 196608);                   // W_TOT bf16
    float* sA = (float*)(ws + 196608 + (size_t)W_TOT * 2);
    float* cA = sA + 1536;
    float* sF = cA + 1536;
    float* cF = sF + 1024;
    float* sM = cF + 1024;
    float* cM = sM + 1024;
    const size_t CB = 196608 + (size_t)W_TOT * 2 + 28672;   // 7958528
    int CH = N_TOT;
    while (CH > 64 && CB + (size_t)CH * 27072ULL > ws_size) CH >>= 1;

    // ws buffers (27072 B/sample)
    char* p = ws + CB;
    u16* Tb    = (u16*)p;    p += (size_t)CH * 4096;
    char* CTXS = p;          p += (size_t)CH * 2048;   // CTX; later S + SIGb
    u16* FU    = (u16*)p;    p += (size_t)CH * 4096;
    u16* QKV   = (u16*)p;    p += (size_t)CH * 12288;  // aliased as U
    u16* AOXP  = (u16*)p;    p += (size_t)CH * 4096;   // AO then XP
    u16* H1    = (u16*)p;    p += (size_t)CH * 128;
    u16* G1    = (u16*)p;    p += (size_t)CH * 256;
    float2* STA = (float2*)p; p += (size_t)CH * 32;
    float2* ST2 = (float2*)p; p += (size_t)CH * 32;
    u16* CTX  = (u16*)CTXS;
    u16* S    = (u16*)CTXS;                          // CH x 512 (first half)
    u16* SIGb = (u16*)(CTXS + (size_t)CH * 1024);    // CH x 512 (second half)
    u16* U    = QKV;

    // d_out as scratch: first half X2, second half T2/X3 (dead before out-proj)
    u16* O16 = (u16*)d_out;

    k_w2b<<<(W_TOT + 255) / 256, 256, 0, stream>>>(
        conv_pw_w, in_proj_w, attn_out_w, ffn_w1, ffn_w2, mlp_w1, mlp_w2,
        gate_w1, se_w1, se_w2, outp_w, Wb);
    k_wfold<<<3584, 256, 0, stream>>>(
        in_proj_w, ln_attn_w, ln_attn_b, in_proj_b,
        ffn_w1, ln_ffn_w, ln_ffn_b, ffn_b1,
        mlp_w1, mlp_ln_w, mlp_ln_b, mlp_b1,
        Wb, sA, cA, sF, cF, sM, cM);

    const int Ri = CH * 4;
    auto g128 = [](int M, int Nc) { return dim3((Nc + 127) / 128, (M + 127) / 128); };
    auto g256 = [](int M, int Nc) { return dim3((M / 256) * (Nc / 256)); };

    for (int c0 = 0; c0 < N_TOT; c0 += CH) {
        u16* X2b  = O16 + (size_t)c0 * 2048;                         // chunk-local rows
        u16* T2X3 = O16 + (size_t)N_TOT * 2048 + (size_t)c0 * 2048;  // T2 then X3

        k_prep_ln<<<CH / 4, 256, 0, stream>>>(br, c0, Tb, CTX, STA);
        // gate
        k_mfma_gemm<1, true, false, 1><<<g128(CH, 128), 256, 0, stream>>>(
            CTX, Wb + W_GATE1, gate_b1, nullptr, G1, CH, 128, 1024, 0);
        k_gate2<<<(CH + 255) / 256, 256, 0, stream>>>(G1, gate_w2, gate_b2,
                                                      alpha + (size_t)c0 * 3, CH);
        // attention expert (LN folded into in_proj weights)
        k_gemm256<0, false, false, 1, true><<<g256(Ri, 1536), 512, 0, stream>>>(
            Tb, Wb + W_INPROJ, nullptr, nullptr, QKV, 1536, 512, 0, 6,
            nullptr, nullptr, STA, sA, cA);
        k_attn<<<CH, 256, 0, stream>>>(QKV, AOXP);
        k_gemm256<0, true, true, 1, false><<<g256(Ri, 512), 512, 0, stream>>>(
            AOXP, Wb + W_ATTNO, attn_out_b, Tb, T2X3, 512, 512, 0, 2,
            nullptr, nullptr, nullptr, nullptr, nullptr);
        k_lnstats<<<Ri / 4, 256, 0, stream>>>(T2X3, ST2);
        k_gemm256<1, false, false, 1, true><<<g256(Ri, 1024), 512, 0, stream>>>(
            T2X3, Wb + W_FFN1, nullptr, nullptr, U, 1024, 512, 0, 4,
            nullptr, nullptr, ST2, sF, cF);
        k_gemm256<0, true, true, 1, false><<<g256(Ri, 512), 512, 0, stream>>>(
            U, Wb + W_FFN2, ffn_b2, T2X3, X2b, 512, 1024, 0, 2,
            nullptr, nullptr, nullptr, nullptr, nullptr);
        // MLP expert (LN folded into mlp1 weights; X3 overwrites T2)
        k_gemm256<1, false, false, 1, true><<<g256(Ri, 1024), 512, 0, stream>>>(
            Tb, Wb + W_MLP1, nullptr, nullptr, U, 1024, 512, 0, 4,
            nullptr, nullptr, STA, sM, cM);
        k_gemm256<0, true, true, 1, false><<<g256(Ri, 512), 512, 0, stream>>>(
            U, Wb + W_MLP2, mlp_b2, Tb, T2X3, 512, 1024, 0, 2,
            nullptr, nullptr, nullptr, nullptr, nullptr);
        // conv expert: pw GEMM + fused depthwise + SE squeeze
        k_gemm256<0, false, false, 3, false><<<g256(Ri, 512), 512, 0, stream>>>(
            Tb, Wb + W_CONVPW, nullptr, nullptr, AOXP, 512, 512, 0, 2,
            conv_dw_w, S, nullptr, nullptr, nullptr);
        k_mfma_gemm<2, false, false, 1><<<g128(CH, 64), 256, 0, stream>>>(
            S, Wb + W_SE1, nullptr, nullptr, H1, CH, 64, 512, 0);
        k_mfma_gemm<3, false, false, 1><<<g128(CH, 512), 256, 0, stream>>>(
            H1, Wb + W_SE2, nullptr, nullptr, SIGb, CH, 512, 64, 0);
        // GN + gelu + alpha-fuse
        k_gnfin_fuse<<<CH, 256, 0, stream>>>(AOXP, SIGb, gn_w, gn_b,
                                             X2b, T2X3, alpha, c0, FU);
        // output projection, NT float4 scatter to (n, o, b)
        k_gemm256<0, false, false, 2, false><<<g256(Ri, 512), 512, 0, stream>>>(
            FU, Wb + W_OUTP, nullptr, nullptr, out, 512, 512, c0, 2,
            nullptr, nullptr, nullptr, nullptr, nullptr);
    }
}